// Round 7
// baseline (1259.370 us; speedup 1.0000x reference)
//
#include <hip/hip_runtime.h>
#include <hip/hip_bf16.h>

// ---------------- problem constants ----------------
constexpr int N_NEWS = 50000, N_KW = 10000, N_ST = 2000;
constexpr int F_NEWS = 768, F_KW = 128, F_ST = 64;
constexpr int HID = 256, OUTD = 128;
constexpr int E_HK = 500000, E_HS = 250000, E_LBL = 150000;

// CSR section offsets in the concatenated degree/cursor pools
constexpr int OFFA = 0;                    // e_hk keyed by dst (kw)
constexpr int OFFB = N_KW;                 // e_hs keyed by dst (st)
constexpr int OFFC = N_KW + N_ST;          // e_hk keyed by src (news)
constexpr int OFFD = OFFC + N_NEWS;        // e_hs keyed by src (news)
constexpr int NTOT = OFFD + N_NEWS;        // 112000

enum { FLAG_ACC = 1, FLAG_RELU = 2 };

typedef unsigned short u16;
typedef __attribute__((ext_vector_type(8))) short bf16x8;
typedef __attribute__((ext_vector_type(8))) unsigned short u16x8;
typedef __attribute__((ext_vector_type(4))) float f32x4;

__device__ __forceinline__ u16 f2bf(float x) {
    return __builtin_bit_cast(u16, __float2bfloat16(x));
}
__device__ __forceinline__ float bf2f(u16 h) {
    unsigned u = ((unsigned)h) << 16;
    return __builtin_bit_cast(float, u);
}
__device__ __forceinline__ void split2(float x, u16& h, u16& l) {
    h = f2bf(x);
    l = f2bf(x - bf2f(h));
}

// ---------------- LDS-free split-bf16 MFMA GEMM with direct fragment loads ----------------
// Fragment layout for mfma_f32_16x16x32_bf16: lane holds row (l&15), k-chunk (l>>4)*8..+8.
// That is a contiguous 16B row-major global read -> no LDS staging, no barriers.
// ASRC: 0 = fp32 A (truncation hi/lo split in registers), 1 = plane A, 2 = dual-table plane A
// WMODE: 0 = write hi+lo planes, 1 = hi only, 2 = fused decoder reduce -> outv
// CFG: 0 = 4 waves as 1x4 (block 64 x 256), 1 = 4 waves as 2x2 (block 128 x 128)
template<int ASRC, int WMODE, bool LOWP, int CFG>
__global__ __launch_bounds__(256) void gemm_kernel(
    const float* __restrict__ Af,
    const u16* __restrict__ A1h, const u16* __restrict__ A1l,
    const u16* __restrict__ A2h, const u16* __restrict__ A2l,
    const int* __restrict__ ridx1, const int* __restrict__ ridx2, int lda, int kpiv,
    const u16* __restrict__ Bhg, const u16* __restrict__ Blg, int ldw,
    const float* __restrict__ bias,
    u16* __restrict__ Chi, u16* __restrict__ Clo, int ldc,
    const float* __restrict__ dw2, const float* __restrict__ db2,
    float* __restrict__ outv,
    int M, int K, int flags)
{
    constexpr int BM = (CFG == 0) ? 64 : 128;
    __shared__ float red[128];

    const int tid = threadIdx.x;
    const int bm = blockIdx.x * BM;
    const int l = tid & 63;
    const int w = tid >> 6;
    const int wm = (CFG == 0) ? 0 : (w >> 1);
    const int wn = (CFG == 0) ? w : (w & 1);
    const int lg = l >> 4, lr = l & 15;

    // ---- per-lane fragment base pointers ----
    const float* afp[4];
    const u16 *pA1h[4], *pA1l[4], *pA2h[4], *pA2l[4];
    const u16 *pBh[4], *pBl[4];
    #pragma unroll
    for (int mt = 0; mt < 4; ++mt) {
        int rg = bm + wm * 64 + mt * 16 + lr;
        if (rg > M - 1) rg = M - 1;
        if constexpr (ASRC == 0) {
            long ar = ridx1 ? (long)ridx1[rg] : (long)rg;
            afp[mt] = Af + ar * lda + lg * 8;
        } else {
            long a1 = ridx1 ? (long)ridx1[rg] : (long)rg;
            pA1h[mt] = A1h + a1 * lda + lg * 8;
            if constexpr (!LOWP) pA1l[mt] = A1l + a1 * lda + lg * 8;
            if constexpr (ASRC == 2) {
                long a2 = ridx2 ? (long)ridx2[rg] : (long)rg;
                pA2h[mt] = A2h + a2 * lda + lg * 8 - kpiv;
                pA2l[mt] = A2l + a2 * lda + lg * 8 - kpiv;
            }
        }
    }
    #pragma unroll
    for (int nt = 0; nt < 4; ++nt) {
        long bc = wn * 64 + nt * 16 + lr;
        pBh[nt] = Bhg + bc * ldw + lg * 8;
        if constexpr (!LOWP) pBl[nt] = Blg + bc * ldw + lg * 8;
    }

    struct Frags { bf16x8 ah[4], al[4], bh[4], bl[4]; };

    auto loadB = [&](Frags& f, int k) {
        #pragma unroll
        for (int nt = 0; nt < 4; ++nt) {
            f.bh[nt] = *(const bf16x8*)(pBh[nt] + k);
            if constexpr (!LOWP) f.bl[nt] = *(const bf16x8*)(pBl[nt] + k);
        }
    };
    auto loadA1 = [&](Frags& f, int k) {
        if constexpr (ASRC == 0) {
            #pragma unroll
            for (int mt = 0; mt < 4; ++mt) {
                float4 v0 = *(const float4*)(afp[mt] + k);
                float4 v1 = *(const float4*)(afp[mt] + k + 4);
                float vv[8] = {v0.x, v0.y, v0.z, v0.w, v1.x, v1.y, v1.z, v1.w};
                bf16x8 h8, l8;
                #pragma unroll
                for (int q = 0; q < 8; ++q) {
                    unsigned u = __builtin_bit_cast(unsigned, vv[q]);
                    unsigned hu = u & 0xFFFF0000u;               // truncation hi
                    h8[q] = (short)(hu >> 16);
                    float lo = vv[q] - __builtin_bit_cast(float, hu);
                    l8[q] = (short)f2bf(lo);                     // RNE lo
                }
                f.ah[mt] = h8;
                f.al[mt] = l8;
            }
        } else {
            #pragma unroll
            for (int mt = 0; mt < 4; ++mt) {
                f.ah[mt] = *(const bf16x8*)(pA1h[mt] + k);
                if constexpr (!LOWP) f.al[mt] = *(const bf16x8*)(pA1l[mt] + k);
            }
        }
    };
    auto loadA2 = [&](Frags& f, int k) {
        if constexpr (ASRC == 2) {
            #pragma unroll
            for (int mt = 0; mt < 4; ++mt) {
                f.ah[mt] = *(const bf16x8*)(pA2h[mt] + k);
                f.al[mt] = *(const bf16x8*)(pA2l[mt] + k);
            }
        }
    };

    f32x4 acc[4][4];
    #pragma unroll
    for (int i = 0; i < 4; ++i)
        #pragma unroll
        for (int j = 0; j < 4; ++j) acc[i][j] = (f32x4){0.f, 0.f, 0.f, 0.f};

    auto mfma_all = [&](const Frags& f) {
        #pragma unroll
        for (int mt = 0; mt < 4; ++mt)
            #pragma unroll
            for (int nt = 0; nt < 4; ++nt) {
                acc[mt][nt] = __builtin_amdgcn_mfma_f32_16x16x32_bf16(f.ah[mt], f.bh[nt], acc[mt][nt], 0, 0, 0);
                if constexpr (!LOWP) {
                    acc[mt][nt] = __builtin_amdgcn_mfma_f32_16x16x32_bf16(f.ah[mt], f.bl[nt], acc[mt][nt], 0, 0, 0);
                    acc[mt][nt] = __builtin_amdgcn_mfma_f32_16x16x32_bf16(f.al[mt], f.bh[nt], acc[mt][nt], 0, 0, 0);
                }
            }
    };

    // ---- 2-deep register-pipelined K loop (K % 64 == 0; kpiv % 64 == 0) ----
    Frags s0, s1;
    const int kend1 = (ASRC == 2) ? kpiv : K;
    loadA1(s0, 0); loadB(s0, 0);
    int k0 = 0;
    for (; k0 < kend1; k0 += 64) {
        loadA1(s1, k0 + 32); loadB(s1, k0 + 32);
        mfma_all(s0);
        int nk = k0 + 64;
        if (nk < K) {
            if constexpr (ASRC == 2) {
                if (nk < kend1) loadA1(s0, nk); else loadA2(s0, nk);
            } else {
                loadA1(s0, nk);
            }
            loadB(s0, nk);
        }
        mfma_all(s1);
    }
    if constexpr (ASRC == 2) {
        for (; k0 < K; k0 += 64) {
            loadA2(s1, k0 + 32); loadB(s1, k0 + 32);
            mfma_all(s0);
            int nk = k0 + 64;
            if (nk < K) { loadA2(s0, nk); loadB(s0, nk); }
            mfma_all(s1);
        }
    }

    // ---- epilogue ----
    if constexpr (WMODE == 2) {
        if (tid < BM) red[tid] = 0.f;
        __syncthreads();
        float bv[4], dwv[4];
        #pragma unroll
        for (int nt = 0; nt < 4; ++nt) {
            int colg = wn * 64 + nt * 16 + lr;
            bv[nt] = bias[colg];
            dwv[nt] = dw2[colg];
        }
        #pragma unroll
        for (int mt = 0; mt < 4; ++mt)
            #pragma unroll
            for (int j = 0; j < 4; ++j) {
                float p = 0.f;
                #pragma unroll
                for (int nt = 0; nt < 4; ++nt)
                    p += fmaxf(acc[mt][nt][j] + bv[nt], 0.f) * dwv[nt];
                p += __shfl_xor(p, 1);
                p += __shfl_xor(p, 2);
                p += __shfl_xor(p, 4);
                p += __shfl_xor(p, 8);
                if (lr == 0) atomicAdd(&red[wm * 64 + mt * 16 + lg * 4 + j], p);
            }
        __syncthreads();
        if (tid < BM) {
            int row = bm + tid;
            if (row < M) outv[row] = red[tid] + db2[0];
        }
    } else {
        float bv[4];
        int col[4];
        #pragma unroll
        for (int nt = 0; nt < 4; ++nt) {
            col[nt] = wn * 64 + nt * 16 + lr;
            bv[nt] = bias ? bias[col[nt]] : 0.f;
        }
        #pragma unroll
        for (int mt = 0; mt < 4; ++mt) {
            int row0 = bm + wm * 64 + mt * 16 + lg * 4;
            #pragma unroll
            for (int j = 0; j < 4; ++j) {
                int row = row0 + j;
                if (row >= M) continue;
                size_t rbase = (size_t)row * ldc;
                #pragma unroll
                for (int nt = 0; nt < 4; ++nt) {
                    size_t off = rbase + col[nt];
                    float v = acc[mt][nt][j] + bv[nt];
                    if (flags & FLAG_RELU) v = fmaxf(v, 0.f);
                    u16 hh, ll; split2(v, hh, ll);
                    Chi[off] = hh;
                    if constexpr (WMODE == 0) Clo[off] = ll;
                }
            }
        }
    }
}

// ---------------- CSR build (merged, sections A|B|C|D) ----------------
__global__ void count_all_kernel(const int* __restrict__ hks, const int* __restrict__ hkd,
                                 const int* __restrict__ hss, const int* __restrict__ hsd,
                                 int* __restrict__ deg)
{
    int e = blockIdx.x * blockDim.x + threadIdx.x;
    if (e < E_HK) {
        atomicAdd(deg + OFFA + hkd[e], 1);
        atomicAdd(deg + OFFC + hks[e], 1);
    } else if (e < E_HK + E_HS) {
        int i = e - E_HK;
        atomicAdd(deg + OFFB + hsd[i], 1);
        atomicAdd(deg + OFFD + hss[i], 1);
    }
}

__global__ void scan_block_kernel(const int* __restrict__ in, int* __restrict__ out,
                                  int* __restrict__ bsum, int n)
{
    __shared__ int tmp[256];
    int i = blockIdx.x * 256 + threadIdx.x;
    int v = (i < n) ? in[i] : 0;
    tmp[threadIdx.x] = v;
    __syncthreads();
    #pragma unroll
    for (int off = 1; off < 256; off <<= 1) {
        int t = (threadIdx.x >= off) ? tmp[threadIdx.x - off] : 0;
        __syncthreads();
        tmp[threadIdx.x] += t;
        __syncthreads();
    }
    if (i < n) out[i] = tmp[threadIdx.x] - v;
    if (threadIdx.x == 255 && bsum) bsum[blockIdx.x] = tmp[255];
}

__global__ void scan2_kernel(int* __restrict__ data, int n) // n <= 512, in-place exclusive
{
    __shared__ int tmp[512];
    int v = (threadIdx.x < n) ? data[threadIdx.x] : 0;
    tmp[threadIdx.x] = v;
    __syncthreads();
    #pragma unroll
    for (int off = 1; off < 512; off <<= 1) {
        int t = (threadIdx.x >= off) ? tmp[threadIdx.x - off] : 0;
        __syncthreads();
        tmp[threadIdx.x] += t;
        __syncthreads();
    }
    if (threadIdx.x < n) data[threadIdx.x] = tmp[threadIdx.x] - v;
}

__global__ void scan_add_kernel(int* __restrict__ out, const int* __restrict__ bsumex, int n)
{
    int i = blockIdx.x * 256 + threadIdx.x;
    if (i < n) out[i] += bsumex[blockIdx.x];
}

__global__ void fill_all_kernel(const int* __restrict__ hks, const int* __restrict__ hkd,
                                const int* __restrict__ hss, const int* __restrict__ hsd,
                                int* __restrict__ cur, u16* __restrict__ adj)
{
    int e = blockIdx.x * blockDim.x + threadIdx.x;
    if (e < E_HK) {
        int s = hks[e], d = hkd[e];
        int p = atomicAdd(cur + OFFA + d, 1); adj[p] = (u16)s;
        int q = atomicAdd(cur + OFFC + s, 1); adj[q] = (u16)d;
    } else if (e < E_HK + E_HS) {
        int i = e - E_HK;
        int s = hss[i], d = hsd[i];
        int p = atomicAdd(cur + OFFB + d, 1); adj[p] = (u16)s;
        int q = atomicAdd(cur + OFFD + s, 1); adj[q] = (u16)d;
    }
}

// ---------------- gather mean (hi-plane read, hi/lo write) ----------------
template <int D>
__global__ void gather_mean_kernel(const u16* __restrict__ Xhi,
                                   const int* __restrict__ cur, const int* __restrict__ deg,
                                   const u16* __restrict__ adj,
                                   u16* __restrict__ Ohi, u16* __restrict__ Olo, int ndst)
{
    constexpr int LANES = D / 4;
    constexpr int RPB = 256 / LANES;
    int r = blockIdx.x * RPB + threadIdx.x / LANES;
    if (r >= ndst) return;
    int lane = threadIdx.x % LANES;
    int end = cur[r];
    int n = deg[r];
    int j = end - n;
    float4 s = {0.f, 0.f, 0.f, 0.f};
    for (; j + 1 < end; j += 2) {
        int s0 = adj[j], s1 = adj[j + 1];
        ushort4 a = *(const ushort4*)(Xhi + (size_t)s0 * D + lane * 4);
        ushort4 b = *(const ushort4*)(Xhi + (size_t)s1 * D + lane * 4);
        s.x += bf2f(a.x) + bf2f(b.x); s.y += bf2f(a.y) + bf2f(b.y);
        s.z += bf2f(a.z) + bf2f(b.z); s.w += bf2f(a.w) + bf2f(b.w);
    }
    if (j < end) {
        ushort4 a = *(const ushort4*)(Xhi + (size_t)adj[j] * D + lane * 4);
        s.x += bf2f(a.x); s.y += bf2f(a.y); s.z += bf2f(a.z); s.w += bf2f(a.w);
    }
    float inv = (n > 0) ? 1.0f / (float)n : 0.f;
    s.x *= inv; s.y *= inv; s.z *= inv; s.w *= inv;
    size_t off = (size_t)r * D + lane * 4;
    ushort4 h, l;
    split2(s.x, h.x, l.x); split2(s.y, h.y, l.y); split2(s.z, h.z, l.z); split2(s.w, h.w, l.w);
    *(ushort4*)(Ohi + off) = h;
    *(ushort4*)(Olo + off) = l;
}

// ---------------- fused news assembly: N += meanC(PP) + meanD(PP2); [relu] ----------------
template <int D, bool RELU>
__global__ void fuse_news_kernel(const u16* __restrict__ PPh, const u16* __restrict__ PP2h,
                                 const int* __restrict__ curC, const int* __restrict__ degC,
                                 const int* __restrict__ curD, const int* __restrict__ degD,
                                 const u16* __restrict__ adj,
                                 u16* __restrict__ Nh, u16* __restrict__ Nl, int ndst)
{
    constexpr int LANES = D / 4;
    constexpr int RPB = 256 / LANES;
    int r = blockIdx.x * RPB + threadIdx.x / LANES;
    if (r >= ndst) return;
    int lane = threadIdx.x % LANES;
    float4 s = {0.f, 0.f, 0.f, 0.f};
    {
        int end = curC[r], n = degC[r];
        float4 a = {0.f, 0.f, 0.f, 0.f};
        for (int j = end - n; j < end; ++j) {
            ushort4 v = *(const ushort4*)(PPh + (size_t)adj[j] * D + lane * 4);
            a.x += bf2f(v.x); a.y += bf2f(v.y); a.z += bf2f(v.z); a.w += bf2f(v.w);
        }
        float inv = (n > 0) ? 1.0f / (float)n : 0.f;
        s.x += a.x * inv; s.y += a.y * inv; s.z += a.z * inv; s.w += a.w * inv;
    }
    {
        int end = curD[r], n = degD[r];
        float4 a = {0.f, 0.f, 0.f, 0.f};
        for (int j = end - n; j < end; ++j) {
            ushort4 v = *(const ushort4*)(PP2h + (size_t)adj[j] * D + lane * 4);
            a.x += bf2f(v.x); a.y += bf2f(v.y); a.z += bf2f(v.z); a.w += bf2f(v.w);
        }
        float inv = (n > 0) ? 1.0f / (float)n : 0.f;
        s.x += a.x * inv; s.y += a.y * inv; s.z += a.z * inv; s.w += a.w * inv;
    }
    size_t off = (size_t)r * D + lane * 4;
    ushort4 h = *(const ushort4*)(Nh + off);
    ushort4 l = *(const ushort4*)(Nl + off);
    s.x += bf2f(h.x) + bf2f(l.x); s.y += bf2f(h.y) + bf2f(l.y);
    s.z += bf2f(h.z) + bf2f(l.z); s.w += bf2f(h.w) + bf2f(l.w);
    if (RELU) {
        s.x = fmaxf(s.x, 0.f); s.y = fmaxf(s.y, 0.f);
        s.z = fmaxf(s.z, 0.f); s.w = fmaxf(s.w, 0.f);
    }
    ushort4 oh, ol;
    split2(s.x, oh.x, ol.x); split2(s.y, oh.y, ol.y); split2(s.z, oh.z, ol.z); split2(s.w, oh.w, ol.w);
    *(ushort4*)(Nh + off) = oh;
    *(ushort4*)(Nl + off) = ol;
}

// ---------------- batched weight split/convert ----------------
#define MAXJOBS 20
struct SplitJobs {
    const float* a[MAXJOBS];
    const float* b[MAXJOBS];     // optional second operand (summed)
    u16* hi[MAXJOBS];
    u16* lo[MAXJOBS];
    int n[MAXJOBS];
    int ncols[MAXJOBS];          // source row width
    int dstride[MAXJOBS];        // dest row stride
    int boff[MAXJOBS + 1];
    int njobs;
};

__global__ void split_all_kernel(SplitJobs J)
{
    int bid = blockIdx.x;
    int j = 0;
    while (j + 1 < J.njobs && bid >= J.boff[j + 1]) ++j;
    int i = (bid - J.boff[j]) * 1024 + threadIdx.x * 4;
    if (i >= J.n[j]) return;
    float4 v = *(const float4*)(J.a[j] + i);
    if (J.b[j]) {
        float4 w = *(const float4*)(J.b[j] + i);
        v.x += w.x; v.y += w.y; v.z += w.z; v.w += w.w;
    }
    int row = i / J.ncols[j], col = i - row * J.ncols[j];
    size_t d = (size_t)row * J.dstride[j] + col;
    ushort4 h, l;
    split2(v.x, h.x, l.x); split2(v.y, h.y, l.y); split2(v.z, h.z, l.z); split2(v.w, h.w, l.w);
    *(ushort4*)(J.hi[j] + d) = h;
    *(ushort4*)(J.lo[j] + d) = l;
}

__global__ void bias_sum_kernel(const float* __restrict__ b1, const float* __restrict__ b2,
                                float* __restrict__ BS1, float* __restrict__ BS2)
{
    int i = blockIdx.x * 256 + threadIdx.x;
    if (i < 256) BS1[i] = b1[256 + i] + b1[768 + i];
    else if (i < 384) { int j = i - 256; BS2[j] = b2[128 + j] + b2[384 + j]; }
}

// ---------------- launch ----------------
extern "C" void kernel_launch(void* const* d_in, const int* in_sizes, int n_in,
                              void* d_out, int out_size, void* d_ws, size_t ws_size,
                              hipStream_t stream)
{
    const float* x_news = (const float*)d_in[0];
    const float* x_kw   = (const float*)d_in[1];
    const float* x_st   = (const float*)d_in[2];
    const float* Wn = (const float*)d_in[3];  const float* bn = (const float*)d_in[4];
    const float* Wk = (const float*)d_in[5];  const float* bk = (const float*)d_in[6];
    const float* Wst = (const float*)d_in[7]; const float* bs = (const float*)d_in[8];
    const float* W1l = (const float*)d_in[9];  const float* b1 = (const float*)d_in[10];
    const float* W1r = (const float*)d_in[11];
    const float* W2l = (const float*)d_in[12]; const float* b2 = (const float*)d_in[13];
    const float* W2r = (const float*)d_in[14];
    const float* DW1 = (const float*)d_in[15]; const float* Db1 = (const float*)d_in[16];
    const float* DW2 = (const float*)d_in[17]; const float* Db2 = (const float*)d_in[18];
    const int* e_hk_src = (const int*)d_in[19];
    const int* e_hk_dst = (const int*)d_in[20];
    const int* e_hs_src = (const int*)d_in[21];
    const int* e_hs_dst = (const int*)d_in[22];
    const int* l_hk_src = (const int*)d_in[23];
    const int* l_hk_dst = (const int*)d_in[24];
    const int* l_hs_src = (const int*)d_in[25];
    const int* l_hs_dst = (const int*)d_in[26];
    float* out = (float*)d_out;

    // ---- workspace layout (bytes, 16B aligned) ----
    char* base = (char*)d_ws;
    auto alloc = [&](size_t bytes) -> char* {
        char* p = base;
        base += (bytes + 15) & ~(size_t)15;
        return p;
    };
    auto aplane = [&](size_t elems) -> u16* { return (u16*)alloc(elems * 2); };

    u16* HNh = aplane((size_t)N_NEWS * HID);  u16* HNl = aplane((size_t)N_NEWS * HID);
    u16* HKh = aplane((size_t)N_KW * HID);    u16* HKl = aplane((size_t)N_KW * HID);
    u16* HSh = aplane((size_t)N_ST * HID);    u16* HSl = aplane((size_t)N_ST * HID);
    u16* K1h = aplane((size_t)N_KW * HID);    u16* K1l = aplane((size_t)N_KW * HID);
    u16* S1h = aplane((size_t)N_ST * HID);    u16* S1l = aplane((size_t)N_ST * HID);
    u16* PAh = aplane((size_t)N_KW * HID);    u16* PAl = aplane((size_t)N_KW * HID);
    u16* N1h = aplane((size_t)N_NEWS * HID);  u16* N1l = aplane((size_t)N_NEWS * HID);
    // weight planes
    u16* WnH = aplane(196608);  u16* WnL = aplane(196608);
    u16* WkH = aplane(32768);   u16* WkL = aplane(32768);
    u16* WsH = aplane(16384);   u16* WsL = aplane(16384);
    u16* CW1KH = aplane(131072); u16* CW1KL = aplane(131072);  // [256][512] W1l0|W1r0
    u16* CW1SH = aplane(131072); u16* CW1SL = aplane(131072);  // [256][512] W1l2|W1r2
    u16* W1l1H = aplane(65536);  u16* W1l1L = aplane(65536);
    u16* W1l3H = aplane(65536);  u16* W1l3L = aplane(65536);
    u16* SW1H = aplane(65536);   u16* SW1L = aplane(65536);    // W1r1+W1r3
    u16* CW2KH = aplane(65536);  u16* CW2KL = aplane(65536);   // [128][512] W2l0|W2r0
    u16* CW2SH = aplane(65536);  u16* CW2SL = aplane(65536);   // [128][512] W2l2|W2r2
    u16* W2l1H = aplane(32768);  u16* W2l1L = aplane(32768);
    u16* W2l3H = aplane(32768);  u16* W2l3L = aplane(32768);
    u16* SW2H = aplane(32768);   u16* SW2L = aplane(32768);    // W2r1+W2r3
    u16* DW1H = aplane(65536);   u16* DW1L = aplane(65536);
    float* BS1 = (float*)alloc(256 * 4);
    float* BS2 = (float*)alloc(128 * 4);
    // int pools
    int* deg = (int*)alloc((size_t)NTOT * 4);
    int* cur = (int*)alloc((size_t)NTOT * 4);
    u16* adj = (u16*)alloc((size_t)2 * (E_HK + E_HS) * 2);
    int* bsum = (int*)alloc(512 * 4);

    // overlays: layer-2 outputs reuse the HN region (dead after layer 1)
    u16* K2h = HNh;
    u16* K2l = K2h + (size_t)N_KW * OUTD;
    u16* N2h = K2l + (size_t)N_KW * OUTD;
    u16* N2l = N2h + (size_t)N_NEWS * OUTD;
    u16* S2h = N2l + (size_t)N_NEWS * OUTD;
    u16* S2l = S2h + (size_t)N_ST * OUTD;

    // ---- CSR build ----
    hipMemsetAsync(deg, 0, (size_t)NTOT * sizeof(int), stream);
    int etot = E_HK + E_HS;
    count_all_kernel<<<(etot + 255) / 256, 256, 0, stream>>>(e_hk_src, e_hk_dst, e_hs_src, e_hs_dst, deg);
    int nb = (NTOT + 255) / 256; // 438
    scan_block_kernel<<<nb, 256, 0, stream>>>(deg, cur, bsum, NTOT);
    scan2_kernel<<<1, 512, 0, stream>>>(bsum, nb);
    scan_add_kernel<<<nb, 256, 0, stream>>>(cur, bsum, NTOT);
    fill_all_kernel<<<(etot + 255) / 256, 256, 0, stream>>>(e_hk_src, e_hk_dst, e_hs_src, e_hs_dst, cur, adj);

    // ---- batched weight conversion ----
    {
        SplitJobs J{};
        int nj = 0, blocks = 0;
        auto job = [&](const float* a, const float* b, u16* hi, u16* lo, int n, int ncols, int dstride) {
            J.a[nj] = a; J.b[nj] = b; J.hi[nj] = hi; J.lo[nj] = lo;
            J.n[nj] = n; J.ncols[nj] = ncols; J.dstride[nj] = dstride;
            J.boff[nj] = blocks;
            blocks += (n / 4 + 255) / 256;
            ++nj;
        };
        job(Wn, nullptr, WnH, WnL, 196608, 196608, 196608);
        job(Wk, nullptr, WkH, WkL, 32768, 32768, 32768);
        job(Wst, nullptr, WsH, WsL, 16384, 16384, 16384);
        job(W1l + 0 * 65536, nullptr, CW1KH, CW1KL, 65536, 256, 512);
        job(W1r + 0 * 65536, nullptr, CW1KH + 256, CW1KL + 256, 65536, 256, 512);
        job(W1l + 2 * 65536, nullptr, CW1SH, CW1SL, 65536, 256, 512);
        job(W1r + 2 * 65536, nullptr, CW1SH + 256, CW1SL + 256, 65536, 256, 512);
        job(W1l + 1 * 65536, nullptr, W1l1H, W1l1L, 65536, 65536, 65536);
        job(W1l + 3 * 65536, nullptr, W1l3H, W1l3L, 65536, 65536, 65536);
        job(W1r + 1 * 65536, W1r + 3 * 65536, SW1H, SW1L, 65536, 65536, 65536);
        job(W2l + 0 * 32768, nullptr, CW2KH, CW2KL, 32768, 256, 512);
        job(W2r + 0 * 32768, nullptr, CW2KH + 256, CW2KL + 256, 32768, 256, 512);
        job(W2l + 2 * 32768, nullptr, CW2SH, CW2SL, 32768, 256, 512);
        job(W2r + 2 * 32768, nullptr, CW2SH + 256, CW2SL + 256, 32768, 256, 512);
        job(W2l + 1 * 32768, nullptr, W2l1H, W2l1L, 32768, 32768, 32768);
        job(W2l + 3 * 32768, nullptr, W2l3H, W2l3L, 32768, 32768, 32768);
        job(W2r + 1 * 32768, W2r + 3 * 32768, SW2H, SW2L, 32768, 32768, 32768);
        job(DW1, nullptr, DW1H, DW1L, 65536, 65536, 65536);
        J.boff[nj] = blocks;
        J.njobs = nj;
        split_all_kernel<<<blocks, 256, 0, stream>>>(J);
    }
    bias_sum_kernel<<<2, 256, 0, stream>>>(b1, b2, BS1, BS2);

    // ---- GEMM wrappers (grid.y == 1 always; block covers full N) ----
    auto gemmF = [&](const float* A, int lda, const u16* Bh, const u16* Bl, int ldw,
                     const float* bias, u16* Ch, u16* Cl, int ldc,
                     int M, int K, int flags) {
        gemm_kernel<0, 0, false, 0><<<(M + 63) / 64, 256, 0, stream>>>(
            A, nullptr, nullptr, nullptr, nullptr, nullptr, nullptr, lda, 0,
            Bh, Bl, ldw, bias, Ch, Cl, ldc, nullptr, nullptr, nullptr, M, K, flags);
    };
    auto gemmP256 = [&](const u16* Ahp, const u16* Alp, int lda, const u16* Bh, const u16* Bl, int ldw,
                        const float* bias, u16* Ch, u16* Cl, int ldc,
                        int M, int K, int flags) {
        gemm_kernel<1, 0, false, 0><<<(M + 63) / 64, 256, 0, stream>>>(
            nullptr, Ahp, Alp, nullptr, nullptr, nullptr, nullptr, lda, 0,
            Bh, Bl, ldw, bias, Ch, Cl, ldc, nullptr, nullptr, nullptr, M, K, flags);
    };
    auto gemmP128 = [&](const u16* Ahp, const u16* Alp, int lda, const u16* Bh, const u16* Bl, int ldw,
                        const float* bias, u16* Ch, u16* Cl, int ldc,
                        int M, int K, int flags) {
        gemm_kernel<1, 0, false, 1><<<(M + 127) / 128, 256, 0, stream>>>(
            nullptr, Ahp, Alp, nullptr, nullptr, nullptr, nullptr, lda, 0,
            Bh, Bl, ldw, bias, Ch, Cl, ldc, nullptr, nullptr, nullptr, M, K, flags);
    };
    auto gemm2_256 = [&](const u16* A1hp, const u16* A1lp, const u16* A2hp, const u16* A2lp,
                         int lda, int kpiv, const u16* Bh, const u16* Bl, int ldw,
                         const float* bias, u16* Ch, u16* Cl, int ldc,
                         int M, int K, int flags) {
        gemm_kernel<2, 0, false, 0><<<(M + 63) / 64, 256, 0, stream>>>(
            nullptr, A1hp, A1lp, A2hp, A2lp, nullptr, nullptr, lda, kpiv,
            Bh, Bl, ldw, bias, Ch, Cl, ldc, nullptr, nullptr, nullptr, M, K, flags);
    };
    auto gemm2_128 = [&](const u16* A1hp, const u16* A1lp, const u16* A2hp, const u16* A2lp,
                         int lda, int kpiv, const u16* Bh, const u16* Bl, int ldw,
                         const float* bias, u16* Ch, u16* Cl, int ldc,
                         int M, int K, int flags) {
        gemm_kernel<2, 0, false, 1><<<(M + 127) / 128, 256, 0, stream>>>(
            nullptr, A1hp, A1lp, A2hp, A2lp, nullptr, nullptr, lda, kpiv,
            Bh, Bl, ldw, bias, Ch, Cl, ldc, nullptr, nullptr, nullptr, M, K, flags);
    };
    auto gemmLP256 = [&](const u16* Ahp, int lda, const u16* Bh, int ldw,
                         u16* Ch, int ldc, int M, int K) {
        gemm_kernel<1, 1, true, 0><<<(M + 63) / 64, 256, 0, stream>>>(
            nullptr, Ahp, nullptr, nullptr, nullptr, nullptr, nullptr, lda, 0,
            Bh, nullptr, ldw, nullptr, Ch, nullptr, ldc, nullptr, nullptr, nullptr, M, K, 0);
    };
    auto gemmLP128 = [&](const u16* Ahp, int lda, const u16* Bh, int ldw,
                         u16* Ch, int ldc, int M, int K) {
        gemm_kernel<1, 1, true, 1><<<(M + 127) / 128, 256, 0, stream>>>(
            nullptr, Ahp, nullptr, nullptr, nullptr, nullptr, nullptr, lda, 0,
            Bh, nullptr, ldw, nullptr, Ch, nullptr, ldc, nullptr, nullptr, nullptr, M, K, 0);
    };
    auto gemmD = [&](const u16* A1hp, const u16* A1lp, const u16* A2hp, const u16* A2lp,
                     const int* r1, const int* r2,
                     const u16* Bh, const u16* Bl,
                     const float* bias, const float* dw2, const float* db2, float* ov) {
        gemm_kernel<2, 2, false, 1><<<(E_LBL + 127) / 128, 256, 0, stream>>>(
            nullptr, A1hp, A1lp, A2hp, A2lp, r1, r2, 128, 128,
            Bh, Bl, 256, bias, nullptr, nullptr, 0, dw2, db2, ov, E_LBL, 256, 0);
    };

    // ---- input projections ----
    gemmF(x_news, F_NEWS, WnH, WnL, F_NEWS, bn, HNh, HNl, HID, N_NEWS, F_NEWS, FLAG_RELU);
    gemmF(x_kw,   F_KW,   WkH, WkL, F_KW,   bk, HKh, HKl, HID, N_KW,   F_KW,   FLAG_RELU);
    gemmF(x_st,   F_ST,   WsH, WsL, F_ST,   bs, HSh, HSl, HID, N_ST,   F_ST,   FLAG_RELU);

    // ---- layer 1 ----
    // k1 = relu([mean_A(hn) | hk] @ [W1l0|W1r0]^T + b1[0])
    gather_mean_kernel<256><<<(N_KW + 3) / 4, 256, 0, stream>>>(HNh, cur + OFFA, deg + OFFA, adj, PAh, PAl, N_KW);
    gemm2_256(PAh, PAl, HKh, HKl, HID, 256, CW1KH, CW1KL, 512, b1, K1h, K1l, HID, N_KW, 512, FLAG_RELU);
    // s1
    gather_mean_kernel<256><<<(N_ST + 3) / 4, 256, 0, stream>>>(HNh, cur + OFFB, deg + OFFB, adj, PAh, PAl, N_ST);
    gemm2_256(PAh, PAl, HSh, HSl, HID, 256, CW1SH, CW1SL, 512, b1 + 2 * 256, S1h, S1l, HID, N_ST, 512, FLAG_RELU);
    // n1: project small sources (hi-only), r-term GEMM, fused gather-assembly
    gemmLP256(HKh, HID, W1l1H, HID, PAh, HID, N_KW, HID);   // PP
    gemmLP256(HSh, HID, W1l3H, HID, PAl, HID, N_ST, HID);   // PP2
    gemmP256(HNh, HNl, HID, SW1H, SW1L, HID, BS1, N1h, N1l, HID, N_NEWS, HID, 0);
    fuse_news_kernel<256, true><<<(N_NEWS + 3) / 4, 256, 0, stream>>>(
        PAh, PAl, cur + OFFC, deg + OFFC, cur + OFFD, deg + OFFD, adj, N1h, N1l, N_NEWS);

    // ---- layer 2 ----
    gather_mean_kernel<256><<<(N_KW + 3) / 4, 256, 0, stream>>>(N1h, cur + OFFA, deg + OFFA, adj, PAh, PAl, N_KW);
    gemm2_128(PAh, PAl, K1h, K1l, HID, 256, CW2KH, CW2KL, 512, b2, K2h, K2l, OUTD, N_KW, 512, 0);
    gather_mean_kernel<256><<<(N_ST + 3) / 4, 256, 0, stream>>>(N1h, cur + OFFB, deg + OFFB, adj, PAh, PAl, N_ST);
    gemm2_128(PAh, PAl, S1h, S1l, HID, 256, CW2SH, CW2SL, 512, b2 + 2 * 128, S2h, S2l, OUTD, N_ST, 512, 0);
    gemmLP128(K1h, HID, W2l1H, HID, PAh, OUTD, N_KW, HID);  // PP (n2)
    gemmLP128(S1h, HID, W2l3H, HID, PAl, OUTD, N_ST, HID);  // PP2 (n2)
    gemmP128(N1h, N1l, HID, SW2H, SW2L, HID, BS2, N2h, N2l, OUTD, N_NEWS, HID, 0);
    fuse_news_kernel<128, false><<<(N_NEWS + 7) / 8, 256, 0, stream>>>(
        PAh, PAl, cur + OFFC, deg + OFFC, cur + OFFD, deg + OFFD, adj, N2h, N2l, N_NEWS);

    // ---- fused decoders ----
    gemmD(N2h, N2l, K2h, K2l, l_hk_src, l_hk_dst, DW1H, DW1L, Db1, DW2, Db2, out);
    gemmD(N2h, N2l, S2h, S2l, l_hs_src, l_hs_dst, DW1H + 32768, DW1L + 32768,
          Db1 + 128, DW2 + 128, Db2 + 1, out + E_LBL);
}

// Round 8
// 1053.708 us; speedup vs baseline: 1.1952x; 1.1952x over previous
//
#include <hip/hip_runtime.h>
#include <hip/hip_bf16.h>

// ---------------- problem constants ----------------
constexpr int N_NEWS = 50000, N_KW = 10000, N_ST = 2000;
constexpr int F_NEWS = 768, F_KW = 128, F_ST = 64;
constexpr int HID = 256, OUTD = 128;
constexpr int E_HK = 500000, E_HS = 250000, E_LBL = 150000;

// CSR section offsets in the concatenated degree/cursor pools
constexpr int OFFA = 0;                    // e_hk keyed by dst (kw)
constexpr int OFFB = N_KW;                 // e_hs keyed by dst (st)
constexpr int OFFC = N_KW + N_ST;          // e_hk keyed by src (news)
constexpr int OFFD = OFFC + N_NEWS;        // e_hs keyed by src (news)
constexpr int NTOT = OFFD + N_NEWS;        // 112000

enum { FLAG_ACC = 1, FLAG_RELU = 2 };

typedef unsigned short u16;
typedef __attribute__((ext_vector_type(8))) short bf16x8;
typedef __attribute__((ext_vector_type(8))) unsigned short u16x8;
typedef __attribute__((ext_vector_type(4))) float f32x4;

__device__ __forceinline__ u16 f2bf(float x) {
    return __builtin_bit_cast(u16, __float2bfloat16(x));
}
__device__ __forceinline__ float bf2f(u16 h) {
    unsigned u = ((unsigned)h) << 16;
    return __builtin_bit_cast(float, u);
}
__device__ __forceinline__ void split2(float x, u16& h, u16& l) {
    h = f2bf(x);
    l = f2bf(x - bf2f(h));
}

// ---------------- hybrid split-bf16 MFMA GEMM ----------------
// A staged in LDS (coalesced global reads, XOR-swizzled, register-prefetched).
// B fragments read DIRECTLY from global (weights are small + L2-resident),
// with one-K-step register prefetch -> LDS traffic halved vs full staging.
// tile 128x128, BK=32, 4 waves (2x2). 3 MFMA/product; LOWP: 1 (hi only).
// ASRC: 0 = fp32 A (hi/lo split in regs), 1 = plane A, 2 = dual-table plane A
// WMODE: 0 = write hi+lo planes, 1 = hi only, 2 = fused decoder reduce -> outv
template<int ASRC, int WMODE, bool LOWP>
__global__ __launch_bounds__(256) void gemm_kernel(
    const float* __restrict__ Af,
    const u16* __restrict__ A1h, const u16* __restrict__ A1l,
    const u16* __restrict__ A2h, const u16* __restrict__ A2l,
    const int* __restrict__ ridx1, const int* __restrict__ ridx2, int lda, int kpiv,
    const u16* __restrict__ Bhg, const u16* __restrict__ Blg, int ldw,
    const float* __restrict__ bias,
    u16* __restrict__ Chi, u16* __restrict__ Clo, int ldc,
    const float* __restrict__ dw2, const float* __restrict__ db2,
    float* __restrict__ outv,
    int M, int K, int flags)
{
    __shared__ u16 Ah[128 * 32];
    __shared__ u16 Al[128 * 32];
    __shared__ float red[128];

    const int tid = threadIdx.x;
    const int bm = blockIdx.x * 128;
    const int bn = blockIdx.y * 128;
    const int l = tid & 63;
    const int w = tid >> 6;
    const int wm = w >> 1, wn = w & 1;
    const int lg = l >> 4, lr = l & 15;

    // ---- A staging pointers: 2 chunks/thread, chunk g -> row g>>2, col8 (g&3)*8 ----
    const float* pAf[2];
    const u16 *pA1h[2], *pA1l[2], *pA2h[2], *pA2l[2];
    int usw[2];
    #pragma unroll
    for (int p = 0; p < 2; ++p) {
        int g = tid + p * 256;
        int row = g >> 2, c8 = (g & 3) * 8;
        usw[p] = (row * 32 + c8) ^ ((row & 7) << 3);
        int rg = bm + row; if (rg > M - 1) rg = M - 1;
        if constexpr (ASRC == 0) {
            long ar = ridx1 ? (long)ridx1[rg] : (long)rg;
            pAf[p] = Af + ar * lda + c8;
        } else {
            long a1 = ridx1 ? (long)ridx1[rg] : (long)rg;
            pA1h[p] = A1h + a1 * lda + c8;
            if constexpr (!LOWP) pA1l[p] = A1l + a1 * lda + c8;
            if constexpr (ASRC == 2) {
                long a2 = ridx2 ? (long)ridx2[rg] : (long)rg;
                pA2h[p] = A2h + a2 * lda + c8 - kpiv;
                pA2l[p] = A2l + a2 * lda + c8 - kpiv;
            }
        }
    }

    // ---- B fragment pointers (direct global) ----
    const u16 *pBh[4], *pBl[4];
    #pragma unroll
    for (int nt = 0; nt < 4; ++nt) {
        long bc = bn + wn * 64 + nt * 16 + lr;
        pBh[nt] = Bhg + bc * ldw + lg * 8;
        if constexpr (!LOWP) pBl[nt] = Blg + bc * ldw + lg * 8;
    }

    // ---- A register staging (single set; lifetime = load -> STOREA) ----
    float4 va[2][2];
    u16x8 rah[2], ral[2];
    auto LOADA = [&](int k0) {
        #pragma unroll
        for (int p = 0; p < 2; ++p) {
            if constexpr (ASRC == 0) {
                va[p][0] = ((const float4*)(pAf[p] + k0))[0];
                va[p][1] = ((const float4*)(pAf[p] + k0))[1];
            } else if constexpr (ASRC == 1) {
                rah[p] = *(const u16x8*)(pA1h[p] + k0);
                if constexpr (!LOWP) ral[p] = *(const u16x8*)(pA1l[p] + k0);
            } else {
                bool first = k0 < kpiv;
                const u16* ph = first ? pA1h[p] + k0 : pA2h[p] + k0;
                const u16* pl = first ? pA1l[p] + k0 : pA2l[p] + k0;
                rah[p] = *(const u16x8*)ph;
                ral[p] = *(const u16x8*)pl;
            }
        }
    };
    auto STOREA = [&]() {
        #pragma unroll
        for (int p = 0; p < 2; ++p) {
            if constexpr (ASRC == 0) {
                float vv[8] = {va[p][0].x, va[p][0].y, va[p][0].z, va[p][0].w,
                               va[p][1].x, va[p][1].y, va[p][1].z, va[p][1].w};
                u16x8 h8, l8;
                #pragma unroll
                for (int q = 0; q < 8; ++q) { u16 hh, ll; split2(vv[q], hh, ll); h8[q] = hh; l8[q] = ll; }
                *(u16x8*)&Ah[usw[p]] = h8;
                *(u16x8*)&Al[usw[p]] = l8;
            } else {
                *(u16x8*)&Ah[usw[p]] = rah[p];
                if constexpr (!LOWP) *(u16x8*)&Al[usw[p]] = ral[p];
            }
        }
    };

    struct BF { bf16x8 bh[4], bl[4]; };
    auto LOADB = [&](BF& f, int k) {
        #pragma unroll
        for (int nt = 0; nt < 4; ++nt) {
            f.bh[nt] = *(const bf16x8*)(pBh[nt] + k);
            if constexpr (!LOWP) f.bl[nt] = *(const bf16x8*)(pBl[nt] + k);
        }
    };

    f32x4 acc[4][4];
    #pragma unroll
    for (int i = 0; i < 4; ++i)
        #pragma unroll
        for (int j = 0; j < 4; ++j) acc[i][j] = (f32x4){0.f, 0.f, 0.f, 0.f};

    auto MFMA = [&](const BF& fb) {
        bf16x8 fah[4], fal[4];
        #pragma unroll
        for (int mt = 0; mt < 4; ++mt) {
            int r = wm * 64 + mt * 16 + lr;
            int us = (r * 32 + lg * 8) ^ ((r & 7) << 3);
            fah[mt] = *(const bf16x8*)&Ah[us];
            if constexpr (!LOWP) fal[mt] = *(const bf16x8*)&Al[us];
        }
        #pragma unroll
        for (int mt = 0; mt < 4; ++mt)
            #pragma unroll
            for (int nt = 0; nt < 4; ++nt) {
                acc[mt][nt] = __builtin_amdgcn_mfma_f32_16x16x32_bf16(fah[mt], fb.bh[nt], acc[mt][nt], 0, 0, 0);
                if constexpr (!LOWP) {
                    acc[mt][nt] = __builtin_amdgcn_mfma_f32_16x16x32_bf16(fah[mt], fb.bl[nt], acc[mt][nt], 0, 0, 0);
                    acc[mt][nt] = __builtin_amdgcn_mfma_f32_16x16x32_bf16(fal[mt], fb.bh[nt], acc[mt][nt], 0, 0, 0);
                }
            }
    };

    // ---- pipelined K loop (K % 64 == 0; kpiv % 64 == 0) ----
    BF fb0, fb1;
    LOADA(0);
    LOADB(fb0, 0);
    for (int k0 = 0; k0 < K; k0 += 64) {
        __syncthreads();
        STOREA();                       // tile k0
        __syncthreads();
        LOADA(k0 + 32);                 // prefetch A (always valid: k0+32 <= K-32)
        LOADB(fb1, k0 + 32);            // prefetch B
        MFMA(fb0);                      // compute k0 (hides prefetch latency)
        __syncthreads();
        STOREA();                       // tile k0+32
        __syncthreads();
        if (k0 + 64 < K) { LOADA(k0 + 64); LOADB(fb0, k0 + 64); }
        MFMA(fb1);                      // compute k0+32
    }

    // ---- epilogue ----
    if constexpr (WMODE == 2) {
        if (tid < 128) red[tid] = 0.f;
        __syncthreads();
        float bv[4], dwv[4];
        #pragma unroll
        for (int nt = 0; nt < 4; ++nt) {
            int colg = wn * 64 + nt * 16 + lr;
            bv[nt] = bias[colg];
            dwv[nt] = dw2[colg];
        }
        #pragma unroll
        for (int mt = 0; mt < 4; ++mt)
            #pragma unroll
            for (int j = 0; j < 4; ++j) {
                float p = 0.f;
                #pragma unroll
                for (int nt = 0; nt < 4; ++nt)
                    p += fmaxf(acc[mt][nt][j] + bv[nt], 0.f) * dwv[nt];
                p += __shfl_xor(p, 1);
                p += __shfl_xor(p, 2);
                p += __shfl_xor(p, 4);
                p += __shfl_xor(p, 8);
                if (lr == 0) atomicAdd(&red[wm * 64 + mt * 16 + lg * 4 + j], p);
            }
        __syncthreads();
        if (tid < 128) {
            int row = bm + tid;
            if (row < M) outv[row] = red[tid] + db2[0];
        }
    } else {
        float bv[4];
        int col[4];
        #pragma unroll
        for (int nt = 0; nt < 4; ++nt) {
            col[nt] = bn + wn * 64 + nt * 16 + lr;
            bv[nt] = bias ? bias[col[nt]] : 0.f;
        }
        #pragma unroll
        for (int mt = 0; mt < 4; ++mt) {
            int row0 = bm + wm * 64 + mt * 16 + lg * 4;
            #pragma unroll
            for (int j = 0; j < 4; ++j) {
                int row = row0 + j;
                if (row >= M) continue;
                size_t rbase = (size_t)row * ldc;
                #pragma unroll
                for (int nt = 0; nt < 4; ++nt) {
                    size_t off = rbase + col[nt];
                    float v = acc[mt][nt][j] + bv[nt];
                    if (flags & FLAG_RELU) v = fmaxf(v, 0.f);
                    u16 hh, ll; split2(v, hh, ll);
                    Chi[off] = hh;
                    if constexpr (WMODE == 0) Clo[off] = ll;
                }
            }
        }
    }
}

// ---------------- CSR build (merged, sections A|B|C|D) ----------------
__global__ void count_all_kernel(const int* __restrict__ hks, const int* __restrict__ hkd,
                                 const int* __restrict__ hss, const int* __restrict__ hsd,
                                 int* __restrict__ deg)
{
    int e = blockIdx.x * blockDim.x + threadIdx.x;
    if (e < E_HK) {
        atomicAdd(deg + OFFA + hkd[e], 1);
        atomicAdd(deg + OFFC + hks[e], 1);
    } else if (e < E_HK + E_HS) {
        int i = e - E_HK;
        atomicAdd(deg + OFFB + hsd[i], 1);
        atomicAdd(deg + OFFD + hss[i], 1);
    }
}

__global__ void scan_block_kernel(const int* __restrict__ in, int* __restrict__ out,
                                  int* __restrict__ bsum, int n)
{
    __shared__ int tmp[256];
    int i = blockIdx.x * 256 + threadIdx.x;
    int v = (i < n) ? in[i] : 0;
    tmp[threadIdx.x] = v;
    __syncthreads();
    #pragma unroll
    for (int off = 1; off < 256; off <<= 1) {
        int t = (threadIdx.x >= off) ? tmp[threadIdx.x - off] : 0;
        __syncthreads();
        tmp[threadIdx.x] += t;
        __syncthreads();
    }
    if (i < n) out[i] = tmp[threadIdx.x] - v;
    if (threadIdx.x == 255 && bsum) bsum[blockIdx.x] = tmp[255];
}

__global__ void scan2_kernel(int* __restrict__ data, int n) // n <= 512, in-place exclusive
{
    __shared__ int tmp[512];
    int v = (threadIdx.x < n) ? data[threadIdx.x] : 0;
    tmp[threadIdx.x] = v;
    __syncthreads();
    #pragma unroll
    for (int off = 1; off < 512; off <<= 1) {
        int t = (threadIdx.x >= off) ? tmp[threadIdx.x - off] : 0;
        __syncthreads();
        tmp[threadIdx.x] += t;
        __syncthreads();
    }
    if (threadIdx.x < n) data[threadIdx.x] = tmp[threadIdx.x] - v;
}

__global__ void scan_add_kernel(int* __restrict__ out, const int* __restrict__ bsumex, int n)
{
    int i = blockIdx.x * 256 + threadIdx.x;
    if (i < n) out[i] += bsumex[blockIdx.x];
}

__global__ void fill_all_kernel(const int* __restrict__ hks, const int* __restrict__ hkd,
                                const int* __restrict__ hss, const int* __restrict__ hsd,
                                int* __restrict__ cur, u16* __restrict__ adj)
{
    int e = blockIdx.x * blockDim.x + threadIdx.x;
    if (e < E_HK) {
        int s = hks[e], d = hkd[e];
        int p = atomicAdd(cur + OFFA + d, 1); adj[p] = (u16)s;
        int q = atomicAdd(cur + OFFC + s, 1); adj[q] = (u16)d;
    } else if (e < E_HK + E_HS) {
        int i = e - E_HK;
        int s = hss[i], d = hsd[i];
        int p = atomicAdd(cur + OFFB + d, 1); adj[p] = (u16)s;
        int q = atomicAdd(cur + OFFD + s, 1); adj[q] = (u16)d;
    }
}

// ---------------- gather mean (hi-plane read, hi/lo write) ----------------
template <int D>
__global__ void gather_mean_kernel(const u16* __restrict__ Xhi,
                                   const int* __restrict__ cur, const int* __restrict__ deg,
                                   const u16* __restrict__ adj,
                                   u16* __restrict__ Ohi, u16* __restrict__ Olo, int ndst)
{
    constexpr int LANES = D / 4;
    constexpr int RPB = 256 / LANES;
    int r = blockIdx.x * RPB + threadIdx.x / LANES;
    if (r >= ndst) return;
    int lane = threadIdx.x % LANES;
    int end = cur[r];
    int n = deg[r];
    int j = end - n;
    float4 s = {0.f, 0.f, 0.f, 0.f};
    for (; j + 1 < end; j += 2) {
        int s0 = adj[j], s1 = adj[j + 1];
        ushort4 a = *(const ushort4*)(Xhi + (size_t)s0 * D + lane * 4);
        ushort4 b = *(const ushort4*)(Xhi + (size_t)s1 * D + lane * 4);
        s.x += bf2f(a.x) + bf2f(b.x); s.y += bf2f(a.y) + bf2f(b.y);
        s.z += bf2f(a.z) + bf2f(b.z); s.w += bf2f(a.w) + bf2f(b.w);
    }
    if (j < end) {
        ushort4 a = *(const ushort4*)(Xhi + (size_t)adj[j] * D + lane * 4);
        s.x += bf2f(a.x); s.y += bf2f(a.y); s.z += bf2f(a.z); s.w += bf2f(a.w);
    }
    float inv = (n > 0) ? 1.0f / (float)n : 0.f;
    s.x *= inv; s.y *= inv; s.z *= inv; s.w *= inv;
    size_t off = (size_t)r * D + lane * 4;
    ushort4 h, l;
    split2(s.x, h.x, l.x); split2(s.y, h.y, l.y); split2(s.z, h.z, l.z); split2(s.w, h.w, l.w);
    *(ushort4*)(Ohi + off) = h;
    *(ushort4*)(Olo + off) = l;
}

// ---------------- fused news assembly: N += meanC(PP) + meanD(PP2); [relu] ----------------
template <int D, bool RELU>
__global__ void fuse_news_kernel(const u16* __restrict__ PPh, const u16* __restrict__ PP2h,
                                 const int* __restrict__ curC, const int* __restrict__ degC,
                                 const int* __restrict__ curD, const int* __restrict__ degD,
                                 const u16* __restrict__ adj,
                                 u16* __restrict__ Nh, u16* __restrict__ Nl, int ndst)
{
    constexpr int LANES = D / 4;
    constexpr int RPB = 256 / LANES;
    int r = blockIdx.x * RPB + threadIdx.x / LANES;
    if (r >= ndst) return;
    int lane = threadIdx.x % LANES;
    float4 s = {0.f, 0.f, 0.f, 0.f};
    {
        int end = curC[r], n = degC[r];
        float4 a = {0.f, 0.f, 0.f, 0.f};
        for (int j = end - n; j < end; ++j) {
            ushort4 v = *(const ushort4*)(PPh + (size_t)adj[j] * D + lane * 4);
            a.x += bf2f(v.x); a.y += bf2f(v.y); a.z += bf2f(v.z); a.w += bf2f(v.w);
        }
        float inv = (n > 0) ? 1.0f / (float)n : 0.f;
        s.x += a.x * inv; s.y += a.y * inv; s.z += a.z * inv; s.w += a.w * inv;
    }
    {
        int end = curD[r], n = degD[r];
        float4 a = {0.f, 0.f, 0.f, 0.f};
        for (int j = end - n; j < end; ++j) {
            ushort4 v = *(const ushort4*)(PP2h + (size_t)adj[j] * D + lane * 4);
            a.x += bf2f(v.x); a.y += bf2f(v.y); a.z += bf2f(v.z); a.w += bf2f(v.w);
        }
        float inv = (n > 0) ? 1.0f / (float)n : 0.f;
        s.x += a.x * inv; s.y += a.y * inv; s.z += a.z * inv; s.w += a.w * inv;
    }
    size_t off = (size_t)r * D + lane * 4;
    ushort4 h = *(const ushort4*)(Nh + off);
    ushort4 l = *(const ushort4*)(Nl + off);
    s.x += bf2f(h.x) + bf2f(l.x); s.y += bf2f(h.y) + bf2f(l.y);
    s.z += bf2f(h.z) + bf2f(l.z); s.w += bf2f(h.w) + bf2f(l.w);
    if (RELU) {
        s.x = fmaxf(s.x, 0.f); s.y = fmaxf(s.y, 0.f);
        s.z = fmaxf(s.z, 0.f); s.w = fmaxf(s.w, 0.f);
    }
    ushort4 oh, ol;
    split2(s.x, oh.x, ol.x); split2(s.y, oh.y, ol.y); split2(s.z, oh.z, ol.z); split2(s.w, oh.w, ol.w);
    *(ushort4*)(Nh + off) = oh;
    *(ushort4*)(Nl + off) = ol;
}

// ---------------- batched weight split/convert ----------------
#define MAXJOBS 20
struct SplitJobs {
    const float* a[MAXJOBS];
    const float* b[MAXJOBS];     // optional second operand (summed)
    u16* hi[MAXJOBS];
    u16* lo[MAXJOBS];
    int n[MAXJOBS];
    int ncols[MAXJOBS];          // source row width
    int dstride[MAXJOBS];        // dest row stride
    int boff[MAXJOBS + 1];
    int njobs;
};

__global__ void split_all_kernel(SplitJobs J)
{
    int bid = blockIdx.x;
    int j = 0;
    while (j + 1 < J.njobs && bid >= J.boff[j + 1]) ++j;
    int i = (bid - J.boff[j]) * 1024 + threadIdx.x * 4;
    if (i >= J.n[j]) return;
    float4 v = *(const float4*)(J.a[j] + i);
    if (J.b[j]) {
        float4 w = *(const float4*)(J.b[j] + i);
        v.x += w.x; v.y += w.y; v.z += w.z; v.w += w.w;
    }
    int row = i / J.ncols[j], col = i - row * J.ncols[j];
    size_t d = (size_t)row * J.dstride[j] + col;
    ushort4 h, l;
    split2(v.x, h.x, l.x); split2(v.y, h.y, l.y); split2(v.z, h.z, l.z); split2(v.w, h.w, l.w);
    *(ushort4*)(J.hi[j] + d) = h;
    *(ushort4*)(J.lo[j] + d) = l;
}

__global__ void bias_sum_kernel(const float* __restrict__ b1, const float* __restrict__ b2,
                                float* __restrict__ BS1, float* __restrict__ BS2)
{
    int i = blockIdx.x * 256 + threadIdx.x;
    if (i < 256) BS1[i] = b1[256 + i] + b1[768 + i];
    else if (i < 384) { int j = i - 256; BS2[j] = b2[128 + j] + b2[384 + j]; }
}

// ---------------- launch ----------------
extern "C" void kernel_launch(void* const* d_in, const int* in_sizes, int n_in,
                              void* d_out, int out_size, void* d_ws, size_t ws_size,
                              hipStream_t stream)
{
    const float* x_news = (const float*)d_in[0];
    const float* x_kw   = (const float*)d_in[1];
    const float* x_st   = (const float*)d_in[2];
    const float* Wn = (const float*)d_in[3];  const float* bn = (const float*)d_in[4];
    const float* Wk = (const float*)d_in[5];  const float* bk = (const float*)d_in[6];
    const float* Wst = (const float*)d_in[7]; const float* bs = (const float*)d_in[8];
    const float* W1l = (const float*)d_in[9];  const float* b1 = (const float*)d_in[10];
    const float* W1r = (const float*)d_in[11];
    const float* W2l = (const float*)d_in[12]; const float* b2 = (const float*)d_in[13];
    const float* W2r = (const float*)d_in[14];
    const float* DW1 = (const float*)d_in[15]; const float* Db1 = (const float*)d_in[16];
    const float* DW2 = (const float*)d_in[17]; const float* Db2 = (const float*)d_in[18];
    const int* e_hk_src = (const int*)d_in[19];
    const int* e_hk_dst = (const int*)d_in[20];
    const int* e_hs_src = (const int*)d_in[21];
    const int* e_hs_dst = (const int*)d_in[22];
    const int* l_hk_src = (const int*)d_in[23];
    const int* l_hk_dst = (const int*)d_in[24];
    const int* l_hs_src = (const int*)d_in[25];
    const int* l_hs_dst = (const int*)d_in[26];
    float* out = (float*)d_out;

    // ---- workspace layout (bytes, 16B aligned) ----
    char* base = (char*)d_ws;
    auto alloc = [&](size_t bytes) -> char* {
        char* p = base;
        base += (bytes + 15) & ~(size_t)15;
        return p;
    };
    auto aplane = [&](size_t elems) -> u16* { return (u16*)alloc(elems * 2); };

    u16* HNh = aplane((size_t)N_NEWS * HID);  u16* HNl = aplane((size_t)N_NEWS * HID);
    u16* HKh = aplane((size_t)N_KW * HID);    u16* HKl = aplane((size_t)N_KW * HID);
    u16* HSh = aplane((size_t)N_ST * HID);    u16* HSl = aplane((size_t)N_ST * HID);
    u16* K1h = aplane((size_t)N_KW * HID);    u16* K1l = aplane((size_t)N_KW * HID);
    u16* S1h = aplane((size_t)N_ST * HID);    u16* S1l = aplane((size_t)N_ST * HID);
    u16* PAh = aplane((size_t)N_KW * HID);    u16* PAl = aplane((size_t)N_KW * HID);
    u16* N1h = aplane((size_t)N_NEWS * HID);  u16* N1l = aplane((size_t)N_NEWS * HID);
    // weight planes
    u16* WnH = aplane(196608);  u16* WnL = aplane(196608);
    u16* WkH = aplane(32768);   u16* WkL = aplane(32768);
    u16* WsH = aplane(16384);   u16* WsL = aplane(16384);
    u16* CW1KH = aplane(131072); u16* CW1KL = aplane(131072);  // [256][512] W1l0|W1r0
    u16* CW1SH = aplane(131072); u16* CW1SL = aplane(131072);  // [256][512] W1l2|W1r2
    u16* W1l1H = aplane(65536);  u16* W1l1L = aplane(65536);
    u16* W1l3H = aplane(65536);  u16* W1l3L = aplane(65536);
    u16* SW1H = aplane(65536);   u16* SW1L = aplane(65536);    // W1r1+W1r3
    u16* CW2KH = aplane(65536);  u16* CW2KL = aplane(65536);   // [128][512] W2l0|W2r0
    u16* CW2SH = aplane(65536);  u16* CW2SL = aplane(65536);   // [128][512] W2l2|W2r2
    u16* W2l1H = aplane(32768);  u16* W2l1L = aplane(32768);
    u16* W2l3H = aplane(32768);  u16* W2l3L = aplane(32768);
    u16* SW2H = aplane(32768);   u16* SW2L = aplane(32768);    // W2r1+W2r3
    u16* DW1H = aplane(65536);   u16* DW1L = aplane(65536);
    float* BS1 = (float*)alloc(256 * 4);
    float* BS2 = (float*)alloc(128 * 4);
    // int pools
    int* deg = (int*)alloc((size_t)NTOT * 4);
    int* cur = (int*)alloc((size_t)NTOT * 4);
    u16* adj = (u16*)alloc((size_t)2 * (E_HK + E_HS) * 2);
    int* bsum = (int*)alloc(512 * 4);

    // overlays: layer-2 outputs reuse the HN region (dead after layer 1)
    u16* K2h = HNh;
    u16* K2l = K2h + (size_t)N_KW * OUTD;
    u16* N2h = K2l + (size_t)N_KW * OUTD;
    u16* N2l = N2h + (size_t)N_NEWS * OUTD;
    u16* S2h = N2l + (size_t)N_NEWS * OUTD;
    u16* S2l = S2h + (size_t)N_ST * OUTD;

    // ---- CSR build ----
    hipMemsetAsync(deg, 0, (size_t)NTOT * sizeof(int), stream);
    int etot = E_HK + E_HS;
    count_all_kernel<<<(etot + 255) / 256, 256, 0, stream>>>(e_hk_src, e_hk_dst, e_hs_src, e_hs_dst, deg);
    int nb = (NTOT + 255) / 256; // 438
    scan_block_kernel<<<nb, 256, 0, stream>>>(deg, cur, bsum, NTOT);
    scan2_kernel<<<1, 512, 0, stream>>>(bsum, nb);
    scan_add_kernel<<<nb, 256, 0, stream>>>(cur, bsum, NTOT);
    fill_all_kernel<<<(etot + 255) / 256, 256, 0, stream>>>(e_hk_src, e_hk_dst, e_hs_src, e_hs_dst, cur, adj);

    // ---- batched weight conversion ----
    {
        SplitJobs J{};
        int nj = 0, blocks = 0;
        auto job = [&](const float* a, const float* b, u16* hi, u16* lo, int n, int ncols, int dstride) {
            J.a[nj] = a; J.b[nj] = b; J.hi[nj] = hi; J.lo[nj] = lo;
            J.n[nj] = n; J.ncols[nj] = ncols; J.dstride[nj] = dstride;
            J.boff[nj] = blocks;
            blocks += (n / 4 + 255) / 256;
            ++nj;
        };
        job(Wn, nullptr, WnH, WnL, 196608, 196608, 196608);
        job(Wk, nullptr, WkH, WkL, 32768, 32768, 32768);
        job(Wst, nullptr, WsH, WsL, 16384, 16384, 16384);
        job(W1l + 0 * 65536, nullptr, CW1KH, CW1KL, 65536, 256, 512);
        job(W1r + 0 * 65536, nullptr, CW1KH + 256, CW1KL + 256, 65536, 256, 512);
        job(W1l + 2 * 65536, nullptr, CW1SH, CW1SL, 65536, 256, 512);
        job(W1r + 2 * 65536, nullptr, CW1SH + 256, CW1SL + 256, 65536, 256, 512);
        job(W1l + 1 * 65536, nullptr, W1l1H, W1l1L, 65536, 65536, 65536);
        job(W1l + 3 * 65536, nullptr, W1l3H, W1l3L, 65536, 65536, 65536);
        job(W1r + 1 * 65536, W1r + 3 * 65536, SW1H, SW1L, 65536, 65536, 65536);
        job(W2l + 0 * 32768, nullptr, CW2KH, CW2KL, 32768, 256, 512);
        job(W2r + 0 * 32768, nullptr, CW2KH + 256, CW2KL + 256, 32768, 256, 512);
        job(W2l + 2 * 32768, nullptr, CW2SH, CW2SL, 32768, 256, 512);
        job(W2r + 2 * 32768, nullptr, CW2SH + 256, CW2SL + 256, 32768, 256, 512);
        job(W2l + 1 * 32768, nullptr, W2l1H, W2l1L, 32768, 32768, 32768);
        job(W2l + 3 * 32768, nullptr, W2l3H, W2l3L, 32768, 32768, 32768);
        job(W2r + 1 * 32768, W2r + 3 * 32768, SW2H, SW2L, 32768, 32768, 32768);
        job(DW1, nullptr, DW1H, DW1L, 65536, 65536, 65536);
        J.boff[nj] = blocks;
        J.njobs = nj;
        split_all_kernel<<<blocks, 256, 0, stream>>>(J);
    }
    bias_sum_kernel<<<2, 256, 0, stream>>>(b1, b2, BS1, BS2);

    // ---- GEMM wrappers ----
    auto gemmF = [&](const float* A, int lda, const u16* Bh, const u16* Bl, int ldw,
                     const float* bias, u16* Ch, u16* Cl, int ldc,
                     int M, int N, int K, int flags) {
        dim3 g((M + 127) / 128, N / 128);
        gemm_kernel<0, 0, false><<<g, 256, 0, stream>>>(
            A, nullptr, nullptr, nullptr, nullptr, nullptr, nullptr, lda, 0,
            Bh, Bl, ldw, bias, Ch, Cl, ldc, nullptr, nullptr, nullptr, M, K, flags);
    };
    auto gemmP = [&](const u16* Ahp, const u16* Alp, int lda, const u16* Bh, const u16* Bl, int ldw,
                     const float* bias, u16* Ch, u16* Cl, int ldc,
                     int M, int N, int K, int flags) {
        dim3 g((M + 127) / 128, N / 128);
        gemm_kernel<1, 0, false><<<g, 256, 0, stream>>>(
            nullptr, Ahp, Alp, nullptr, nullptr, nullptr, nullptr, lda, 0,
            Bh, Bl, ldw, bias, Ch, Cl, ldc, nullptr, nullptr, nullptr, M, K, flags);
    };
    auto gemm2 = [&](const u16* A1hp, const u16* A1lp, const u16* A2hp, const u16* A2lp,
                     int lda, int kpiv, const u16* Bh, const u16* Bl, int ldw,
                     const float* bias, u16* Ch, u16* Cl, int ldc,
                     int M, int N, int K, int flags) {
        dim3 g((M + 127) / 128, N / 128);
        gemm_kernel<2, 0, false><<<g, 256, 0, stream>>>(
            nullptr, A1hp, A1lp, A2hp, A2lp, nullptr, nullptr, lda, kpiv,
            Bh, Bl, ldw, bias, Ch, Cl, ldc, nullptr, nullptr, nullptr, M, K, flags);
    };
    auto gemmLP = [&](const u16* Ahp, int lda, const u16* Bh, int ldw,
                      u16* Ch, int ldc, int M, int N, int K) {
        dim3 g((M + 127) / 128, N / 128);
        gemm_kernel<1, 1, true><<<g, 256, 0, stream>>>(
            nullptr, Ahp, nullptr, nullptr, nullptr, nullptr, nullptr, lda, 0,
            Bh, nullptr, ldw, nullptr, Ch, nullptr, ldc, nullptr, nullptr, nullptr, M, K, 0);
    };
    auto gemmD = [&](const u16* A1hp, const u16* A1lp, const u16* A2hp, const u16* A2lp,
                     const int* r1, const int* r2,
                     const u16* Bh, const u16* Bl,
                     const float* bias, const float* dw2, const float* db2, float* ov) {
        dim3 g((E_LBL + 127) / 128, 1);
        gemm_kernel<2, 2, false><<<g, 256, 0, stream>>>(
            nullptr, A1hp, A1lp, A2hp, A2lp, r1, r2, 128, 128,
            Bh, Bl, 256, bias, nullptr, nullptr, 0, dw2, db2, ov, E_LBL, 256, 0);
    };

    // ---- input projections ----
    gemmF(x_news, F_NEWS, WnH, WnL, F_NEWS, bn, HNh, HNl, HID, N_NEWS, HID, F_NEWS, FLAG_RELU);
    gemmF(x_kw,   F_KW,   WkH, WkL, F_KW,   bk, HKh, HKl, HID, N_KW,   HID, F_KW,   FLAG_RELU);
    gemmF(x_st,   F_ST,   WsH, WsL, F_ST,   bs, HSh, HSl, HID, N_ST,   HID, F_ST,   FLAG_RELU);

    // ---- layer 1 ----
    // k1 = relu([mean_A(hn) | hk] @ [W1l0|W1r0]^T + b1[0])
    gather_mean_kernel<256><<<(N_KW + 3) / 4, 256, 0, stream>>>(HNh, cur + OFFA, deg + OFFA, adj, PAh, PAl, N_KW);
    gemm2(PAh, PAl, HKh, HKl, HID, 256, CW1KH, CW1KL, 512, b1, K1h, K1l, HID, N_KW, HID, 512, FLAG_RELU);
    // s1
    gather_mean_kernel<256><<<(N_ST + 3) / 4, 256, 0, stream>>>(HNh, cur + OFFB, deg + OFFB, adj, PAh, PAl, N_ST);
    gemm2(PAh, PAl, HSh, HSl, HID, 256, CW1SH, CW1SL, 512, b1 + 2 * 256, S1h, S1l, HID, N_ST, HID, 512, FLAG_RELU);
    // n1: project small sources (hi-only), r-term GEMM, fused gather-assembly
    gemmLP(HKh, HID, W1l1H, HID, PAh, HID, N_KW, HID, HID);   // PP
    gemmLP(HSh, HID, W1l3H, HID, PAl, HID, N_ST, HID, HID);   // PP2
    gemmP(HNh, HNl, HID, SW1H, SW1L, HID, BS1, N1h, N1l, HID, N_NEWS, HID, HID, 0);
    fuse_news_kernel<256, true><<<(N_NEWS + 3) / 4, 256, 0, stream>>>(
        PAh, PAl, cur + OFFC, deg + OFFC, cur + OFFD, deg + OFFD, adj, N1h, N1l, N_NEWS);

    // ---- layer 2 ----
    gather_mean_kernel<256><<<(N_KW + 3) / 4, 256, 0, stream>>>(N1h, cur + OFFA, deg + OFFA, adj, PAh, PAl, N_KW);
    gemm2(PAh, PAl, K1h, K1l, HID, 256, CW2KH, CW2KL, 512, b2, K2h, K2l, OUTD, N_KW, OUTD, 512, 0);
    gather_mean_kernel<256><<<(N_ST + 3) / 4, 256, 0, stream>>>(N1h, cur + OFFB, deg + OFFB, adj, PAh, PAl, N_ST);
    gemm2(PAh, PAl, S1h, S1l, HID, 256, CW2SH, CW2SL, 512, b2 + 2 * 128, S2h, S2l, OUTD, N_ST, OUTD, 512, 0);
    gemmLP(K1h, HID, W2l1H, HID, PAh, OUTD, N_KW, OUTD, HID);  // PP (n2)
    gemmLP(S1h, HID, W2l3H, HID, PAl, OUTD, N_ST, OUTD, HID);  // PP2 (n2)
    gemmP(N1h, N1l, HID, SW2H, SW2L, HID, BS2, N2h, N2l, OUTD, N_NEWS, OUTD, HID, 0);
    fuse_news_kernel<128, false><<<(N_NEWS + 7) / 8, 256, 0, stream>>>(
        PAh, PAl, cur + OFFC, deg + OFFC, cur + OFFD, deg + OFFD, adj, N2h, N2l, N_NEWS);

    // ---- fused decoders ----
    gemmD(N2h, N2l, K2h, K2l, l_hk_src, l_hk_dst, DW1H, DW1L, Db1, DW2, Db2, out);
    gemmD(N2h, N2l, S2h, S2l, l_hs_src, l_hs_dst, DW1H + 32768, DW1L + 32768,
          Db1 + 128, DW2 + 128, Db2 + 1, out + E_LBL);
}

// Round 9
// 868.948 us; speedup vs baseline: 1.4493x; 1.2126x over previous
//
#include <hip/hip_runtime.h>
#include <hip/hip_bf16.h>

// ---------------- problem constants ----------------
constexpr int N_NEWS = 50000, N_KW = 10000, N_ST = 2000;
constexpr int F_NEWS = 768, F_KW = 128, F_ST = 64;
constexpr int HID = 256, OUTD = 128;
constexpr int E_HK = 500000, E_HS = 250000, E_LBL = 150000;

// CSR section offsets in the concatenated degree/cursor pools
constexpr int OFFA = 0;                    // e_hk keyed by dst (kw)
constexpr int OFFB = N_KW;                 // e_hs keyed by dst (st)
constexpr int OFFC = N_KW + N_ST;          // e_hk keyed by src (news)
constexpr int OFFD = OFFC + N_NEWS;        // e_hs keyed by src (news)
constexpr int NTOT = OFFD + N_NEWS;        // 112000

enum { FLAG_ACC = 1, FLAG_RELU = 2 };

typedef unsigned short u16;
typedef __attribute__((ext_vector_type(8))) short bf16x8;
typedef __attribute__((ext_vector_type(8))) unsigned short u16x8;
typedef __attribute__((ext_vector_type(4))) float f32x4;

__device__ __forceinline__ u16 f2bf(float x) {
    return __builtin_bit_cast(u16, __float2bfloat16(x));
}
__device__ __forceinline__ float bf2f(u16 h) {
    unsigned u = ((unsigned)h) << 16;
    return __builtin_bit_cast(float, u);
}
__device__ __forceinline__ void split2(float x, u16& h, u16& l) {
    h = f2bf(x);
    l = f2bf(x - bf2f(h));
}

// ---------------- split-bf16 MFMA GEMM, swizzled LDS, 2-deep register prefetch --------
// Full LDS staging of A and B (round-6 structure, measured best). Two named staging
// register sets; the load for tile k+64 is issued while tile k computes -> ~2 MFMA
// sections + 2 barriers of latency cover per wave (x ~3 blocks/CU co-resident).
// tile 128x128, BK=32, 4 waves (2x2). 3 MFMA/product (hi*hi+hi*lo+lo*hi); LOWP: 1.
// ASRC: 0 = fp32 A (convert in staging), 1 = plane A, 2 = dual-table plane A (pivot kpiv)
// WMODE: 0 = write hi+lo planes, 1 = hi only, 2 = fused decoder reduce -> outv
template<int ASRC, int WMODE, bool LOWP>
__global__ __launch_bounds__(256) void gemm_kernel(
    const float* __restrict__ Af,
    const u16* __restrict__ A1h, const u16* __restrict__ A1l,
    const u16* __restrict__ A2h, const u16* __restrict__ A2l,
    const int* __restrict__ ridx1, const int* __restrict__ ridx2, int lda, int kpiv,
    const u16* __restrict__ Bhg, const u16* __restrict__ Blg, int ldw,
    const float* __restrict__ bias,
    u16* __restrict__ Chi, u16* __restrict__ Clo, int ldc,
    const float* __restrict__ dw2, const float* __restrict__ db2,
    float* __restrict__ outv,
    int M, int K, int flags)
{
    __shared__ u16 Ah[128 * 32], Bh[128 * 32];
    __shared__ u16 Al[128 * 32], Bl[128 * 32];
    __shared__ float red[128];

    const int tid = threadIdx.x;
    const int bm = blockIdx.x * 128;
    const int bn = blockIdx.y * 128;
    const int l = tid & 63;
    const int w = tid >> 6;
    const int wm = w >> 1, wn = w & 1;
    const int lg = l >> 4, lr = l & 15;

    // ---- hoisted staging pointers (2 chunks of 256 threads) ----
    const float* pAf[2];
    const u16 *pA1h[2], *pA1l[2], *pA2h[2], *pA2l[2], *pBh[2], *pBl[2];
    int usw[2];
    #pragma unroll
    for (int p = 0; p < 2; ++p) {
        int g = tid + p * 256;
        int row = g >> 2, c8 = (g & 3) * 8;
        usw[p] = (row * 32 + c8) ^ ((row & 7) << 3);
        int rg = bm + row; if (rg > M - 1) rg = M - 1;
        long br = (long)(bn + row) * ldw + c8;
        pBh[p] = Bhg + br;
        if constexpr (!LOWP) pBl[p] = Blg + br;
        if constexpr (ASRC == 0) {
            long ar = ridx1 ? (long)ridx1[rg] : (long)rg;
            pAf[p] = Af + ar * lda + c8;
        } else if constexpr (ASRC == 1) {
            long ar = ridx1 ? (long)ridx1[rg] : (long)rg;
            pA1h[p] = A1h + ar * lda + c8;
            if constexpr (!LOWP) pA1l[p] = A1l + ar * lda + c8;
        } else {
            long a1 = ridx1 ? (long)ridx1[rg] : (long)rg;
            long a2 = ridx2 ? (long)ridx2[rg] : (long)rg;
            pA1h[p] = A1h + a1 * lda + c8;
            pA1l[p] = A1l + a1 * lda + c8;
            pA2h[p] = A2h + a2 * lda + c8 - kpiv;
            pA2l[p] = A2l + a2 * lda + c8 - kpiv;
        }
    }

    // ---- two named staging register sets (2-deep pipeline; rule-#20 safe) ----
    struct Stage {
        float4 va[2][2];
        u16x8 rah[2], ral[2], rbh[2], rbl[2];
    };
    Stage s0, s1;

    auto LOADset = [&](Stage& S, int k0) {
        #pragma unroll
        for (int p = 0; p < 2; ++p) {
            if constexpr (ASRC == 0) {
                S.va[p][0] = ((const float4*)(pAf[p] + k0))[0];
                S.va[p][1] = ((const float4*)(pAf[p] + k0))[1];
            } else if constexpr (ASRC == 1) {
                S.rah[p] = *(const u16x8*)(pA1h[p] + k0);
                if constexpr (!LOWP) S.ral[p] = *(const u16x8*)(pA1l[p] + k0);
            } else {
                bool first = k0 < kpiv;
                const u16* ph = first ? pA1h[p] + k0 : pA2h[p] + k0;
                const u16* pl = first ? pA1l[p] + k0 : pA2l[p] + k0;
                S.rah[p] = *(const u16x8*)ph;
                S.ral[p] = *(const u16x8*)pl;
            }
            S.rbh[p] = *(const u16x8*)(pBh[p] + k0);
            if constexpr (!LOWP) S.rbl[p] = *(const u16x8*)(pBl[p] + k0);
        }
    };
    auto STOREset = [&](const Stage& S) {
        #pragma unroll
        for (int p = 0; p < 2; ++p) {
            if constexpr (ASRC == 0) {
                float vv[8] = {S.va[p][0].x, S.va[p][0].y, S.va[p][0].z, S.va[p][0].w,
                               S.va[p][1].x, S.va[p][1].y, S.va[p][1].z, S.va[p][1].w};
                u16x8 h8, l8;
                #pragma unroll
                for (int q = 0; q < 8; ++q) { u16 hh, ll; split2(vv[q], hh, ll); h8[q] = hh; l8[q] = ll; }
                *(u16x8*)&Ah[usw[p]] = h8;
                *(u16x8*)&Al[usw[p]] = l8;
            } else {
                *(u16x8*)&Ah[usw[p]] = S.rah[p];
                if constexpr (!LOWP) *(u16x8*)&Al[usw[p]] = S.ral[p];
            }
            *(u16x8*)&Bh[usw[p]] = S.rbh[p];
            if constexpr (!LOWP) *(u16x8*)&Bl[usw[p]] = S.rbl[p];
        }
    };

    f32x4 acc[4][4];
    #pragma unroll
    for (int i = 0; i < 4; ++i)
        #pragma unroll
        for (int j = 0; j < 4; ++j) acc[i][j] = (f32x4){0.f, 0.f, 0.f, 0.f};

    auto MFMA = [&]() {
        bf16x8 fah[4], fal[4], fbh[4], fbl[4];
        #pragma unroll
        for (int mt = 0; mt < 4; ++mt) {
            int r = wm * 64 + mt * 16 + lr;
            int us = (r * 32 + lg * 8) ^ ((r & 7) << 3);
            fah[mt] = *(const bf16x8*)&Ah[us];
            if constexpr (!LOWP) fal[mt] = *(const bf16x8*)&Al[us];
        }
        #pragma unroll
        for (int nt = 0; nt < 4; ++nt) {
            int r = wn * 64 + nt * 16 + lr;
            int us = (r * 32 + lg * 8) ^ ((r & 7) << 3);
            fbh[nt] = *(const bf16x8*)&Bh[us];
            if constexpr (!LOWP) fbl[nt] = *(const bf16x8*)&Bl[us];
        }
        #pragma unroll
        for (int mt = 0; mt < 4; ++mt)
            #pragma unroll
            for (int nt = 0; nt < 4; ++nt) {
                acc[mt][nt] = __builtin_amdgcn_mfma_f32_16x16x32_bf16(fah[mt], fbh[nt], acc[mt][nt], 0, 0, 0);
                if constexpr (!LOWP) {
                    acc[mt][nt] = __builtin_amdgcn_mfma_f32_16x16x32_bf16(fah[mt], fbl[nt], acc[mt][nt], 0, 0, 0);
                    acc[mt][nt] = __builtin_amdgcn_mfma_f32_16x16x32_bf16(fal[mt], fbh[nt], acc[mt][nt], 0, 0, 0);
                }
            }
    };

    // ---- 2-deep pipelined K loop (K % 64 == 0; kpiv % 64 == 0) ----
    LOADset(s0, 0);
    LOADset(s1, 32);
    for (int k0 = 0; k0 < K; k0 += 64) {
        __syncthreads();            // prev fragment reads done -> LDS reusable
        STOREset(s0);               // tile k0
        __syncthreads();            // tile ready
        if (k0 + 64 < K) LOADset(s0, k0 + 64);   // 2 steps ahead
        MFMA();                     // compute k0
        __syncthreads();
        STOREset(s1);               // tile k0+32
        __syncthreads();
        if (k0 + 96 < K) LOADset(s1, k0 + 96);
        MFMA();                     // compute k0+32
    }

    // ---- epilogue ----
    if constexpr (WMODE == 2) {
        if (tid < 128) red[tid] = 0.f;
        __syncthreads();
        float bv[4], dwv[4];
        #pragma unroll
        for (int nt = 0; nt < 4; ++nt) {
            int colg = wn * 64 + nt * 16 + lr;
            bv[nt] = bias[colg];
            dwv[nt] = dw2[colg];
        }
        #pragma unroll
        for (int mt = 0; mt < 4; ++mt)
            #pragma unroll
            for (int j = 0; j < 4; ++j) {
                float p = 0.f;
                #pragma unroll
                for (int nt = 0; nt < 4; ++nt)
                    p += fmaxf(acc[mt][nt][j] + bv[nt], 0.f) * dwv[nt];
                p += __shfl_xor(p, 1);
                p += __shfl_xor(p, 2);
                p += __shfl_xor(p, 4);
                p += __shfl_xor(p, 8);
                if (lr == 0) atomicAdd(&red[wm * 64 + mt * 16 + lg * 4 + j], p);
            }
        __syncthreads();
        if (tid < 128) {
            int row = bm + tid;
            if (row < M) outv[row] = red[tid] + db2[0];
        }
    } else {
        float bv[4];
        int col[4];
        #pragma unroll
        for (int nt = 0; nt < 4; ++nt) {
            col[nt] = bn + wn * 64 + nt * 16 + lr;
            bv[nt] = bias ? bias[col[nt]] : 0.f;
        }
        #pragma unroll
        for (int mt = 0; mt < 4; ++mt) {
            int row0 = bm + wm * 64 + mt * 16 + lg * 4;
            #pragma unroll
            for (int j = 0; j < 4; ++j) {
                int row = row0 + j;
                if (row >= M) continue;
                size_t rbase = (size_t)row * ldc;
                #pragma unroll
                for (int nt = 0; nt < 4; ++nt) {
                    size_t off = rbase + col[nt];
                    float v = acc[mt][nt][j] + bv[nt];
                    if (flags & FLAG_RELU) v = fmaxf(v, 0.f);
                    u16 hh, ll; split2(v, hh, ll);
                    Chi[off] = hh;
                    if constexpr (WMODE == 0) Clo[off] = ll;
                }
            }
        }
    }
}

// ---------------- CSR build (merged, sections A|B|C|D) ----------------
__global__ void count_all_kernel(const int* __restrict__ hks, const int* __restrict__ hkd,
                                 const int* __restrict__ hss, const int* __restrict__ hsd,
                                 int* __restrict__ deg)
{
    int e = blockIdx.x * blockDim.x + threadIdx.x;
    if (e < E_HK) {
        atomicAdd(deg + OFFA + hkd[e], 1);
        atomicAdd(deg + OFFC + hks[e], 1);
    } else if (e < E_HK + E_HS) {
        int i = e - E_HK;
        atomicAdd(deg + OFFB + hsd[i], 1);
        atomicAdd(deg + OFFD + hss[i], 1);
    }
}

__global__ void scan_block_kernel(const int* __restrict__ in, int* __restrict__ out,
                                  int* __restrict__ bsum, int n)
{
    __shared__ int tmp[256];
    int i = blockIdx.x * 256 + threadIdx.x;
    int v = (i < n) ? in[i] : 0;
    tmp[threadIdx.x] = v;
    __syncthreads();
    #pragma unroll
    for (int off = 1; off < 256; off <<= 1) {
        int t = (threadIdx.x >= off) ? tmp[threadIdx.x - off] : 0;
        __syncthreads();
        tmp[threadIdx.x] += t;
        __syncthreads();
    }
    if (i < n) out[i] = tmp[threadIdx.x] - v;
    if (threadIdx.x == 255 && bsum) bsum[blockIdx.x] = tmp[255];
}

__global__ void scan2_kernel(int* __restrict__ data, int n) // n <= 512, in-place exclusive
{
    __shared__ int tmp[512];
    int v = (threadIdx.x < n) ? data[threadIdx.x] : 0;
    tmp[threadIdx.x] = v;
    __syncthreads();
    #pragma unroll
    for (int off = 1; off < 512; off <<= 1) {
        int t = (threadIdx.x >= off) ? tmp[threadIdx.x - off] : 0;
        __syncthreads();
        tmp[threadIdx.x] += t;
        __syncthreads();
    }
    if (threadIdx.x < n) data[threadIdx.x] = tmp[threadIdx.x] - v;
}

__global__ void scan_add_kernel(int* __restrict__ out, const int* __restrict__ bsumex, int n)
{
    int i = blockIdx.x * 256 + threadIdx.x;
    if (i < n) out[i] += bsumex[blockIdx.x];
}

__global__ void fill_all_kernel(const int* __restrict__ hks, const int* __restrict__ hkd,
                                const int* __restrict__ hss, const int* __restrict__ hsd,
                                int* __restrict__ cur, u16* __restrict__ adj)
{
    int e = blockIdx.x * blockDim.x + threadIdx.x;
    if (e < E_HK) {
        int s = hks[e], d = hkd[e];
        int p = atomicAdd(cur + OFFA + d, 1); adj[p] = (u16)s;
        int q = atomicAdd(cur + OFFC + s, 1); adj[q] = (u16)d;
    } else if (e < E_HK + E_HS) {
        int i = e - E_HK;
        int s = hss[i], d = hsd[i];
        int p = atomicAdd(cur + OFFB + d, 1); adj[p] = (u16)s;
        int q = atomicAdd(cur + OFFD + s, 1); adj[q] = (u16)d;
    }
}

// ---------------- gather mean (hi-plane read, hi/lo write; 16B/lane) ----------------
template <int D>
__global__ void gather_mean_kernel(const u16* __restrict__ Xhi,
                                   const int* __restrict__ cur, const int* __restrict__ deg,
                                   const u16* __restrict__ adj,
                                   u16* __restrict__ Ohi, u16* __restrict__ Olo, int ndst)
{
    constexpr int LANES = D / 8;          // 16B per lane
    constexpr int RPB = 256 / LANES;
    int r = blockIdx.x * RPB + threadIdx.x / LANES;
    if (r >= ndst) return;
    int lane = threadIdx.x % LANES;
    int end = cur[r];
    int n = deg[r];
    int j = end - n;
    float s[8];
    #pragma unroll
    for (int q = 0; q < 8; ++q) s[q] = 0.f;
    for (; j + 1 < end; j += 2) {
        u16x8 a = *(const u16x8*)(Xhi + (size_t)adj[j] * D + lane * 8);
        u16x8 b = *(const u16x8*)(Xhi + (size_t)adj[j + 1] * D + lane * 8);
        #pragma unroll
        for (int q = 0; q < 8; ++q) s[q] += bf2f(a[q]) + bf2f(b[q]);
    }
    if (j < end) {
        u16x8 a = *(const u16x8*)(Xhi + (size_t)adj[j] * D + lane * 8);
        #pragma unroll
        for (int q = 0; q < 8; ++q) s[q] += bf2f(a[q]);
    }
    float inv = (n > 0) ? 1.0f / (float)n : 0.f;
    size_t off = (size_t)r * D + lane * 8;
    u16x8 h8, l8;
    #pragma unroll
    for (int q = 0; q < 8; ++q) { u16 hh, ll; split2(s[q] * inv, hh, ll); h8[q] = hh; l8[q] = ll; }
    *(u16x8*)(Ohi + off) = h8;
    *(u16x8*)(Olo + off) = l8;
}

// ---------------- fused news assembly: N += meanC(PP) + meanD(PP2); [relu] ----------------
template <int D, bool RELU>
__global__ void fuse_news_kernel(const u16* __restrict__ PPh, const u16* __restrict__ PP2h,
                                 const int* __restrict__ curC, const int* __restrict__ degC,
                                 const int* __restrict__ curD, const int* __restrict__ degD,
                                 const u16* __restrict__ adj,
                                 u16* __restrict__ Nh, u16* __restrict__ Nl, int ndst)
{
    constexpr int LANES = D / 8;          // 16B per lane
    constexpr int RPB = 256 / LANES;
    int r = blockIdx.x * RPB + threadIdx.x / LANES;
    if (r >= ndst) return;
    int lane = threadIdx.x % LANES;
    float s[8];
    #pragma unroll
    for (int q = 0; q < 8; ++q) s[q] = 0.f;
    {
        int end = curC[r], n = degC[r];
        float a[8];
        #pragma unroll
        for (int q = 0; q < 8; ++q) a[q] = 0.f;
        for (int j = end - n; j < end; ++j) {
            u16x8 v = *(const u16x8*)(PPh + (size_t)adj[j] * D + lane * 8);
            #pragma unroll
            for (int q = 0; q < 8; ++q) a[q] += bf2f(v[q]);
        }
        float inv = (n > 0) ? 1.0f / (float)n : 0.f;
        #pragma unroll
        for (int q = 0; q < 8; ++q) s[q] += a[q] * inv;
    }
    {
        int end = curD[r], n = degD[r];
        float a[8];
        #pragma unroll
        for (int q = 0; q < 8; ++q) a[q] = 0.f;
        for (int j = end - n; j < end; ++j) {
            u16x8 v = *(const u16x8*)(PP2h + (size_t)adj[j] * D + lane * 8);
            #pragma unroll
            for (int q = 0; q < 8; ++q) a[q] += bf2f(v[q]);
        }
        float inv = (n > 0) ? 1.0f / (float)n : 0.f;
        #pragma unroll
        for (int q = 0; q < 8; ++q) s[q] += a[q] * inv;
    }
    size_t off = (size_t)r * D + lane * 8;
    u16x8 h = *(const u16x8*)(Nh + off);
    u16x8 l = *(const u16x8*)(Nl + off);
    #pragma unroll
    for (int q = 0; q < 8; ++q) {
        float v = s[q] + bf2f(h[q]) + bf2f(l[q]);
        if (RELU) v = fmaxf(v, 0.f);
        s[q] = v;
    }
    u16x8 oh, ol;
    #pragma unroll
    for (int q = 0; q < 8; ++q) { u16 hh, ll; split2(s[q], hh, ll); oh[q] = hh; ol[q] = ll; }
    *(u16x8*)(Nh + off) = oh;
    *(u16x8*)(Nl + off) = ol;
}

// ---------------- batched weight split/convert ----------------
#define MAXJOBS 20
struct SplitJobs {
    const float* a[MAXJOBS];
    const float* b[MAXJOBS];     // optional second operand (summed)
    u16* hi[MAXJOBS];
    u16* lo[MAXJOBS];
    int n[MAXJOBS];
    int ncols[MAXJOBS];          // source row width
    int dstride[MAXJOBS];        // dest row stride
    int boff[MAXJOBS + 1];
    int njobs;
};

__global__ void split_all_kernel(SplitJobs J)
{
    int bid = blockIdx.x;
    int j = 0;
    while (j + 1 < J.njobs && bid >= J.boff[j + 1]) ++j;
    int i = (bid - J.boff[j]) * 1024 + threadIdx.x * 4;
    if (i >= J.n[j]) return;
    float4 v = *(const float4*)(J.a[j] + i);
    if (J.b[j]) {
        float4 w = *(const float4*)(J.b[j] + i);
        v.x += w.x; v.y += w.y; v.z += w.z; v.w += w.w;
    }
    int row = i / J.ncols[j], col = i - row * J.ncols[j];
    size_t d = (size_t)row * J.dstride[j] + col;
    ushort4 h, l;
    split2(v.x, h.x, l.x); split2(v.y, h.y, l.y); split2(v.z, h.z, l.z); split2(v.w, h.w, l.w);
    *(ushort4*)(J.hi[j] + d) = h;
    *(ushort4*)(J.lo[j] + d) = l;
}

__global__ void bias_sum_kernel(const float* __restrict__ b1, const float* __restrict__ b2,
                                float* __restrict__ BS1, float* __restrict__ BS2)
{
    int i = blockIdx.x * 256 + threadIdx.x;
    if (i < 256) BS1[i] = b1[256 + i] + b1[768 + i];
    else if (i < 384) { int j = i - 256; BS2[j] = b2[128 + j] + b2[384 + j]; }
}

// ---------------- launch ----------------
extern "C" void kernel_launch(void* const* d_in, const int* in_sizes, int n_in,
                              void* d_out, int out_size, void* d_ws, size_t ws_size,
                              hipStream_t stream)
{
    const float* x_news = (const float*)d_in[0];
    const float* x_kw   = (const float*)d_in[1];
    const float* x_st   = (const float*)d_in[2];
    const float* Wn = (const float*)d_in[3];  const float* bn = (const float*)d_in[4];
    const float* Wk = (const float*)d_in[5];  const float* bk = (const float*)d_in[6];
    const float* Wst = (const float*)d_in[7]; const float* bs = (const float*)d_in[8];
    const float* W1l = (const float*)d_in[9];  const float* b1 = (const float*)d_in[10];
    const float* W1r = (const float*)d_in[11];
    const float* W2l = (const float*)d_in[12]; const float* b2 = (const float*)d_in[13];
    const float* W2r = (const float*)d_in[14];
    const float* DW1 = (const float*)d_in[15]; const float* Db1 = (const float*)d_in[16];
    const float* DW2 = (const float*)d_in[17]; const float* Db2 = (const float*)d_in[18];
    const int* e_hk_src = (const int*)d_in[19];
    const int* e_hk_dst = (const int*)d_in[20];
    const int* e_hs_src = (const int*)d_in[21];
    const int* e_hs_dst = (const int*)d_in[22];
    const int* l_hk_src = (const int*)d_in[23];
    const int* l_hk_dst = (const int*)d_in[24];
    const int* l_hs_src = (const int*)d_in[25];
    const int* l_hs_dst = (const int*)d_in[26];
    float* out = (float*)d_out;

    // ---- workspace layout (bytes, 16B aligned) ----
    char* base = (char*)d_ws;
    auto alloc = [&](size_t bytes) -> char* {
        char* p = base;
        base += (bytes + 15) & ~(size_t)15;
        return p;
    };
    auto aplane = [&](size_t elems) -> u16* { return (u16*)alloc(elems * 2); };

    u16* HNh = aplane((size_t)N_NEWS * HID);  u16* HNl = aplane((size_t)N_NEWS * HID);
    u16* HKh = aplane((size_t)N_KW * HID);    u16* HKl = aplane((size_t)N_KW * HID);
    u16* HSh = aplane((size_t)N_ST * HID);    u16* HSl = aplane((size_t)N_ST * HID);
    u16* K1h = aplane((size_t)N_KW * HID);    u16* K1l = aplane((size_t)N_KW * HID);
    u16* S1h = aplane((size_t)N_ST * HID);    u16* S1l = aplane((size_t)N_ST * HID);
    u16* PAh = aplane((size_t)N_KW * HID);    u16* PAl = aplane((size_t)N_KW * HID);
    u16* N1h = aplane((size_t)N_NEWS * HID);  u16* N1l = aplane((size_t)N_NEWS * HID);
    // weight planes
    u16* WnH = aplane(196608);  u16* WnL = aplane(196608);
    u16* WkH = aplane(32768);   u16* WkL = aplane(32768);
    u16* WsH = aplane(16384);   u16* WsL = aplane(16384);
    u16* CW1KH = aplane(131072); u16* CW1KL = aplane(131072);  // [256][512] W1l0|W1r0
    u16* CW1SH = aplane(131072); u16* CW1SL = aplane(131072);  // [256][512] W1l2|W1r2
    u16* W1l1H = aplane(65536);  u16* W1l1L = aplane(65536);
    u16* W1l3H = aplane(65536);  u16* W1l3L = aplane(65536);
    u16* SW1H = aplane(65536);   u16* SW1L = aplane(65536);    // W1r1+W1r3
    u16* CW2KH = aplane(65536);  u16* CW2KL = aplane(65536);   // [128][512] W2l0|W2r0
    u16* CW2SH = aplane(65536);  u16* CW2SL = aplane(65536);   // [128][512] W2l2|W2r2
    u16* W2l1H = aplane(32768);  u16* W2l1L = aplane(32768);
    u16* W2l3H = aplane(32768);  u16* W2l3L = aplane(32768);
    u16* SW2H = aplane(32768);   u16* SW2L = aplane(32768);    // W2r1+W2r3
    u16* DW1H = aplane(65536);   u16* DW1L = aplane(65536);
    float* BS1 = (float*)alloc(256 * 4);
    float* BS2 = (float*)alloc(128 * 4);
    // int pools
    int* deg = (int*)alloc((size_t)NTOT * 4);
    int* cur = (int*)alloc((size_t)NTOT * 4);
    u16* adj = (u16*)alloc((size_t)2 * (E_HK + E_HS) * 2);
    int* bsum = (int*)alloc(512 * 4);

    // overlays: layer-2 outputs reuse the HN region (dead after layer 1)
    u16* K2h = HNh;
    u16* K2l = K2h + (size_t)N_KW * OUTD;
    u16* N2h = K2l + (size_t)N_KW * OUTD;
    u16* N2l = N2h + (size_t)N_NEWS * OUTD;
    u16* S2h = N2l + (size_t)N_NEWS * OUTD;
    u16* S2l = S2h + (size_t)N_ST * OUTD;

    // ---- CSR build ----
    hipMemsetAsync(deg, 0, (size_t)NTOT * sizeof(int), stream);
    int etot = E_HK + E_HS;
    count_all_kernel<<<(etot + 255) / 256, 256, 0, stream>>>(e_hk_src, e_hk_dst, e_hs_src, e_hs_dst, deg);
    int nb = (NTOT + 255) / 256; // 438
    scan_block_kernel<<<nb, 256, 0, stream>>>(deg, cur, bsum, NTOT);
    scan2_kernel<<<1, 512, 0, stream>>>(bsum, nb);
    scan_add_kernel<<<nb, 256, 0, stream>>>(cur, bsum, NTOT);
    fill_all_kernel<<<(etot + 255) / 256, 256, 0, stream>>>(e_hk_src, e_hk_dst, e_hs_src, e_hs_dst, cur, adj);

    // ---- batched weight conversion ----
    {
        SplitJobs J{};
        int nj = 0, blocks = 0;
        auto job = [&](const float* a, const float* b, u16* hi, u16* lo, int n, int ncols, int dstride) {
            J.a[nj] = a; J.b[nj] = b; J.hi[nj] = hi; J.lo[nj] = lo;
            J.n[nj] = n; J.ncols[nj] = ncols; J.dstride[nj] = dstride;
            J.boff[nj] = blocks;
            blocks += (n / 4 + 255) / 256;
            ++nj;
        };
        job(Wn, nullptr, WnH, WnL, 196608, 196608, 196608);
        job(Wk, nullptr, WkH, WkL, 32768, 32768, 32768);
        job(Wst, nullptr, WsH, WsL, 16384, 16384, 16384);
        job(W1l + 0 * 65536, nullptr, CW1KH, CW1KL, 65536, 256, 512);
        job(W1r + 0 * 65536, nullptr, CW1KH + 256, CW1KL + 256, 65536, 256, 512);
        job(W1l + 2 * 65536, nullptr, CW1SH, CW1SL, 65536, 256, 512);
        job(W1r + 2 * 65536, nullptr, CW1SH + 256, CW1SL + 256, 65536, 256, 512);
        job(W1l + 1 * 65536, nullptr, W1l1H, W1l1L, 65536, 65536, 65536);
        job(W1l + 3 * 65536, nullptr, W1l3H, W1l3L, 65536, 65536, 65536);
        job(W1r + 1 * 65536, W1r + 3 * 65536, SW1H, SW1L, 65536, 65536, 65536);
        job(W2l + 0 * 32768, nullptr, CW2KH, CW2KL, 32768, 256, 512);
        job(W2r + 0 * 32768, nullptr, CW2KH + 256, CW2KL + 256, 32768, 256, 512);
        job(W2l + 2 * 32768, nullptr, CW2SH, CW2SL, 32768, 256, 512);
        job(W2r + 2 * 32768, nullptr, CW2SH + 256, CW2SL + 256, 32768, 256, 512);
        job(W2l + 1 * 32768, nullptr, W2l1H, W2l1L, 32768, 32768, 32768);
        job(W2l + 3 * 32768, nullptr, W2l3H, W2l3L, 32768, 32768, 32768);
        job(W2r + 1 * 32768, W2r + 3 * 32768, SW2H, SW2L, 32768, 32768, 32768);
        job(DW1, nullptr, DW1H, DW1L, 65536, 65536, 65536);
        J.boff[nj] = blocks;
        J.njobs = nj;
        split_all_kernel<<<blocks, 256, 0, stream>>>(J);
    }
    bias_sum_kernel<<<2, 256, 0, stream>>>(b1, b2, BS1, BS2);

    // ---- GEMM wrappers ----
    auto gemmF = [&](const float* A, int lda, const u16* Bh, const u16* Bl, int ldw,
                     const float* bias, u16* Ch, u16* Cl, int ldc,
                     int M, int N, int K, int flags) {
        dim3 g((M + 127) / 128, N / 128);
        gemm_kernel<0, 0, false><<<g, 256, 0, stream>>>(
            A, nullptr, nullptr, nullptr, nullptr, nullptr, nullptr, lda, 0,
            Bh, Bl, ldw, bias, Ch, Cl, ldc, nullptr, nullptr, nullptr, M, K, flags);
    };
    auto gemmP = [&](const u16* Ahp, const u16* Alp, int lda, const u16* Bh, const u16* Bl, int ldw,
                     const float* bias, u16* Ch, u16* Cl, int ldc,
                     int M, int N, int K, int flags) {
        dim3 g((M + 127) / 128, N / 128);
        gemm_kernel<1, 0, false><<<g, 256, 0, stream>>>(
            nullptr, Ahp, Alp, nullptr, nullptr, nullptr, nullptr, lda, 0,
            Bh, Bl, ldw, bias, Ch, Cl, ldc, nullptr, nullptr, nullptr, M, K, flags);
    };
    auto gemm2 = [&](const u16* A1hp, const u16* A1lp, const u16* A2hp, const u16* A2lp,
                     int lda, int kpiv, const u16* Bh, const u16* Bl, int ldw,
                     const float* bias, u16* Ch, u16* Cl, int ldc,
                     int M, int N, int K, int flags) {
        dim3 g((M + 127) / 128, N / 128);
        gemm_kernel<2, 0, false><<<g, 256, 0, stream>>>(
            nullptr, A1hp, A1lp, A2hp, A2lp, nullptr, nullptr, lda, kpiv,
            Bh, Bl, ldw, bias, Ch, Cl, ldc, nullptr, nullptr, nullptr, M, K, flags);
    };
    auto gemmLP = [&](const u16* Ahp, int lda, const u16* Bh, int ldw,
                      u16* Ch, int ldc, int M, int N, int K) {
        dim3 g((M + 127) / 128, N / 128);
        gemm_kernel<1, 1, true><<<g, 256, 0, stream>>>(
            nullptr, Ahp, nullptr, nullptr, nullptr, nullptr, nullptr, lda, 0,
            Bh, nullptr, ldw, nullptr, Ch, nullptr, ldc, nullptr, nullptr, nullptr, M, K, 0);
    };
    auto gemmD = [&](const u16* A1hp, const u16* A1lp, const u16* A2hp, const u16* A2lp,
                     const int* r1, const int* r2,
                     const u16* Bh, const u16* Bl,
                     const float* bias, const float* dw2, const float* db2, float* ov) {
        dim3 g((E_LBL + 127) / 128, 1);
        gemm_kernel<2, 2, false><<<g, 256, 0, stream>>>(
            nullptr, A1hp, A1lp, A2hp, A2lp, r1, r2, 128, 128,
            Bh, Bl, 256, bias, nullptr, nullptr, 0, dw2, db2, ov, E_LBL, 256, 0);
    };

    // ---- input projections ----
    gemmF(x_news, F_NEWS, WnH, WnL, F_NEWS, bn, HNh, HNl, HID, N_NEWS, HID, F_NEWS, FLAG_RELU);
    gemmF(x_kw,   F_KW,   WkH, WkL, F_KW,   bk, HKh, HKl, HID, N_KW,   HID, F_KW,   FLAG_RELU);
    gemmF(x_st,   F_ST,   WsH, WsL, F_ST,   bs, HSh, HSl, HID, N_ST,   HID, F_ST,   FLAG_RELU);

    // ---- layer 1 ----
    // k1 = relu([mean_A(hn) | hk] @ [W1l0|W1r0]^T + b1[0])
    gather_mean_kernel<256><<<(N_KW + 7) / 8, 256, 0, stream>>>(HNh, cur + OFFA, deg + OFFA, adj, PAh, PAl, N_KW);
    gemm2(PAh, PAl, HKh, HKl, HID, 256, CW1KH, CW1KL, 512, b1, K1h, K1l, HID, N_KW, HID, 512, FLAG_RELU);
    // s1
    gather_mean_kernel<256><<<(N_ST + 7) / 8, 256, 0, stream>>>(HNh, cur + OFFB, deg + OFFB, adj, PAh, PAl, N_ST);
    gemm2(PAh, PAl, HSh, HSl, HID, 256, CW1SH, CW1SL, 512, b1 + 2 * 256, S1h, S1l, HID, N_ST, HID, 512, FLAG_RELU);
    // n1: project small sources (hi-only), r-term GEMM, fused gather-assembly
    gemmLP(HKh, HID, W1l1H, HID, PAh, HID, N_KW, HID, HID);   // PP
    gemmLP(HSh, HID, W1l3H, HID, PAl, HID, N_ST, HID, HID);   // PP2
    gemmP(HNh, HNl, HID, SW1H, SW1L, HID, BS1, N1h, N1l, HID, N_NEWS, HID, HID, 0);
    fuse_news_kernel<256, true><<<(N_NEWS + 7) / 8, 256, 0, stream>>>(
        PAh, PAl, cur + OFFC, deg + OFFC, cur + OFFD, deg + OFFD, adj, N1h, N1l, N_NEWS);

    // ---- layer 2 ----
    gather_mean_kernel<256><<<(N_KW + 7) / 8, 256, 0, stream>>>(N1h, cur + OFFA, deg + OFFA, adj, PAh, PAl, N_KW);
    gemm2(PAh, PAl, K1h, K1l, HID, 256, CW2KH, CW2KL, 512, b2, K2h, K2l, OUTD, N_KW, OUTD, 512, 0);
    gather_mean_kernel<256><<<(N_ST + 7) / 8, 256, 0, stream>>>(N1h, cur + OFFB, deg + OFFB, adj, PAh, PAl, N_ST);
    gemm2(PAh, PAl, S1h, S1l, HID, 256, CW2SH, CW2SL, 512, b2 + 2 * 128, S2h, S2l, OUTD, N_ST, OUTD, 512, 0);
    gemmLP(K1h, HID, W2l1H, HID, PAh, OUTD, N_KW, OUTD, HID);  // PP (n2)
    gemmLP(S1h, HID, W2l3H, HID, PAl, OUTD, N_ST, OUTD, HID);  // PP2 (n2)
    gemmP(N1h, N1l, HID, SW2H, SW2L, HID, BS2, N2h, N2l, OUTD, N_NEWS, OUTD, HID, 0);
    fuse_news_kernel<128, false><<<(N_NEWS + 15) / 16, 256, 0, stream>>>(
        PAh, PAl, cur + OFFC, deg + OFFC, cur + OFFD, deg + OFFD, adj, N2h, N2l, N_NEWS);

    // ---- fused decoders ----
    gemmD(N2h, N2l, K2h, K2l, l_hk_src, l_hk_dst, DW1H, DW1L, Db1, DW2, Db2, out);
    gemmD(N2h, N2l, S2h, S2l, l_hs_src, l_hs_dst, DW1H + 32768, DW1L + 32768,
          Db1 + 128, DW2 + 128, Db2 + 1, out + E_LBL);
}

// Round 10
// 854.700 us; speedup vs baseline: 1.4735x; 1.0167x over previous
//
#include <hip/hip_runtime.h>
#include <hip/hip_bf16.h>

// ---------------- problem constants ----------------
constexpr int N_NEWS = 50000, N_KW = 10000, N_ST = 2000;
constexpr int F_NEWS = 768, F_KW = 128, F_ST = 64;
constexpr int HID = 256, OUTD = 128;
constexpr int E_HK = 500000, E_HS = 250000, E_LBL = 150000;

// CSR section offsets in the concatenated degree/cursor pools
constexpr int OFFA = 0;                    // e_hk keyed by dst (kw)
constexpr int OFFB = N_KW;                 // e_hs keyed by dst (st)
constexpr int OFFC = N_KW + N_ST;          // e_hk keyed by src (news)
constexpr int OFFD = OFFC + N_NEWS;        // e_hs keyed by src (news)
constexpr int NTOT = OFFD + N_NEWS;        // 112000

enum { FLAG_ACC = 1, FLAG_RELU = 2 };

typedef unsigned short u16;
typedef __attribute__((ext_vector_type(8))) short bf16x8;
typedef __attribute__((ext_vector_type(8))) unsigned short u16x8;
typedef __attribute__((ext_vector_type(4))) float f32x4;

__device__ __forceinline__ u16 f2bf(float x) {
    return __builtin_bit_cast(u16, __float2bfloat16(x));
}
__device__ __forceinline__ float bf2f(u16 h) {
    unsigned u = ((unsigned)h) << 16;
    return __builtin_bit_cast(float, u);
}
__device__ __forceinline__ void split2(float x, u16& h, u16& l) {
    h = f2bf(x);
    l = f2bf(x - bf2f(h));
}

// async global->LDS DMA, 16B per lane; LDS dest = wave-uniform base + lane*16
__device__ __forceinline__ void gload16(const void* g, void* s) {
    __builtin_amdgcn_global_load_lds(
        (const __attribute__((address_space(1))) void*)g,
        (__attribute__((address_space(3))) void*)s, 16, 0, 0);
}

// ---------------- split-bf16 MFMA GEMM, global_load_lds staging (m97 structure) --------
// LDS is written LINEARLY by the DMA; the swizzle lives in the per-lane GLOBAL source
// address (granule cg^(r&3) for planes, cg^(r&7) for fp32) and the matching fragment
// read. Per K-step: drain-barrier -> ds_read frags -> barrier -> issue next-tile DMA
// -> MFMA (loads in flight under compute).
// tile 128x128, BK=32, 4 waves (2x2). 3 MFMA/product (hi*hi+hi*lo+lo*hi); LOWP: 1.
// ASRC: 0 = fp32 A (DMA fp32, split in regs), 1 = plane A, 2 = dual-table plane A
// WMODE: 0 = write hi+lo planes, 1 = hi only, 2 = fused decoder reduce -> outv
template<int ASRC, int WMODE, bool LOWP>
__global__ __launch_bounds__(256) void gemm_kernel(
    const float* __restrict__ Af,
    const u16* __restrict__ A1h, const u16* __restrict__ A1l,
    const u16* __restrict__ A2h, const u16* __restrict__ A2l,
    const int* __restrict__ ridx1, const int* __restrict__ ridx2, int lda, int kpiv,
    const u16* __restrict__ Bhg, const u16* __restrict__ Blg, int ldw,
    const float* __restrict__ bias,
    u16* __restrict__ Chi, u16* __restrict__ Clo, int ldc,
    const float* __restrict__ dw2, const float* __restrict__ db2,
    float* __restrict__ outv,
    int M, int K, int flags)
{
    constexpr int A_BYTES = (ASRC == 0) ? 16384 : (LOWP ? 8192 : 16384);
    constexpr int B_BYTES = LOWP ? 8192 : 16384;
    __shared__ __align__(16) char ldsraw[A_BYTES + B_BYTES];
    __shared__ float red[128];
    float* Af32 = (float*)ldsraw;
    u16* Ah = (u16*)ldsraw;
    u16* Al = (u16*)(ldsraw + 8192);
    u16* Bh = (u16*)(ldsraw + A_BYTES);
    u16* Bl = (u16*)(ldsraw + A_BYTES + 8192);

    const int tid = threadIdx.x;
    const int bm = blockIdx.x * 128;
    const int bn = blockIdx.y * 128;
    const int l = tid & 63;
    const int w = tid >> 6;
    const int wm = w >> 1, wn = w & 1;
    const int lg = l >> 4, lr = l & 15;

    // ---- per-thread DMA source pointers (swizzled granule addressing) ----
    // plane A/B: tile = 128 rows x 32 u16 = 512 granules; loads j=0,1: g=(w*2+j)*64+l
    // fp32 A:    tile = 128 rows x 32 f32 = 1024 granules; loads j=0..3: g=(w*4+j)*64+l
    const float* srcAf[4];
    const u16 *srcA1h[2], *srcA1l[2], *srcA2h[2], *srcA2l[2];
    const u16 *srcBh[2], *srcBl[2];
    float* dstAf[4];
    u16 *dstAh[2], *dstAl[2], *dstBh[2], *dstBl[2];

    if constexpr (ASRC == 0) {
        #pragma unroll
        for (int j = 0; j < 4; ++j) {
            int g = (w * 4 + j) * 64 + l;
            int r = g >> 3, cg = g & 7;
            int rg = bm + r; if (rg > M - 1) rg = M - 1;
            long ar = ridx1 ? (long)ridx1[rg] : (long)rg;
            srcAf[j] = Af + ar * lda + (cg ^ (r & 7)) * 4;
            dstAf[j] = Af32 + (w * 4 + j) * 256;      // 64 lanes * 4 floats
        }
    } else {
        #pragma unroll
        for (int j = 0; j < 2; ++j) {
            int g = (w * 2 + j) * 64 + l;
            int r = g >> 2, cg = g & 3;
            int rg = bm + r; if (rg > M - 1) rg = M - 1;
            int col = (cg ^ (r & 3)) * 8;
            long a1 = ridx1 ? (long)ridx1[rg] : (long)rg;
            srcA1h[j] = A1h + a1 * lda + col;
            if constexpr (!LOWP) srcA1l[j] = A1l + a1 * lda + col;
            if constexpr (ASRC == 2) {
                long a2 = ridx2 ? (long)ridx2[rg] : (long)rg;
                srcA2h[j] = A2h + a2 * lda + col - kpiv;
                srcA2l[j] = A2l + a2 * lda + col - kpiv;
            }
            dstAh[j] = Ah + (w * 2 + j) * 512;        // 64 lanes * 8 u16
            if constexpr (!LOWP) dstAl[j] = Al + (w * 2 + j) * 512;
        }
    }
    #pragma unroll
    for (int j = 0; j < 2; ++j) {
        int g = (w * 2 + j) * 64 + l;
        int r = g >> 2, cg = g & 3;
        int col = (cg ^ (r & 3)) * 8;
        srcBh[j] = Bhg + (long)(bn + r) * ldw + col;
        if constexpr (!LOWP) srcBl[j] = Blg + (long)(bn + r) * ldw + col;
        dstBh[j] = Bh + (w * 2 + j) * 512;
        if constexpr (!LOWP) dstBl[j] = Bl + (w * 2 + j) * 512;
    }

    auto ISSUE = [&](int k0) {
        if constexpr (ASRC == 0) {
            #pragma unroll
            for (int j = 0; j < 4; ++j) gload16(srcAf[j] + k0, dstAf[j]);
        } else if constexpr (ASRC == 1) {
            #pragma unroll
            for (int j = 0; j < 2; ++j) {
                gload16(srcA1h[j] + k0, dstAh[j]);
                if constexpr (!LOWP) gload16(srcA1l[j] + k0, dstAl[j]);
            }
        } else {
            bool first = k0 < kpiv;
            #pragma unroll
            for (int j = 0; j < 2; ++j) {
                gload16((first ? srcA1h[j] : srcA2h[j]) + k0, dstAh[j]);
                gload16((first ? srcA1l[j] : srcA2l[j]) + k0, dstAl[j]);
            }
        }
        #pragma unroll
        for (int j = 0; j < 2; ++j) {
            gload16(srcBh[j] + k0, dstBh[j]);
            if constexpr (!LOWP) gload16(srcBl[j] + k0, dstBl[j]);
        }
    };

    f32x4 acc[4][4];
    #pragma unroll
    for (int i = 0; i < 4; ++i)
        #pragma unroll
        for (int j = 0; j < 4; ++j) acc[i][j] = (f32x4){0.f, 0.f, 0.f, 0.f};

    // fragment registers (read phase -> compute phase)
    bf16x8 fah[4], fal[4], fbh[4], fbl[4];
    float4 vaf[4][2];

    auto READ_FRAGS = [&]() {
        #pragma unroll
        for (int mt = 0; mt < 4; ++mt) {
            int r = wm * 64 + mt * 16 + lr;
            if constexpr (ASRC == 0) {
                int cg0 = (lg * 2) ^ (r & 7);
                int cg1 = (lg * 2 + 1) ^ (r & 7);
                vaf[mt][0] = *(const float4*)&Af32[r * 32 + cg0 * 4];
                vaf[mt][1] = *(const float4*)&Af32[r * 32 + cg1 * 4];
            } else {
                int cg = lg ^ (r & 3);
                fah[mt] = *(const bf16x8*)&Ah[r * 32 + cg * 8];
                if constexpr (!LOWP) fal[mt] = *(const bf16x8*)&Al[r * 32 + cg * 8];
            }
        }
        #pragma unroll
        for (int nt = 0; nt < 4; ++nt) {
            int r = wn * 64 + nt * 16 + lr;
            int cg = lg ^ (r & 3);
            fbh[nt] = *(const bf16x8*)&Bh[r * 32 + cg * 8];
            if constexpr (!LOWP) fbl[nt] = *(const bf16x8*)&Bl[r * 32 + cg * 8];
        }
    };

    auto COMPUTE = [&]() {
        if constexpr (ASRC == 0) {
            #pragma unroll
            for (int mt = 0; mt < 4; ++mt) {
                float vv[8] = {vaf[mt][0].x, vaf[mt][0].y, vaf[mt][0].z, vaf[mt][0].w,
                               vaf[mt][1].x, vaf[mt][1].y, vaf[mt][1].z, vaf[mt][1].w};
                bf16x8 h8, l8;
                #pragma unroll
                for (int q = 0; q < 8; ++q) {
                    u16 hh, ll; split2(vv[q], hh, ll);
                    h8[q] = (short)hh; l8[q] = (short)ll;
                }
                fah[mt] = h8; fal[mt] = l8;
            }
        }
        #pragma unroll
        for (int mt = 0; mt < 4; ++mt)
            #pragma unroll
            for (int nt = 0; nt < 4; ++nt) {
                acc[mt][nt] = __builtin_amdgcn_mfma_f32_16x16x32_bf16(fah[mt], fbh[nt], acc[mt][nt], 0, 0, 0);
                if constexpr (!LOWP) {
                    acc[mt][nt] = __builtin_amdgcn_mfma_f32_16x16x32_bf16(fah[mt], fbl[nt], acc[mt][nt], 0, 0, 0);
                    acc[mt][nt] = __builtin_amdgcn_mfma_f32_16x16x32_bf16(fal[mt], fbh[nt], acc[mt][nt], 0, 0, 0);
                }
            }
    };

    // ---- m97-style K loop (K % 32 == 0; kpiv % 32 == 0) ----
    ISSUE(0);
    for (int k0 = 0; k0 < K; k0 += 32) {
        __syncthreads();                 // drain DMA for tile k0 (compiler: vmcnt(0))
        READ_FRAGS();                    // LDS -> regs
        __syncthreads();                 // all waves done reading
        if (k0 + 32 < K) ISSUE(k0 + 32); // next tile flies during compute
        COMPUTE();
    }

    // ---- epilogue ----
    if constexpr (WMODE == 2) {
        if (tid < 128) red[tid] = 0.f;
        __syncthreads();
        float bv[4], dwv[4];
        #pragma unroll
        for (int nt = 0; nt < 4; ++nt) {
            int colg = wn * 64 + nt * 16 + lr;
            bv[nt] = bias[colg];
            dwv[nt] = dw2[colg];
        }
        #pragma unroll
        for (int mt = 0; mt < 4; ++mt)
            #pragma unroll
            for (int j = 0; j < 4; ++j) {
                float p = 0.f;
                #pragma unroll
                for (int nt = 0; nt < 4; ++nt)
                    p += fmaxf(acc[mt][nt][j] + bv[nt], 0.f) * dwv[nt];
                p += __shfl_xor(p, 1);
                p += __shfl_xor(p, 2);
                p += __shfl_xor(p, 4);
                p += __shfl_xor(p, 8);
                if (lr == 0) atomicAdd(&red[wm * 64 + mt * 16 + lg * 4 + j], p);
            }
        __syncthreads();
        if (tid < 128) {
            int row = bm + tid;
            if (row < M) outv[row] = red[tid] + db2[0];
        }
    } else {
        float bv[4];
        int col[4];
        #pragma unroll
        for (int nt = 0; nt < 4; ++nt) {
            col[nt] = bn + wn * 64 + nt * 16 + lr;
            bv[nt] = bias ? bias[col[nt]] : 0.f;
        }
        #pragma unroll
        for (int mt = 0; mt < 4; ++mt) {
            int row0 = bm + wm * 64 + mt * 16 + lg * 4;
            #pragma unroll
            for (int j = 0; j < 4; ++j) {
                int row = row0 + j;
                if (row >= M) continue;
                size_t rbase = (size_t)row * ldc;
                #pragma unroll
                for (int nt = 0; nt < 4; ++nt) {
                    size_t off = rbase + col[nt];
                    float v = acc[mt][nt][j] + bv[nt];
                    if (flags & FLAG_RELU) v = fmaxf(v, 0.f);
                    u16 hh, ll; split2(v, hh, ll);
                    Chi[off] = hh;
                    if constexpr (WMODE == 0) Clo[off] = ll;
                }
            }
        }
    }
}

// ---------------- CSR build (merged, sections A|B|C|D) ----------------
__global__ void count_all_kernel(const int* __restrict__ hks, const int* __restrict__ hkd,
                                 const int* __restrict__ hss, const int* __restrict__ hsd,
                                 int* __restrict__ deg)
{
    int e = blockIdx.x * blockDim.x + threadIdx.x;
    if (e < E_HK) {
        atomicAdd(deg + OFFA + hkd[e], 1);
        atomicAdd(deg + OFFC + hks[e], 1);
    } else if (e < E_HK + E_HS) {
        int i = e - E_HK;
        atomicAdd(deg + OFFB + hsd[i], 1);
        atomicAdd(deg + OFFD + hss[i], 1);
    }
}

__global__ void scan_block_kernel(const int* __restrict__ in, int* __restrict__ out,
                                  int* __restrict__ bsum, int n)
{
    __shared__ int tmp[256];
    int i = blockIdx.x * 256 + threadIdx.x;
    int v = (i < n) ? in[i] : 0;
    tmp[threadIdx.x] = v;
    __syncthreads();
    #pragma unroll
    for (int off = 1; off < 256; off <<= 1) {
        int t = (threadIdx.x >= off) ? tmp[threadIdx.x - off] : 0;
        __syncthreads();
        tmp[threadIdx.x] += t;
        __syncthreads();
    }
    if (i < n) out[i] = tmp[threadIdx.x] - v;
    if (threadIdx.x == 255 && bsum) bsum[blockIdx.x] = tmp[255];
}

__global__ void scan2_kernel(int* __restrict__ data, int n) // n <= 512, in-place exclusive
{
    __shared__ int tmp[512];
    int v = (threadIdx.x < n) ? data[threadIdx.x] : 0;
    tmp[threadIdx.x] = v;
    __syncthreads();
    #pragma unroll
    for (int off = 1; off < 512; off <<= 1) {
        int t = (threadIdx.x >= off) ? tmp[threadIdx.x - off] : 0;
        __syncthreads();
        tmp[threadIdx.x] += t;
        __syncthreads();
    }
    if (threadIdx.x < n) data[threadIdx.x] = tmp[threadIdx.x] - v;
}

__global__ void scan_add_kernel(int* __restrict__ out, const int* __restrict__ bsumex, int n)
{
    int i = blockIdx.x * 256 + threadIdx.x;
    if (i < n) out[i] += bsumex[blockIdx.x];
}

__global__ void fill_all_kernel(const int* __restrict__ hks, const int* __restrict__ hkd,
                                const int* __restrict__ hss, const int* __restrict__ hsd,
                                int* __restrict__ cur, u16* __restrict__ adj)
{
    int e = blockIdx.x * blockDim.x + threadIdx.x;
    if (e < E_HK) {
        int s = hks[e], d = hkd[e];
        int p = atomicAdd(cur + OFFA + d, 1); adj[p] = (u16)s;
        int q = atomicAdd(cur + OFFC + s, 1); adj[q] = (u16)d;
    } else if (e < E_HK + E_HS) {
        int i = e - E_HK;
        int s = hss[i], d = hsd[i];
        int p = atomicAdd(cur + OFFB + d, 1); adj[p] = (u16)s;
        int q = atomicAdd(cur + OFFD + s, 1); adj[q] = (u16)d;
    }
}

// ---------------- gather mean (hi-plane read, hi/lo write; 16B/lane) ----------------
template <int D>
__global__ void gather_mean_kernel(const u16* __restrict__ Xhi,
                                   const int* __restrict__ cur, const int* __restrict__ deg,
                                   const u16* __restrict__ adj,
                                   u16* __restrict__ Ohi, u16* __restrict__ Olo, int ndst)
{
    constexpr int LANES = D / 8;          // 16B per lane
    constexpr int RPB = 256 / LANES;
    int r = blockIdx.x * RPB + threadIdx.x / LANES;
    if (r >= ndst) return;
    int lane = threadIdx.x % LANES;
    int end = cur[r];
    int n = deg[r];
    int j = end - n;
    float s[8];
    #pragma unroll
    for (int q = 0; q < 8; ++q) s[q] = 0.f;
    for (; j + 1 < end; j += 2) {
        u16x8 a = *(const u16x8*)(Xhi + (size_t)adj[j] * D + lane * 8);
        u16x8 b = *(const u16x8*)(Xhi + (size_t)adj[j + 1] * D + lane * 8);
        #pragma unroll
        for (int q = 0; q < 8; ++q) s[q] += bf2f(a[q]) + bf2f(b[q]);
    }
    if (j < end) {
        u16x8 a = *(const u16x8*)(Xhi + (size_t)adj[j] * D + lane * 8);
        #pragma unroll
        for (int q = 0; q < 8; ++q) s[q] += bf2f(a[q]);
    }
    float inv = (n > 0) ? 1.0f / (float)n : 0.f;
    size_t off = (size_t)r * D + lane * 8;
    u16x8 h8, l8;
    #pragma unroll
    for (int q = 0; q < 8; ++q) { u16 hh, ll; split2(s[q] * inv, hh, ll); h8[q] = hh; l8[q] = ll; }
    *(u16x8*)(Ohi + off) = h8;
    *(u16x8*)(Olo + off) = l8;
}

// ---------------- fused news assembly: N += meanC(PP) + meanD(PP2); [relu] ----------------
template <int D, bool RELU>
__global__ void fuse_news_kernel(const u16* __restrict__ PPh, const u16* __restrict__ PP2h,
                                 const int* __restrict__ curC, const int* __restrict__ degC,
                                 const int* __restrict__ curD, const int* __restrict__ degD,
                                 const u16* __restrict__ adj,
                                 u16* __restrict__ Nh, u16* __restrict__ Nl, int ndst)
{
    constexpr int LANES = D / 8;          // 16B per lane
    constexpr int RPB = 256 / LANES;
    int r = blockIdx.x * RPB + threadIdx.x / LANES;
    if (r >= ndst) return;
    int lane = threadIdx.x % LANES;
    float s[8];
    #pragma unroll
    for (int q = 0; q < 8; ++q) s[q] = 0.f;
    {
        int end = curC[r], n = degC[r];
        float a[8];
        #pragma unroll
        for (int q = 0; q < 8; ++q) a[q] = 0.f;
        for (int j = end - n; j < end; ++j) {
            u16x8 v = *(const u16x8*)(PPh + (size_t)adj[j] * D + lane * 8);
            #pragma unroll
            for (int q = 0; q < 8; ++q) a[q] += bf2f(v[q]);
        }
        float inv = (n > 0) ? 1.0f / (float)n : 0.f;
        #pragma unroll
        for (int q = 0; q < 8; ++q) s[q] += a[q] * inv;
    }
    {
        int end = curD[r], n = degD[r];
        float a[8];
        #pragma unroll
        for (int q = 0; q < 8; ++q) a[q] = 0.f;
        for (int j = end - n; j < end; ++j) {
            u16x8 v = *(const u16x8*)(PP2h + (size_t)adj[j] * D + lane * 8);
            #pragma unroll
            for (int q = 0; q < 8; ++q) a[q] += bf2f(v[q]);
        }
        float inv = (n > 0) ? 1.0f / (float)n : 0.f;
        #pragma unroll
        for (int q = 0; q < 8; ++q) s[q] += a[q] * inv;
    }
    size_t off = (size_t)r * D + lane * 8;
    u16x8 h = *(const u16x8*)(Nh + off);
    u16x8 l = *(const u16x8*)(Nl + off);
    #pragma unroll
    for (int q = 0; q < 8; ++q) {
        float v = s[q] + bf2f(h[q]) + bf2f(l[q]);
        if (RELU) v = fmaxf(v, 0.f);
        s[q] = v;
    }
    u16x8 oh, ol;
    #pragma unroll
    for (int q = 0; q < 8; ++q) { u16 hh, ll; split2(s[q], hh, ll); oh[q] = hh; ol[q] = ll; }
    *(u16x8*)(Nh + off) = oh;
    *(u16x8*)(Nl + off) = ol;
}

// ---------------- batched weight split/convert ----------------
#define MAXJOBS 20
struct SplitJobs {
    const float* a[MAXJOBS];
    const float* b[MAXJOBS];     // optional second operand (summed)
    u16* hi[MAXJOBS];
    u16* lo[MAXJOBS];
    int n[MAXJOBS];
    int ncols[MAXJOBS];          // source row width
    int dstride[MAXJOBS];        // dest row stride
    int boff[MAXJOBS + 1];
    int njobs;
};

__global__ void split_all_kernel(SplitJobs J)
{
    int bid = blockIdx.x;
    int j = 0;
    while (j + 1 < J.njobs && bid >= J.boff[j + 1]) ++j;
    int i = (bid - J.boff[j]) * 1024 + threadIdx.x * 4;
    if (i >= J.n[j]) return;
    float4 v = *(const float4*)(J.a[j] + i);
    if (J.b[j]) {
        float4 w = *(const float4*)(J.b[j] + i);
        v.x += w.x; v.y += w.y; v.z += w.z; v.w += w.w;
    }
    int row = i / J.ncols[j], col = i - row * J.ncols[j];
    size_t d = (size_t)row * J.dstride[j] + col;
    ushort4 h, l;
    split2(v.x, h.x, l.x); split2(v.y, h.y, l.y); split2(v.z, h.z, l.z); split2(v.w, h.w, l.w);
    *(ushort4*)(J.hi[j] + d) = h;
    *(ushort4*)(J.lo[j] + d) = l;
}

__global__ void bias_sum_kernel(const float* __restrict__ b1, const float* __restrict__ b2,
                                float* __restrict__ BS1, float* __restrict__ BS2)
{
    int i = blockIdx.x * 256 + threadIdx.x;
    if (i < 256) BS1[i] = b1[256 + i] + b1[768 + i];
    else if (i < 384) { int j = i - 256; BS2[j] = b2[128 + j] + b2[384 + j]; }
}

// ---------------- launch ----------------
extern "C" void kernel_launch(void* const* d_in, const int* in_sizes, int n_in,
                              void* d_out, int out_size, void* d_ws, size_t ws_size,
                              hipStream_t stream)
{
    const float* x_news = (const float*)d_in[0];
    const float* x_kw   = (const float*)d_in[1];
    const float* x_st   = (const float*)d_in[2];
    const float* Wn = (const float*)d_in[3];  const float* bn = (const float*)d_in[4];
    const float* Wk = (const float*)d_in[5];  const float* bk = (const float*)d_in[6];
    const float* Wst = (const float*)d_in[7]; const float* bs = (const float*)d_in[8];
    const float* W1l = (const float*)d_in[9];  const float* b1 = (const float*)d_in[10];
    const float* W1r = (const float*)d_in[11];
    const float* W2l = (const float*)d_in[12]; const float* b2 = (const float*)d_in[13];
    const float* W2r = (const float*)d_in[14];
    const float* DW1 = (const float*)d_in[15]; const float* Db1 = (const float*)d_in[16];
    const float* DW2 = (const float*)d_in[17]; const float* Db2 = (const float*)d_in[18];
    const int* e_hk_src = (const int*)d_in[19];
    const int* e_hk_dst = (const int*)d_in[20];
    const int* e_hs_src = (const int*)d_in[21];
    const int* e_hs_dst = (const int*)d_in[22];
    const int* l_hk_src = (const int*)d_in[23];
    const int* l_hk_dst = (const int*)d_in[24];
    const int* l_hs_src = (const int*)d_in[25];
    const int* l_hs_dst = (const int*)d_in[26];
    float* out = (float*)d_out;

    // ---- workspace layout (bytes, 16B aligned) ----
    char* base = (char*)d_ws;
    auto alloc = [&](size_t bytes) -> char* {
        char* p = base;
        base += (bytes + 15) & ~(size_t)15;
        return p;
    };
    auto aplane = [&](size_t elems) -> u16* { return (u16*)alloc(elems * 2); };

    u16* HNh = aplane((size_t)N_NEWS * HID);  u16* HNl = aplane((size_t)N_NEWS * HID);
    u16* HKh = aplane((size_t)N_KW * HID);    u16* HKl = aplane((size_t)N_KW * HID);
    u16* HSh = aplane((size_t)N_ST * HID);    u16* HSl = aplane((size_t)N_ST * HID);
    u16* K1h = aplane((size_t)N_KW * HID);    u16* K1l = aplane((size_t)N_KW * HID);
    u16* S1h = aplane((size_t)N_ST * HID);    u16* S1l = aplane((size_t)N_ST * HID);
    u16* PAh = aplane((size_t)N_KW * HID);    u16* PAl = aplane((size_t)N_KW * HID);
    u16* N1h = aplane((size_t)N_NEWS * HID);  u16* N1l = aplane((size_t)N_NEWS * HID);
    // weight planes
    u16* WnH = aplane(196608);  u16* WnL = aplane(196608);
    u16* WkH = aplane(32768);   u16* WkL = aplane(32768);
    u16* WsH = aplane(16384);   u16* WsL = aplane(16384);
    u16* CW1KH = aplane(131072); u16* CW1KL = aplane(131072);  // [256][512] W1l0|W1r0
    u16* CW1SH = aplane(131072); u16* CW1SL = aplane(131072);  // [256][512] W1l2|W1r2
    u16* W1l1H = aplane(65536);  u16* W1l1L = aplane(65536);
    u16* W1l3H = aplane(65536);  u16* W1l3L = aplane(65536);
    u16* SW1H = aplane(65536);   u16* SW1L = aplane(65536);    // W1r1+W1r3
    u16* CW2KH = aplane(65536);  u16* CW2KL = aplane(65536);   // [128][512] W2l0|W2r0
    u16* CW2SH = aplane(65536);  u16* CW2SL = aplane(65536);   // [128][512] W2l2|W2r2
    u16* W2l1H = aplane(32768);  u16* W2l1L = aplane(32768);
    u16* W2l3H = aplane(32768);  u16* W2l3L = aplane(32768);
    u16* SW2H = aplane(32768);   u16* SW2L = aplane(32768);    // W2r1+W2r3
    u16* DW1H = aplane(65536);   u16* DW1L = aplane(65536);
    float* BS1 = (float*)alloc(256 * 4);
    float* BS2 = (float*)alloc(128 * 4);
    // int pools
    int* deg = (int*)alloc((size_t)NTOT * 4);
    int* cur = (int*)alloc((size_t)NTOT * 4);
    u16* adj = (u16*)alloc((size_t)2 * (E_HK + E_HS) * 2);
    int* bsum = (int*)alloc(512 * 4);

    // overlays: layer-2 outputs reuse the HN region (dead after layer 1)
    u16* K2h = HNh;
    u16* K2l = K2h + (size_t)N_KW * OUTD;
    u16* N2h = K2l + (size_t)N_KW * OUTD;
    u16* N2l = N2h + (size_t)N_NEWS * OUTD;
    u16* S2h = N2l + (size_t)N_NEWS * OUTD;
    u16* S2l = S2h + (size_t)N_ST * OUTD;

    // ---- CSR build ----
    hipMemsetAsync(deg, 0, (size_t)NTOT * sizeof(int), stream);
    int etot = E_HK + E_HS;
    count_all_kernel<<<(etot + 255) / 256, 256, 0, stream>>>(e_hk_src, e_hk_dst, e_hs_src, e_hs_dst, deg);
    int nb = (NTOT + 255) / 256; // 438
    scan_block_kernel<<<nb, 256, 0, stream>>>(deg, cur, bsum, NTOT);
    scan2_kernel<<<1, 512, 0, stream>>>(bsum, nb);
    scan_add_kernel<<<nb, 256, 0, stream>>>(cur, bsum, NTOT);
    fill_all_kernel<<<(etot + 255) / 256, 256, 0, stream>>>(e_hk_src, e_hk_dst, e_hs_src, e_hs_dst, cur, adj);

    // ---- batched weight conversion ----
    {
        SplitJobs J{};
        int nj = 0, blocks = 0;
        auto job = [&](const float* a, const float* b, u16* hi, u16* lo, int n, int ncols, int dstride) {
            J.a[nj] = a; J.b[nj] = b; J.hi[nj] = hi; J.lo[nj] = lo;
            J.n[nj] = n; J.ncols[nj] = ncols; J.dstride[nj] = dstride;
            J.boff[nj] = blocks;
            blocks += (n / 4 + 255) / 256;
            ++nj;
        };
        job(Wn, nullptr, WnH, WnL, 196608, 196608, 196608);
        job(Wk, nullptr, WkH, WkL, 32768, 32768, 32768);
        job(Wst, nullptr, WsH, WsL, 16384, 16384, 16384);
        job(W1l + 0 * 65536, nullptr, CW1KH, CW1KL, 65536, 256, 512);
        job(W1r + 0 * 65536, nullptr, CW1KH + 256, CW1KL + 256, 65536, 256, 512);
        job(W1l + 2 * 65536, nullptr, CW1SH, CW1SL, 65536, 256, 512);
        job(W1r + 2 * 65536, nullptr, CW1SH + 256, CW1SL + 256, 65536, 256, 512);
        job(W1l + 1 * 65536, nullptr, W1l1H, W1l1L, 65536, 65536, 65536);
        job(W1l + 3 * 65536, nullptr, W1l3H, W1l3L, 65536, 65536, 65536);
        job(W1r + 1 * 65536, W1r + 3 * 65536, SW1H, SW1L, 65536, 65536, 65536);
        job(W2l + 0 * 32768, nullptr, CW2KH, CW2KL, 32768, 256, 512);
        job(W2r + 0 * 32768, nullptr, CW2KH + 256, CW2KL + 256, 32768, 256, 512);
        job(W2l + 2 * 32768, nullptr, CW2SH, CW2SL, 32768, 256, 512);
        job(W2r + 2 * 32768, nullptr, CW2SH + 256, CW2SL + 256, 32768, 256, 512);
        job(W2l + 1 * 32768, nullptr, W2l1H, W2l1L, 32768, 32768, 32768);
        job(W2l + 3 * 32768, nullptr, W2l3H, W2l3L, 32768, 32768, 32768);
        job(W2r + 1 * 32768, W2r + 3 * 32768, SW2H, SW2L, 32768, 32768, 32768);
        job(DW1, nullptr, DW1H, DW1L, 65536, 65536, 65536);
        J.boff[nj] = blocks;
        J.njobs = nj;
        split_all_kernel<<<blocks, 256, 0, stream>>>(J);
    }
    bias_sum_kernel<<<2, 256, 0, stream>>>(b1, b2, BS1, BS2);

    // ---- GEMM wrappers ----
    auto gemmF = [&](const float* A, int lda, const u16* Bh, const u16* Bl, int ldw,
                     const float* bias, u16* Ch, u16* Cl, int ldc,
                     int M, int N, int K, int flags) {
        dim3 g((M + 127) / 128, N / 128);
        gemm_kernel<0, 0, false><<<g, 256, 0, stream>>>(
            A, nullptr, nullptr, nullptr, nullptr, nullptr, nullptr, lda, 0,
            Bh, Bl, ldw, bias, Ch, Cl, ldc, nullptr, nullptr, nullptr, M, K, flags);
    };
    auto gemmP = [&](const u16* Ahp, const u16* Alp, int lda, const u16* Bh, const u16* Bl, int ldw,
                     const float* bias, u16* Ch, u16* Cl, int ldc,
                     int M, int N, int K, int flags) {
        dim3 g((M + 127) / 128, N / 128);
        gemm_kernel<1, 0, false><<<g, 256, 0, stream>>>(
            nullptr, Ahp, Alp, nullptr, nullptr, nullptr, nullptr, lda, 0,
            Bh, Bl, ldw, bias, Ch, Cl, ldc, nullptr, nullptr, nullptr, M, K, flags);
    };
    auto gemm2 = [&](const u16* A1hp, const u16* A1lp, const u16* A2hp, const u16* A2lp,
                     int lda, int kpiv, const u16* Bh, const u16* Bl, int ldw,
                     const float* bias, u16* Ch, u16* Cl, int ldc,
                     int M, int N, int K, int flags) {
        dim3 g((M + 127) / 128, N / 128);
        gemm_kernel<2, 0, false><<<g, 256, 0, stream>>>(
            nullptr, A1hp, A1lp, A2hp, A2lp, nullptr, nullptr, lda, kpiv,
            Bh, Bl, ldw, bias, Ch, Cl, ldc, nullptr, nullptr, nullptr, M, K, flags);
    };
    auto gemmLP = [&](const u16* Ahp, int lda, const u16* Bh, int ldw,
                      u16* Ch, int ldc, int M, int N, int K) {
        dim3 g((M + 127) / 128, N / 128);
        gemm_kernel<1, 1, true><<<g, 256, 0, stream>>>(
            nullptr, Ahp, nullptr, nullptr, nullptr, nullptr, nullptr, lda, 0,
            Bh, nullptr, ldw, nullptr, Ch, nullptr, ldc, nullptr, nullptr, nullptr, M, K, 0);
    };
    auto gemmD = [&](const u16* A1hp, const u16* A1lp, const u16* A2hp, const u16* A2lp,
                     const int* r1, const int* r2,
                     const u16* Bh, const u16* Bl,
                     const float* bias, const float* dw2, const float* db2, float* ov) {
        dim3 g((E_LBL + 127) / 128, 1);
        gemm_kernel<2, 2, false><<<g, 256, 0, stream>>>(
            nullptr, A1hp, A1lp, A2hp, A2lp, r1, r2, 128, 128,
            Bh, Bl, 256, bias, nullptr, nullptr, 0, dw2, db2, ov, E_LBL, 256, 0);
    };

    // ---- input projections ----
    gemmF(x_news, F_NEWS, WnH, WnL, F_NEWS, bn, HNh, HNl, HID, N_NEWS, HID, F_NEWS, FLAG_RELU);
    gemmF(x_kw,   F_KW,   WkH, WkL, F_KW,   bk, HKh, HKl, HID, N_KW,   HID, F_KW,   FLAG_RELU);
    gemmF(x_st,   F_ST,   WsH, WsL, F_ST,   bs, HSh, HSl, HID, N_ST,   HID, F_ST,   FLAG_RELU);

    // ---- layer 1 ----
    // k1 = relu([mean_A(hn) | hk] @ [W1l0|W1r0]^T + b1[0])
    gather_mean_kernel<256><<<(N_KW + 7) / 8, 256, 0, stream>>>(HNh, cur + OFFA, deg + OFFA, adj, PAh, PAl, N_KW);
    gemm2(PAh, PAl, HKh, HKl, HID, 256, CW1KH, CW1KL, 512, b1, K1h, K1l, HID, N_KW, HID, 512, FLAG_RELU);
    // s1
    gather_mean_kernel<256><<<(N_ST + 7) / 8, 256, 0, stream>>>(HNh, cur + OFFB, deg + OFFB, adj, PAh, PAl, N_ST);
    gemm2(PAh, PAl, HSh, HSl, HID, 256, CW1SH, CW1SL, 512, b1 + 2 * 256, S1h, S1l, HID, N_ST, HID, 512, FLAG_RELU);
    // n1: project small sources (hi-only), r-term GEMM, fused gather-assembly
    gemmLP(HKh, HID, W1l1H, HID, PAh, HID, N_KW, HID, HID);   // PP
    gemmLP(HSh, HID, W1l3H, HID, PAl, HID, N_ST, HID, HID);   // PP2
    gemmP(HNh, HNl, HID, SW1H, SW1L, HID, BS1, N1h, N1l, HID, N_NEWS, HID, HID, 0);
    fuse_news_kernel<256, true><<<(N_NEWS + 7) / 8, 256, 0, stream>>>(
        PAh, PAl, cur + OFFC, deg + OFFC, cur + OFFD, deg + OFFD, adj, N1h, N1l, N_NEWS);

    // ---- layer 2 ----
    gather_mean_kernel<256><<<(N_KW + 7) / 8, 256, 0, stream>>>(N1h, cur + OFFA, deg + OFFA, adj, PAh, PAl, N_KW);
    gemm2(PAh, PAl, K1h, K1l, HID, 256, CW2KH, CW2KL, 512, b2, K2h, K2l, OUTD, N_KW, OUTD, 512, 0);
    gather_mean_kernel<256><<<(N_ST + 7) / 8, 256, 0, stream>>>(N1h, cur + OFFB, deg + OFFB, adj, PAh, PAl, N_ST);
    gemm2(PAh, PAl, S1h, S1l, HID, 256, CW2SH, CW2SL, 512, b2 + 2 * 128, S2h, S2l, OUTD, N_ST, OUTD, 512, 0);
    gemmLP(K1h, HID, W2l1H, HID, PAh, OUTD, N_KW, OUTD, HID);  // PP (n2)
    gemmLP(S1h, HID, W2l3H, HID, PAl, OUTD, N_ST, OUTD, HID);  // PP2 (n2)
    gemmP(N1h, N1l, HID, SW2H, SW2L, HID, BS2, N2h, N2l, OUTD, N_NEWS, OUTD, HID, 0);
    fuse_news_kernel<128, false><<<(N_NEWS + 15) / 16, 256, 0, stream>>>(
        PAh, PAl, cur + OFFC, deg + OFFC, cur + OFFD, deg + OFFD, adj, N2h, N2l, N_NEWS);

    // ---- fused decoders ----
    gemmD(N2h, N2l, K2h, K2l, l_hk_src, l_hk_dst, DW1H, DW1L, Db1, DW2, Db2, out);
    gemmD(N2h, N2l, S2h, S2l, l_hs_src, l_hs_dst, DW1H + 32768, DW1L + 32768,
          Db1 + 128, DW2 + 128, Db2 + 1, out + E_LBL);
}

// Round 11
// 738.760 us; speedup vs baseline: 1.7047x; 1.1569x over previous
//
#include <hip/hip_runtime.h>
#include <hip/hip_bf16.h>

// ---------------- problem constants ----------------
constexpr int N_NEWS = 50000, N_KW = 10000, N_ST = 2000;
constexpr int F_NEWS = 768, F_KW = 128, F_ST = 64;
constexpr int HID = 256, OUTD = 128;
constexpr int E_HK = 500000, E_HS = 250000, E_LBL = 150000;

// CSR section offsets in the concatenated degree/cursor pools
constexpr int OFFA = 0;                    // e_hk keyed by dst (kw)
constexpr int OFFB = N_KW;                 // e_hs keyed by dst (st)
constexpr int OFFC = N_KW + N_ST;          // e_hk keyed by src (news)
constexpr int OFFD = OFFC + N_NEWS;        // e_hs keyed by src (news)
constexpr int NTOT = OFFD + N_NEWS;        // 112000

enum { FLAG_ACC = 1, FLAG_RELU = 2 };

typedef unsigned short u16;
typedef __attribute__((ext_vector_type(8))) short bf16x8;
typedef __attribute__((ext_vector_type(8))) unsigned short u16x8;
typedef __attribute__((ext_vector_type(4))) float f32x4;

__device__ __forceinline__ u16 f2bf(float x) {
    return __builtin_bit_cast(u16, __float2bfloat16(x));
}
__device__ __forceinline__ float bf2f(u16 h) {
    unsigned u = ((unsigned)h) << 16;
    return __builtin_bit_cast(float, u);
}
__device__ __forceinline__ void split2(float x, u16& h, u16& l) {
    h = f2bf(x);
    l = f2bf(x - bf2f(h));
}

// async global->LDS DMA, 16B per lane; LDS dest = wave-uniform base + lane*16
__device__ __forceinline__ void gload16(const void* g, void* s) {
    __builtin_amdgcn_global_load_lds(
        (const __attribute__((address_space(1))) void*)g,
        (__attribute__((address_space(3))) void*)s, 16, 0, 0);
}

// ---------------- split-bf16 MFMA GEMM, global_load_lds staging (m97 structure) --------
// ASRC: 0 = fp32 A (DMA fp32, split in regs), 1 = plane A, 2 = dual-table plane A
// WMODE: 0 = write hi+lo planes, 1 = hi only, 2 = fused decoder reduce -> outv
// LOWP: hi-plane-only operands, 1 MFMA/product (vs 3)
template<int ASRC, int WMODE, bool LOWP>
__global__ __launch_bounds__(256) void gemm_kernel(
    const float* __restrict__ Af,
    const u16* __restrict__ A1h, const u16* __restrict__ A1l,
    const u16* __restrict__ A2h, const u16* __restrict__ A2l,
    const int* __restrict__ ridx1, const int* __restrict__ ridx2, int lda, int kpiv,
    const u16* __restrict__ Bhg, const u16* __restrict__ Blg, int ldw,
    const float* __restrict__ bias,
    u16* __restrict__ Chi, u16* __restrict__ Clo, int ldc,
    const float* __restrict__ dw2, const float* __restrict__ db2,
    float* __restrict__ outv,
    int M, int K, int flags)
{
    constexpr int A_BYTES = (ASRC == 0) ? 16384 : (LOWP ? 8192 : 16384);
    constexpr int B_BYTES = LOWP ? 8192 : 16384;
    __shared__ __align__(16) char ldsraw[A_BYTES + B_BYTES];
    __shared__ float red[128];
    float* Af32 = (float*)ldsraw;
    u16* Ah = (u16*)ldsraw;
    u16* Al = (u16*)(ldsraw + 8192);
    u16* Bh = (u16*)(ldsraw + A_BYTES);
    u16* Bl = (u16*)(ldsraw + A_BYTES + 8192);

    const int tid = threadIdx.x;
    const int bm = blockIdx.x * 128;
    const int bn = blockIdx.y * 128;
    const int l = tid & 63;
    const int w = tid >> 6;
    const int wm = w >> 1, wn = w & 1;
    const int lg = l >> 4, lr = l & 15;

    const float* srcAf[4];
    const u16 *srcA1h[2], *srcA1l[2], *srcA2h[2], *srcA2l[2];
    const u16 *srcBh[2], *srcBl[2];
    float* dstAf[4];
    u16 *dstAh[2], *dstAl[2], *dstBh[2], *dstBl[2];

    if constexpr (ASRC == 0) {
        #pragma unroll
        for (int j = 0; j < 4; ++j) {
            int g = (w * 4 + j) * 64 + l;
            int r = g >> 3, cg = g & 7;
            int rg = bm + r; if (rg > M - 1) rg = M - 1;
            long ar = ridx1 ? (long)ridx1[rg] : (long)rg;
            srcAf[j] = Af + ar * lda + (cg ^ (r & 7)) * 4;
            dstAf[j] = Af32 + (w * 4 + j) * 256;
        }
    } else {
        #pragma unroll
        for (int j = 0; j < 2; ++j) {
            int g = (w * 2 + j) * 64 + l;
            int r = g >> 2, cg = g & 3;
            int rg = bm + r; if (rg > M - 1) rg = M - 1;
            int col = (cg ^ (r & 3)) * 8;
            long a1 = ridx1 ? (long)ridx1[rg] : (long)rg;
            srcA1h[j] = A1h + a1 * lda + col;
            if constexpr (!LOWP) srcA1l[j] = A1l + a1 * lda + col;
            if constexpr (ASRC == 2) {
                long a2 = ridx2 ? (long)ridx2[rg] : (long)rg;
                srcA2h[j] = A2h + a2 * lda + col - kpiv;
                if constexpr (!LOWP) srcA2l[j] = A2l + a2 * lda + col - kpiv;
            }
            dstAh[j] = Ah + (w * 2 + j) * 512;
            if constexpr (!LOWP) dstAl[j] = Al + (w * 2 + j) * 512;
        }
    }
    #pragma unroll
    for (int j = 0; j < 2; ++j) {
        int g = (w * 2 + j) * 64 + l;
        int r = g >> 2, cg = g & 3;
        int col = (cg ^ (r & 3)) * 8;
        srcBh[j] = Bhg + (long)(bn + r) * ldw + col;
        if constexpr (!LOWP) srcBl[j] = Blg + (long)(bn + r) * ldw + col;
        dstBh[j] = Bh + (w * 2 + j) * 512;
        if constexpr (!LOWP) dstBl[j] = Bl + (w * 2 + j) * 512;
    }

    auto ISSUE = [&](int k0) {
        if constexpr (ASRC == 0) {
            #pragma unroll
            for (int j = 0; j < 4; ++j) gload16(srcAf[j] + k0, dstAf[j]);
        } else if constexpr (ASRC == 1) {
            #pragma unroll
            for (int j = 0; j < 2; ++j) {
                gload16(srcA1h[j] + k0, dstAh[j]);
                if constexpr (!LOWP) gload16(srcA1l[j] + k0, dstAl[j]);
            }
        } else {
            bool first = k0 < kpiv;
            #pragma unroll
            for (int j = 0; j < 2; ++j) {
                gload16((first ? srcA1h[j] : srcA2h[j]) + k0, dstAh[j]);
                if constexpr (!LOWP) gload16((first ? srcA1l[j] : srcA2l[j]) + k0, dstAl[j]);
            }
        }
        #pragma unroll
        for (int j = 0; j < 2; ++j) {
            gload16(srcBh[j] + k0, dstBh[j]);
            if constexpr (!LOWP) gload16(srcBl[j] + k0, dstBl[j]);
        }
    };

    f32x4 acc[4][4];
    #pragma unroll
    for (int i = 0; i < 4; ++i)
        #pragma unroll
        for (int j = 0; j < 4; ++j) acc[i][j] = (f32x4){0.f, 0.f, 0.f, 0.f};

    bf16x8 fah[4], fal[4], fbh[4], fbl[4];
    float4 vaf[4][2];

    auto READ_FRAGS = [&]() {
        #pragma unroll
        for (int mt = 0; mt < 4; ++mt) {
            int r = wm * 64 + mt * 16 + lr;
            if constexpr (ASRC == 0) {
                int cg0 = (lg * 2) ^ (r & 7);
                int cg1 = (lg * 2 + 1) ^ (r & 7);
                vaf[mt][0] = *(const float4*)&Af32[r * 32 + cg0 * 4];
                vaf[mt][1] = *(const float4*)&Af32[r * 32 + cg1 * 4];
            } else {
                int cg = lg ^ (r & 3);
                fah[mt] = *(const bf16x8*)&Ah[r * 32 + cg * 8];
                if constexpr (!LOWP) fal[mt] = *(const bf16x8*)&Al[r * 32 + cg * 8];
            }
        }
        #pragma unroll
        for (int nt = 0; nt < 4; ++nt) {
            int r = wn * 64 + nt * 16 + lr;
            int cg = lg ^ (r & 3);
            fbh[nt] = *(const bf16x8*)&Bh[r * 32 + cg * 8];
            if constexpr (!LOWP) fbl[nt] = *(const bf16x8*)&Bl[r * 32 + cg * 8];
        }
    };

    auto COMPUTE = [&]() {
        if constexpr (ASRC == 0) {
            #pragma unroll
            for (int mt = 0; mt < 4; ++mt) {
                float vv[8] = {vaf[mt][0].x, vaf[mt][0].y, vaf[mt][0].z, vaf[mt][0].w,
                               vaf[mt][1].x, vaf[mt][1].y, vaf[mt][1].z, vaf[mt][1].w};
                bf16x8 h8, l8;
                #pragma unroll
                for (int q = 0; q < 8; ++q) {
                    u16 hh, ll; split2(vv[q], hh, ll);
                    h8[q] = (short)hh; l8[q] = (short)ll;
                }
                fah[mt] = h8; fal[mt] = l8;
            }
        }
        #pragma unroll
        for (int mt = 0; mt < 4; ++mt)
            #pragma unroll
            for (int nt = 0; nt < 4; ++nt) {
                acc[mt][nt] = __builtin_amdgcn_mfma_f32_16x16x32_bf16(fah[mt], fbh[nt], acc[mt][nt], 0, 0, 0);
                if constexpr (!LOWP) {
                    acc[mt][nt] = __builtin_amdgcn_mfma_f32_16x16x32_bf16(fah[mt], fbl[nt], acc[mt][nt], 0, 0, 0);
                    acc[mt][nt] = __builtin_amdgcn_mfma_f32_16x16x32_bf16(fal[mt], fbh[nt], acc[mt][nt], 0, 0, 0);
                }
            }
    };

    ISSUE(0);
    for (int k0 = 0; k0 < K; k0 += 32) {
        __syncthreads();                 // drain DMA for tile k0
        READ_FRAGS();
        __syncthreads();
        if (k0 + 32 < K) ISSUE(k0 + 32); // next tile flies during compute
        COMPUTE();
    }

    if constexpr (WMODE == 2) {
        if (tid < 128) red[tid] = 0.f;
        __syncthreads();
        float bv[4], dwv[4];
        #pragma unroll
        for (int nt = 0; nt < 4; ++nt) {
            int colg = wn * 64 + nt * 16 + lr;
            bv[nt] = bias[colg];
            dwv[nt] = dw2[colg];
        }
        #pragma unroll
        for (int mt = 0; mt < 4; ++mt)
            #pragma unroll
            for (int j = 0; j < 4; ++j) {
                float p = 0.f;
                #pragma unroll
                for (int nt = 0; nt < 4; ++nt)
                    p += fmaxf(acc[mt][nt][j] + bv[nt], 0.f) * dwv[nt];
                p += __shfl_xor(p, 1);
                p += __shfl_xor(p, 2);
                p += __shfl_xor(p, 4);
                p += __shfl_xor(p, 8);
                if (lr == 0) atomicAdd(&red[wm * 64 + mt * 16 + lg * 4 + j], p);
            }
        __syncthreads();
        if (tid < 128) {
            int row = bm + tid;
            if (row < M) outv[row] = red[tid] + db2[0];
        }
    } else {
        float bv[4];
        int col[4];
        #pragma unroll
        for (int nt = 0; nt < 4; ++nt) {
            col[nt] = bn + wn * 64 + nt * 16 + lr;
            bv[nt] = bias ? bias[col[nt]] : 0.f;
        }
        #pragma unroll
        for (int mt = 0; mt < 4; ++mt) {
            int row0 = bm + wm * 64 + mt * 16 + lg * 4;
            #pragma unroll
            for (int j = 0; j < 4; ++j) {
                int row = row0 + j;
                if (row >= M) continue;
                size_t rbase = (size_t)row * ldc;
                #pragma unroll
                for (int nt = 0; nt < 4; ++nt) {
                    size_t off = rbase + col[nt];
                    float v = acc[mt][nt][j] + bv[nt];
                    if (flags & FLAG_RELU) v = fmaxf(v, 0.f);
                    u16 hh, ll; split2(v, hh, ll);
                    Chi[off] = hh;
                    if constexpr (WMODE == 0) Clo[off] = ll;
                }
            }
        }
    }
}

// ---------------- CSR build (merged, sections A|B|C|D) ----------------
__global__ void count_all_kernel(const int* __restrict__ hks, const int* __restrict__ hkd,
                                 const int* __restrict__ hss, const int* __restrict__ hsd,
                                 int* __restrict__ deg)
{
    int e = blockIdx.x * blockDim.x + threadIdx.x;
    if (e < E_HK) {
        atomicAdd(deg + OFFA + hkd[e], 1);
        atomicAdd(deg + OFFC + hks[e], 1);
    } else if (e < E_HK + E_HS) {
        int i = e - E_HK;
        atomicAdd(deg + OFFB + hsd[i], 1);
        atomicAdd(deg + OFFD + hss[i], 1);
    }
}

__global__ void scan_block_kernel(const int* __restrict__ in, int* __restrict__ out,
                                  int* __restrict__ bsum, int n)
{
    __shared__ int tmp[256];
    int i = blockIdx.x * 256 + threadIdx.x;
    int v = (i < n) ? in[i] : 0;
    tmp[threadIdx.x] = v;
    __syncthreads();
    #pragma unroll
    for (int off = 1; off < 256; off <<= 1) {
        int t = (threadIdx.x >= off) ? tmp[threadIdx.x - off] : 0;
        __syncthreads();
        tmp[threadIdx.x] += t;
        __syncthreads();
    }
    if (i < n) out[i] = tmp[threadIdx.x] - v;
    if (threadIdx.x == 255 && bsum) bsum[blockIdx.x] = tmp[255];
}

__global__ void scan2_kernel(int* __restrict__ data, int n) // n <= 512, in-place exclusive
{
    __shared__ int tmp[512];
    int v = (threadIdx.x < n) ? data[threadIdx.x] : 0;
    tmp[threadIdx.x] = v;
    __syncthreads();
    #pragma unroll
    for (int off = 1; off < 512; off <<= 1) {
        int t = (threadIdx.x >= off) ? tmp[threadIdx.x - off] : 0;
        __syncthreads();
        tmp[threadIdx.x] += t;
        __syncthreads();
    }
    if (threadIdx.x < n) data[threadIdx.x] = tmp[threadIdx.x] - v;
}

__global__ void scan_add_kernel(int* __restrict__ out, const int* __restrict__ bsumex, int n)
{
    int i = blockIdx.x * 256 + threadIdx.x;
    if (i < n) out[i] += bsumex[blockIdx.x];
}

__global__ void fill_all_kernel(const int* __restrict__ hks, const int* __restrict__ hkd,
                                const int* __restrict__ hss, const int* __restrict__ hsd,
                                int* __restrict__ cur, u16* __restrict__ adj)
{
    int e = blockIdx.x * blockDim.x + threadIdx.x;
    if (e < E_HK) {
        int s = hks[e], d = hkd[e];
        int p = atomicAdd(cur + OFFA + d, 1); adj[p] = (u16)s;
        int q = atomicAdd(cur + OFFC + s, 1); adj[q] = (u16)d;
    } else if (e < E_HK + E_HS) {
        int i = e - E_HK;
        int s = hss[i], d = hsd[i];
        int p = atomicAdd(cur + OFFB + d, 1); adj[p] = (u16)s;
        int q = atomicAdd(cur + OFFD + s, 1); adj[q] = (u16)d;
    }
}

// ---------------- gather mean (hi-plane read; hi[+lo] write; 16B/lane) ----------------
template <int D, bool WRITELO>
__global__ void gather_mean_kernel(const u16* __restrict__ Xhi,
                                   const int* __restrict__ cur, const int* __restrict__ deg,
                                   const u16* __restrict__ adj,
                                   u16* __restrict__ Ohi, u16* __restrict__ Olo, int ndst)
{
    constexpr int LANES = D / 8;          // 16B per lane
    constexpr int RPB = 256 / LANES;
    int r = blockIdx.x * RPB + threadIdx.x / LANES;
    if (r >= ndst) return;
    int lane = threadIdx.x % LANES;
    int end = cur[r];
    int n = deg[r];
    int j = end - n;
    float s[8];
    #pragma unroll
    for (int q = 0; q < 8; ++q) s[q] = 0.f;
    for (; j + 1 < end; j += 2) {
        u16x8 a = *(const u16x8*)(Xhi + (size_t)adj[j] * D + lane * 8);
        u16x8 b = *(const u16x8*)(Xhi + (size_t)adj[j + 1] * D + lane * 8);
        #pragma unroll
        for (int q = 0; q < 8; ++q) s[q] += bf2f(a[q]) + bf2f(b[q]);
    }
    if (j < end) {
        u16x8 a = *(const u16x8*)(Xhi + (size_t)adj[j] * D + lane * 8);
        #pragma unroll
        for (int q = 0; q < 8; ++q) s[q] += bf2f(a[q]);
    }
    float inv = (n > 0) ? 1.0f / (float)n : 0.f;
    size_t off = (size_t)r * D + lane * 8;
    u16x8 h8, l8;
    #pragma unroll
    for (int q = 0; q < 8; ++q) { u16 hh, ll; split2(s[q] * inv, hh, ll); h8[q] = hh; l8[q] = ll; }
    *(u16x8*)(Ohi + off) = h8;
    if constexpr (WRITELO) *(u16x8*)(Olo + off) = l8;
}

// ---------------- fused news assembly: N += meanC(PP) + meanD(PP2); [relu] ----------------
template <int D, bool RELU, bool HASLO>
__global__ void fuse_news_kernel(const u16* __restrict__ PPh, const u16* __restrict__ PP2h,
                                 const int* __restrict__ curC, const int* __restrict__ degC,
                                 const int* __restrict__ curD, const int* __restrict__ degD,
                                 const u16* __restrict__ adj,
                                 u16* __restrict__ Nh, u16* __restrict__ Nl, int ndst)
{
    constexpr int LANES = D / 8;          // 16B per lane
    constexpr int RPB = 256 / LANES;
    int r = blockIdx.x * RPB + threadIdx.x / LANES;
    if (r >= ndst) return;
    int lane = threadIdx.x % LANES;
    float s[8];
    #pragma unroll
    for (int q = 0; q < 8; ++q) s[q] = 0.f;
    {
        int end = curC[r], n = degC[r];
        float a[8];
        #pragma unroll
        for (int q = 0; q < 8; ++q) a[q] = 0.f;
        for (int j = end - n; j < end; ++j) {
            u16x8 v = *(const u16x8*)(PPh + (size_t)adj[j] * D + lane * 8);
            #pragma unroll
            for (int q = 0; q < 8; ++q) a[q] += bf2f(v[q]);
        }
        float inv = (n > 0) ? 1.0f / (float)n : 0.f;
        #pragma unroll
        for (int q = 0; q < 8; ++q) s[q] += a[q] * inv;
    }
    {
        int end = curD[r], n = degD[r];
        float a[8];
        #pragma unroll
        for (int q = 0; q < 8; ++q) a[q] = 0.f;
        for (int j = end - n; j < end; ++j) {
            u16x8 v = *(const u16x8*)(PP2h + (size_t)adj[j] * D + lane * 8);
            #pragma unroll
            for (int q = 0; q < 8; ++q) a[q] += bf2f(v[q]);
        }
        float inv = (n > 0) ? 1.0f / (float)n : 0.f;
        #pragma unroll
        for (int q = 0; q < 8; ++q) s[q] += a[q] * inv;
    }
    size_t off = (size_t)r * D + lane * 8;
    u16x8 h = *(const u16x8*)(Nh + off);
    if constexpr (HASLO) {
        u16x8 l = *(const u16x8*)(Nl + off);
        #pragma unroll
        for (int q = 0; q < 8; ++q) s[q] += bf2f(h[q]) + bf2f(l[q]);
    } else {
        #pragma unroll
        for (int q = 0; q < 8; ++q) s[q] += bf2f(h[q]);
    }
    #pragma unroll
    for (int q = 0; q < 8; ++q) {
        float v = s[q];
        if (RELU) v = fmaxf(v, 0.f);
        s[q] = v;
    }
    u16x8 oh, ol;
    #pragma unroll
    for (int q = 0; q < 8; ++q) { u16 hh, ll; split2(s[q], hh, ll); oh[q] = hh; ol[q] = ll; }
    *(u16x8*)(Nh + off) = oh;
    if constexpr (HASLO) *(u16x8*)(Nl + off) = ol;
}

// ---------------- batched weight split/convert ----------------
#define MAXJOBS 20
struct SplitJobs {
    const float* a[MAXJOBS];
    const float* b[MAXJOBS];     // optional second operand (summed)
    u16* hi[MAXJOBS];
    u16* lo[MAXJOBS];
    int n[MAXJOBS];
    int ncols[MAXJOBS];          // source row width
    int dstride[MAXJOBS];        // dest row stride
    int boff[MAXJOBS + 1];
    int njobs;
};

__global__ void split_all_kernel(SplitJobs J)
{
    int bid = blockIdx.x;
    int j = 0;
    while (j + 1 < J.njobs && bid >= J.boff[j + 1]) ++j;
    int i = (bid - J.boff[j]) * 1024 + threadIdx.x * 4;
    if (i >= J.n[j]) return;
    float4 v = *(const float4*)(J.a[j] + i);
    if (J.b[j]) {
        float4 w = *(const float4*)(J.b[j] + i);
        v.x += w.x; v.y += w.y; v.z += w.z; v.w += w.w;
    }
    int row = i / J.ncols[j], col = i - row * J.ncols[j];
    size_t d = (size_t)row * J.dstride[j] + col;
    ushort4 h, l;
    split2(v.x, h.x, l.x); split2(v.y, h.y, l.y); split2(v.z, h.z, l.z); split2(v.w, h.w, l.w);
    *(ushort4*)(J.hi[j] + d) = h;
    *(ushort4*)(J.lo[j] + d) = l;
}

__global__ void bias_sum_kernel(const float* __restrict__ b1, const float* __restrict__ b2,
                                float* __restrict__ BS1, float* __restrict__ BS2)
{
    int i = blockIdx.x * 256 + threadIdx.x;
    if (i < 256) BS1[i] = b1[256 + i] + b1[768 + i];
    else if (i < 384) { int j = i - 256; BS2[j] = b2[128 + j] + b2[384 + j]; }
}

// ---------------- launch ----------------
extern "C" void kernel_launch(void* const* d_in, const int* in_sizes, int n_in,
                              void* d_out, int out_size, void* d_ws, size_t ws_size,
                              hipStream_t stream)
{
    const float* x_news = (const float*)d_in[0];
    const float* x_kw   = (const float*)d_in[1];
    const float* x_st   = (const float*)d_in[2];
    const float* Wn = (const float*)d_in[3];  const float* bn = (const float*)d_in[4];
    const float* Wk = (const float*)d_in[5];  const float* bk = (const float*)d_in[6];
    const float* Wst = (const float*)d_in[7]; const float* bs = (const float*)d_in[8];
    const float* W1l = (const float*)d_in[9];  const float* b1 = (const float*)d_in[10];
    const float* W1r = (const float*)d_in[11];
    const float* W2l = (const float*)d_in[12]; const float* b2 = (const float*)d_in[13];
    const float* W2r = (const float*)d_in[14];
    const float* DW1 = (const float*)d_in[15]; const float* Db1 = (const float*)d_in[16];
    const float* DW2 = (const float*)d_in[17]; const float* Db2 = (const float*)d_in[18];
    const int* e_hk_src = (const int*)d_in[19];
    const int* e_hk_dst = (const int*)d_in[20];
    const int* e_hs_src = (const int*)d_in[21];
    const int* e_hs_dst = (const int*)d_in[22];
    const int* l_hk_src = (const int*)d_in[23];
    const int* l_hk_dst = (const int*)d_in[24];
    const int* l_hs_src = (const int*)d_in[25];
    const int* l_hs_dst = (const int*)d_in[26];
    float* out = (float*)d_out;

    // ---- workspace layout (bytes, 16B aligned) ----
    char* base = (char*)d_ws;
    auto alloc = [&](size_t bytes) -> char* {
        char* p = base;
        base += (bytes + 15) & ~(size_t)15;
        return p;
    };
    auto aplane = [&](size_t elems) -> u16* { return (u16*)alloc(elems * 2); };

    u16* HNh = aplane((size_t)N_NEWS * HID);  u16* HNl = aplane((size_t)N_NEWS * HID);
    u16* HKh = aplane((size_t)N_KW * HID);    u16* HKl = aplane((size_t)N_KW * HID);
    u16* HSh = aplane((size_t)N_ST * HID);    u16* HSl = aplane((size_t)N_ST * HID);
    u16* K1h = aplane((size_t)N_KW * HID);
    u16* S1h = aplane((size_t)N_ST * HID);
    u16* PAh = aplane((size_t)(N_KW + N_ST) * HID);   // 12000 rows (kw | st sections)
    u16* PAl = aplane((size_t)(N_KW + N_ST) * HID);
    u16* N1h = aplane((size_t)N_NEWS * HID);
    // weight planes
    u16* WnH = aplane(196608);  u16* WnL = aplane(196608);
    u16* WkH = aplane(32768);   u16* WkL = aplane(32768);
    u16* WsH = aplane(16384);   u16* WsL = aplane(16384);
    u16* CW1KH = aplane(131072); u16* CW1KL = aplane(131072);  // [256][512] W1l0|W1r0
    u16* CW1SH = aplane(131072); u16* CW1SL = aplane(131072);  // [256][512] W1l2|W1r2
    u16* W1l1H = aplane(65536);  u16* W1l1L = aplane(65536);
    u16* W1l3H = aplane(65536);  u16* W1l3L = aplane(65536);
    u16* SW1H = aplane(65536);   u16* SW1L = aplane(65536);    // W1r1+W1r3
    u16* CW2KH = aplane(65536);  u16* CW2KL = aplane(65536);   // [128][512] W2l0|W2r0
    u16* CW2SH = aplane(65536);  u16* CW2SL = aplane(65536);   // [128][512] W2l2|W2r2
    u16* W2l1H = aplane(32768);  u16* W2l1L = aplane(32768);
    u16* W2l3H = aplane(32768);  u16* W2l3L = aplane(32768);
    u16* SW2H = aplane(32768);   u16* SW2L = aplane(32768);    // W2r1+W2r3
    u16* DW1H = aplane(65536);   u16* DW1L = aplane(65536);
    float* BS1 = (float*)alloc(256 * 4);
    float* BS2 = (float*)alloc(128 * 4);
    // int pools
    int* deg = (int*)alloc((size_t)NTOT * 4);
    int* cur = (int*)alloc((size_t)NTOT * 4);
    u16* adj = (u16*)alloc((size_t)2 * (E_HK + E_HS) * 2);
    int* bsum = (int*)alloc(512 * 4);

    // overlays: layer-2 outputs reuse the HN region (dead after layer 1)
    u16* K2h = HNh;
    u16* N2h = K2h + (size_t)N_KW * OUTD;
    u16* S2h = N2h + (size_t)N_NEWS * OUTD;

    // ---- CSR build ----
    hipMemsetAsync(deg, 0, (size_t)NTOT * sizeof(int), stream);
    int etot = E_HK + E_HS;
    count_all_kernel<<<(etot + 255) / 256, 256, 0, stream>>>(e_hk_src, e_hk_dst, e_hs_src, e_hs_dst, deg);
    int nb = (NTOT + 255) / 256; // 438
    scan_block_kernel<<<nb, 256, 0, stream>>>(deg, cur, bsum, NTOT);
    scan2_kernel<<<1, 512, 0, stream>>>(bsum, nb);
    scan_add_kernel<<<nb, 256, 0, stream>>>(cur, bsum, NTOT);
    fill_all_kernel<<<(etot + 255) / 256, 256, 0, stream>>>(e_hk_src, e_hk_dst, e_hs_src, e_hs_dst, cur, adj);

    // ---- batched weight conversion ----
    {
        SplitJobs J{};
        int nj = 0, blocks = 0;
        auto job = [&](const float* a, const float* b, u16* hi, u16* lo, int n, int ncols, int dstride) {
            J.a[nj] = a; J.b[nj] = b; J.hi[nj] = hi; J.lo[nj] = lo;
            J.n[nj] = n; J.ncols[nj] = ncols; J.dstride[nj] = dstride;
            J.boff[nj] = blocks;
            blocks += (n / 4 + 255) / 256;
            ++nj;
        };
        job(Wn, nullptr, WnH, WnL, 196608, 196608, 196608);
        job(Wk, nullptr, WkH, WkL, 32768, 32768, 32768);
        job(Wst, nullptr, WsH, WsL, 16384, 16384, 16384);
        job(W1l + 0 * 65536, nullptr, CW1KH, CW1KL, 65536, 256, 512);
        job(W1r + 0 * 65536, nullptr, CW1KH + 256, CW1KL + 256, 65536, 256, 512);
        job(W1l + 2 * 65536, nullptr, CW1SH, CW1SL, 65536, 256, 512);
        job(W1r + 2 * 65536, nullptr, CW1SH + 256, CW1SL + 256, 65536, 256, 512);
        job(W1l + 1 * 65536, nullptr, W1l1H, W1l1L, 65536, 65536, 65536);
        job(W1l + 3 * 65536, nullptr, W1l3H, W1l3L, 65536, 65536, 65536);
        job(W1r + 1 * 65536, W1r + 3 * 65536, SW1H, SW1L, 65536, 65536, 65536);
        job(W2l + 0 * 32768, nullptr, CW2KH, CW2KL, 32768, 256, 512);
        job(W2r + 0 * 32768, nullptr, CW2KH + 256, CW2KL + 256, 32768, 256, 512);
        job(W2l + 2 * 32768, nullptr, CW2SH, CW2SL, 32768, 256, 512);
        job(W2r + 2 * 32768, nullptr, CW2SH + 256, CW2SL + 256, 32768, 256, 512);
        job(W2l + 1 * 32768, nullptr, W2l1H, W2l1L, 32768, 32768, 32768);
        job(W2l + 3 * 32768, nullptr, W2l3H, W2l3L, 32768, 32768, 32768);
        job(W2r + 1 * 32768, W2r + 3 * 32768, SW2H, SW2L, 32768, 32768, 32768);
        job(DW1, nullptr, DW1H, DW1L, 65536, 65536, 65536);
        J.boff[nj] = blocks;
        J.njobs = nj;
        split_all_kernel<<<blocks, 256, 0, stream>>>(J);
    }
    bias_sum_kernel<<<2, 256, 0, stream>>>(b1, b2, BS1, BS2);

    // ---- GEMM wrappers ----
    // full-precision fp32-A projection, write hi+lo
    auto gemmF = [&](const float* A, int lda, const u16* Bh, const u16* Bl, int ldw,
                     const float* bias, u16* Ch, u16* Cl, int ldc,
                     int M, int N, int K, int flags) {
        dim3 g((M + 127) / 128, N / 128);
        gemm_kernel<0, 0, false><<<g, 256, 0, stream>>>(
            A, nullptr, nullptr, nullptr, nullptr, nullptr, nullptr, lda, 0,
            Bh, Bl, ldw, bias, Ch, Cl, ldc, nullptr, nullptr, nullptr, M, K, flags);
    };
    // full-precision plane GEMM, write hi only
    auto gemmP1 = [&](const u16* Ahp, const u16* Alp, int lda, const u16* Bh, const u16* Bl, int ldw,
                      const float* bias, u16* Ch, int ldc,
                      int M, int N, int K, int flags) {
        dim3 g((M + 127) / 128, N / 128);
        gemm_kernel<1, 1, false><<<g, 256, 0, stream>>>(
            nullptr, Ahp, Alp, nullptr, nullptr, nullptr, nullptr, lda, 0,
            Bh, Bl, ldw, bias, Ch, nullptr, ldc, nullptr, nullptr, nullptr, M, K, flags);
    };
    // full-precision dual-table GEMM, write hi only
    auto gemm21 = [&](const u16* A1hp, const u16* A1lp, const u16* A2hp, const u16* A2lp,
                      int lda, int kpiv, const u16* Bh, const u16* Bl, int ldw,
                      const float* bias, u16* Ch, int ldc,
                      int M, int N, int K, int flags) {
        dim3 g((M + 127) / 128, N / 128);
        gemm_kernel<2, 1, false><<<g, 256, 0, stream>>>(
            nullptr, A1hp, A1lp, A2hp, A2lp, nullptr, nullptr, lda, kpiv,
            Bh, Bl, ldw, bias, Ch, nullptr, ldc, nullptr, nullptr, nullptr, M, K, flags);
    };
    // LOWP plane GEMM (1 MFMA), write hi only
    auto gemmLP = [&](const u16* Ahp, int lda, const u16* Bh, int ldw,
                      const float* bias, u16* Ch, int ldc, int M, int N, int K, int flags) {
        dim3 g((M + 127) / 128, N / 128);
        gemm_kernel<1, 1, true><<<g, 256, 0, stream>>>(
            nullptr, Ahp, nullptr, nullptr, nullptr, nullptr, nullptr, lda, 0,
            Bh, nullptr, ldw, bias, Ch, nullptr, ldc, nullptr, nullptr, nullptr, M, K, flags);
    };
    // LOWP dual-table GEMM (1 MFMA), write hi only
    auto gemmL2 = [&](const u16* A1hp, const u16* A2hp, int lda, int kpiv,
                      const u16* Bh, int ldw, const float* bias, u16* Ch, int ldc,
                      int M, int N, int K, int flags) {
        dim3 g((M + 127) / 128, N / 128);
        gemm_kernel<2, 1, true><<<g, 256, 0, stream>>>(
            nullptr, A1hp, nullptr, A2hp, nullptr, nullptr, nullptr, lda, kpiv,
            Bh, nullptr, ldw, bias, Ch, nullptr, ldc, nullptr, nullptr, nullptr, M, K, flags);
    };
    // LOWP fused decoder (1 MFMA): gathered dual-table A, reduce -> outv
    auto gemmD = [&](const u16* A1hp, const u16* A2hp,
                     const int* r1, const int* r2, const u16* Bh,
                     const float* bias, const float* dw2, const float* db2, float* ov) {
        dim3 g((E_LBL + 127) / 128, 1);
        gemm_kernel<2, 2, true><<<g, 256, 0, stream>>>(
            nullptr, A1hp, nullptr, A2hp, nullptr, r1, r2, 128, 128,
            Bh, nullptr, 256, bias, nullptr, nullptr, 0, dw2, db2, ov, E_LBL, 256, 0);
    };

    // ---- input projections (full precision, hi+lo outputs) ----
    gemmF(x_news, F_NEWS, WnH, WnL, F_NEWS, bn, HNh, HNl, HID, N_NEWS, HID, F_NEWS, FLAG_RELU);
    gemmF(x_kw,   F_KW,   WkH, WkL, F_KW,   bk, HKh, HKl, HID, N_KW,   HID, F_KW,   FLAG_RELU);
    gemmF(x_st,   F_ST,   WsH, WsL, F_ST,   bs, HSh, HSl, HID, N_ST,   HID, F_ST,   FLAG_RELU);

    // ---- layer 1 (full-precision compute, hi-only storage) ----
    // merged gather for kw (rows 0..9999) and st (rows 10000..11999)
    gather_mean_kernel<256, true><<<(N_KW + N_ST + 7) / 8, 256, 0, stream>>>(
        HNh, cur + OFFA, deg + OFFA, adj, PAh, PAl, N_KW + N_ST);
    // k1 = relu([mean_A(hn) | hk] @ [W1l0|W1r0]^T + b1[0])
    gemm21(PAh, PAl, HKh, HKl, HID, 256, CW1KH, CW1KL, 512, b1, K1h, HID, N_KW, HID, 512, FLAG_RELU);
    // s1
    gemm21(PAh + (size_t)N_KW * HID, PAl + (size_t)N_KW * HID, HSh, HSl, HID, 256,
           CW1SH, CW1SL, 512, b1 + 2 * 256, S1h, HID, N_ST, HID, 512, FLAG_RELU);
    // n1: project small sources (hi-only), r-term GEMM, fused gather-assembly
    gemmLP(HKh, HID, W1l1H, HID, nullptr, PAh, HID, N_KW, HID, HID, 0);   // PP
    gemmLP(HSh, HID, W1l3H, HID, nullptr, PAl, HID, N_ST, HID, HID, 0);   // PP2
    gemmP1(HNh, HNl, HID, SW1H, SW1L, HID, BS1, N1h, HID, N_NEWS, HID, HID, 0);
    fuse_news_kernel<256, true, false><<<(N_NEWS + 7) / 8, 256, 0, stream>>>(
        PAh, PAl, cur + OFFC, deg + OFFC, cur + OFFD, deg + OFFD, adj, N1h, nullptr, N_NEWS);

    // ---- layer 2 (LOWP: hi-only, 1 MFMA) ----
    gather_mean_kernel<256, false><<<(N_KW + N_ST + 7) / 8, 256, 0, stream>>>(
        N1h, cur + OFFA, deg + OFFA, adj, PAh, nullptr, N_KW + N_ST);
    gemmL2(PAh, K1h, HID, 256, CW2KH, 512, b2, K2h, OUTD, N_KW, OUTD, 512, 0);
    gemmL2(PAh + (size_t)N_KW * HID, S1h, HID, 256, CW2SH, 512, b2 + 2 * 128, S2h, OUTD, N_ST, OUTD, 512, 0);
    gemmLP(K1h, HID, W2l1H, HID, nullptr, PAh, OUTD, N_KW, OUTD, HID, 0);  // PP (n2)
    gemmLP(S1h, HID, W2l3H, HID, nullptr, PAl, OUTD, N_ST, OUTD, HID, 0);  // PP2 (n2)
    gemmLP(N1h, HID, SW2H, HID, BS2, N2h, OUTD, N_NEWS, OUTD, HID, 0);
    fuse_news_kernel<128, false, false><<<(N_NEWS + 15) / 16, 256, 0, stream>>>(
        PAh, PAl, cur + OFFC, deg + OFFC, cur + OFFD, deg + OFFD, adj, N2h, nullptr, N_NEWS);

    // ---- fused decoders (LOWP) ----
    gemmD(N2h, K2h, l_hk_src, l_hk_dst, DW1H, Db1, DW2, Db2, out);
    gemmD(N2h, S2h, l_hs_src, l_hs_dst, DW1H + 32768, Db1 + 128, DW2 + 128, Db2 + 1, out + E_LBL);
}

// Round 12
// 738.413 us; speedup vs baseline: 1.7055x; 1.0005x over previous
//
#include <hip/hip_runtime.h>
#include <hip/hip_bf16.h>

// ---------------- problem constants ----------------
constexpr int N_NEWS = 50000, N_KW = 10000, N_ST = 2000;
constexpr int F_NEWS = 768, F_KW = 128, F_ST = 64;
constexpr int HID = 256, OUTD = 128;
constexpr int E_HK = 500000, E_HS = 250000, E_LBL = 150000;

// CSR section offsets in the concatenated degree/cursor pools
constexpr int OFFA = 0;                    // e_hk keyed by dst (kw)
constexpr int OFFB = N_KW;                 // e_hs keyed by dst (st)
constexpr int OFFC = N_KW + N_ST;          // e_hk keyed by src (news)
constexpr int OFFD = OFFC + N_NEWS;        // e_hs keyed by src (news)
constexpr int NTOT = OFFD + N_NEWS;        // 112000

enum { FLAG_ACC = 1, FLAG_RELU = 2 };

typedef unsigned short u16;
typedef __attribute__((ext_vector_type(8))) short bf16x8;
typedef __attribute__((ext_vector_type(8))) unsigned short u16x8;
typedef __attribute__((ext_vector_type(4))) float f32x4;

__device__ __forceinline__ u16 f2bf(float x) {
    return __builtin_bit_cast(u16, __float2bfloat16(x));
}
__device__ __forceinline__ float bf2f(u16 h) {
    unsigned u = ((unsigned)h) << 16;
    return __builtin_bit_cast(float, u);
}
__device__ __forceinline__ void split2(float x, u16& h, u16& l) {
    h = f2bf(x);
    l = f2bf(x - bf2f(h));
}

// async global->LDS DMA, 16B per lane; LDS dest = wave-uniform base + lane*16
__device__ __forceinline__ void gload16(const void* g, void* s) {
    __builtin_amdgcn_global_load_lds(
        (const __attribute__((address_space(1))) void*)g,
        (__attribute__((address_space(3))) void*)s, 16, 0, 0);
}

// one vmcnt(0) + raw barrier per K-tile (minimum 2-phase recipe; rule #18 pin)
#define PIPE_SYNC() do {                                   \
    asm volatile("s_waitcnt vmcnt(0)" ::: "memory");       \
    __builtin_amdgcn_s_barrier();                          \
    __builtin_amdgcn_sched_barrier(0);                     \
} while (0)

// ---------------- split-bf16 MFMA GEMM, dbuf LDS + counted-sync pipeline --------
// ASRC: 0 = fp32 A (DMA fp32, split in regs), 1 = plane A, 2 = dual-table plane A
// WMODE: 0 = write hi+lo planes, 1 = hi only, 2 = fused decoder reduce -> outv
// LOWP: hi-plane-only operands, 1 MFMA/product (vs 3)
template<int ASRC, int WMODE, bool LOWP>
__global__ __launch_bounds__(256) void gemm_kernel(
    const float* __restrict__ Af,
    const u16* __restrict__ A1h, const u16* __restrict__ A1l,
    const u16* __restrict__ A2h, const u16* __restrict__ A2l,
    const int* __restrict__ ridx1, const int* __restrict__ ridx2, int lda, int kpiv,
    const u16* __restrict__ Bhg, const u16* __restrict__ Blg, int ldw,
    const float* __restrict__ bias,
    u16* __restrict__ Chi, u16* __restrict__ Clo, int ldc,
    const float* __restrict__ dw2, const float* __restrict__ db2,
    float* __restrict__ outv,
    int M, int K, int flags)
{
    constexpr int A_BYTES = (ASRC == 0) ? 16384 : (LOWP ? 8192 : 16384);
    constexpr int B_BYTES = LOWP ? 8192 : 16384;
    constexpr int BUF_BYTES = A_BYTES + B_BYTES;
    __shared__ __align__(16) char ldsraw[2 * BUF_BYTES];
    __shared__ float red[128];

    const int tid = threadIdx.x;
    const int bm = blockIdx.x * 128;
    const int bn = blockIdx.y * 128;
    const int l = tid & 63;
    const int w = tid >> 6;
    const int wm = w >> 1, wn = w & 1;
    const int lg = l >> 4, lr = l & 15;

    // ---- per-thread DMA sources + in-buffer dest byte offsets ----
    const float* srcAf[4];
    const u16 *srcA1h[2], *srcA1l[2], *srcA2h[2], *srcA2l[2];
    const u16 *srcBh[2], *srcBl[2];
    int offAf[4], offAh[2], offAl[2], offBh[2], offBl[2];

    if constexpr (ASRC == 0) {
        #pragma unroll
        for (int j = 0; j < 4; ++j) {
            int g = (w * 4 + j) * 64 + l;
            int r = g >> 3, cg = g & 7;
            int rg = bm + r; if (rg > M - 1) rg = M - 1;
            long ar = ridx1 ? (long)ridx1[rg] : (long)rg;
            srcAf[j] = Af + ar * lda + (cg ^ (r & 7)) * 4;
            offAf[j] = (w * 4 + j) * 1024;           // 64 lanes * 16 B
        }
    } else {
        #pragma unroll
        for (int j = 0; j < 2; ++j) {
            int g = (w * 2 + j) * 64 + l;
            int r = g >> 2, cg = g & 3;
            int rg = bm + r; if (rg > M - 1) rg = M - 1;
            int col = (cg ^ (r & 3)) * 8;
            long a1 = ridx1 ? (long)ridx1[rg] : (long)rg;
            srcA1h[j] = A1h + a1 * lda + col;
            if constexpr (!LOWP) srcA1l[j] = A1l + a1 * lda + col;
            if constexpr (ASRC == 2) {
                long a2 = ridx2 ? (long)ridx2[rg] : (long)rg;
                srcA2h[j] = A2h + a2 * lda + col - kpiv;
                if constexpr (!LOWP) srcA2l[j] = A2l + a2 * lda + col - kpiv;
            }
            offAh[j] = (w * 2 + j) * 1024;
            offAl[j] = 8192 + (w * 2 + j) * 1024;
        }
    }
    #pragma unroll
    for (int j = 0; j < 2; ++j) {
        int g = (w * 2 + j) * 64 + l;
        int r = g >> 2, cg = g & 3;
        int col = (cg ^ (r & 3)) * 8;
        srcBh[j] = Bhg + (long)(bn + r) * ldw + col;
        if constexpr (!LOWP) srcBl[j] = Blg + (long)(bn + r) * ldw + col;
        offBh[j] = A_BYTES + (w * 2 + j) * 1024;
        offBl[j] = A_BYTES + 8192 + (w * 2 + j) * 1024;
    }

    auto ISSUE = [&](int k0, int bo) {
        char* buf = ldsraw + bo;
        if constexpr (ASRC == 0) {
            #pragma unroll
            for (int j = 0; j < 4; ++j) gload16(srcAf[j] + k0, buf + offAf[j]);
        } else if constexpr (ASRC == 1) {
            #pragma unroll
            for (int j = 0; j < 2; ++j) {
                gload16(srcA1h[j] + k0, buf + offAh[j]);
                if constexpr (!LOWP) gload16(srcA1l[j] + k0, buf + offAl[j]);
            }
        } else {
            bool first = k0 < kpiv;
            #pragma unroll
            for (int j = 0; j < 2; ++j) {
                gload16((first ? srcA1h[j] : srcA2h[j]) + k0, buf + offAh[j]);
                if constexpr (!LOWP) gload16((first ? srcA1l[j] : srcA2l[j]) + k0, buf + offAl[j]);
            }
        }
        #pragma unroll
        for (int j = 0; j < 2; ++j) {
            gload16(srcBh[j] + k0, buf + offBh[j]);
            if constexpr (!LOWP) gload16(srcBl[j] + k0, buf + offBl[j]);
        }
    };

    f32x4 acc[4][4];
    #pragma unroll
    for (int i = 0; i < 4; ++i)
        #pragma unroll
        for (int j = 0; j < 4; ++j) acc[i][j] = (f32x4){0.f, 0.f, 0.f, 0.f};

    bf16x8 fah[4], fal[4], fbh[4], fbl[4];
    float4 vaf[4][2];

    auto READ_FRAGS = [&](int bo) {
        const char* buf = ldsraw + bo;
        const float* Af32b = (const float*)buf;
        const u16* AhB = (const u16*)buf;
        const u16* AlB = (const u16*)(buf + 8192);
        const u16* BhB = (const u16*)(buf + A_BYTES);
        const u16* BlB = (const u16*)(buf + A_BYTES + 8192);
        #pragma unroll
        for (int mt = 0; mt < 4; ++mt) {
            int r = wm * 64 + mt * 16 + lr;
            if constexpr (ASRC == 0) {
                int cg0 = (lg * 2) ^ (r & 7);
                int cg1 = (lg * 2 + 1) ^ (r & 7);
                vaf[mt][0] = *(const float4*)&Af32b[r * 32 + cg0 * 4];
                vaf[mt][1] = *(const float4*)&Af32b[r * 32 + cg1 * 4];
            } else {
                int cg = lg ^ (r & 3);
                fah[mt] = *(const bf16x8*)&AhB[r * 32 + cg * 8];
                if constexpr (!LOWP) fal[mt] = *(const bf16x8*)&AlB[r * 32 + cg * 8];
            }
        }
        #pragma unroll
        for (int nt = 0; nt < 4; ++nt) {
            int r = wn * 64 + nt * 16 + lr;
            int cg = lg ^ (r & 3);
            fbh[nt] = *(const bf16x8*)&BhB[r * 32 + cg * 8];
            if constexpr (!LOWP) fbl[nt] = *(const bf16x8*)&BlB[r * 32 + cg * 8];
        }
    };

    auto COMPUTE = [&]() {
        if constexpr (ASRC == 0) {
            #pragma unroll
            for (int mt = 0; mt < 4; ++mt) {
                float vv[8] = {vaf[mt][0].x, vaf[mt][0].y, vaf[mt][0].z, vaf[mt][0].w,
                               vaf[mt][1].x, vaf[mt][1].y, vaf[mt][1].z, vaf[mt][1].w};
                bf16x8 h8, l8;
                #pragma unroll
                for (int q = 0; q < 8; ++q) {
                    u16 hh, ll; split2(vv[q], hh, ll);
                    h8[q] = (short)hh; l8[q] = (short)ll;
                }
                fah[mt] = h8; fal[mt] = l8;
            }
        }
        #pragma unroll
        for (int mt = 0; mt < 4; ++mt)
            #pragma unroll
            for (int nt = 0; nt < 4; ++nt) {
                acc[mt][nt] = __builtin_amdgcn_mfma_f32_16x16x32_bf16(fah[mt], fbh[nt], acc[mt][nt], 0, 0, 0);
                if constexpr (!LOWP) {
                    acc[mt][nt] = __builtin_amdgcn_mfma_f32_16x16x32_bf16(fah[mt], fbl[nt], acc[mt][nt], 0, 0, 0);
                    acc[mt][nt] = __builtin_amdgcn_mfma_f32_16x16x32_bf16(fal[mt], fbh[nt], acc[mt][nt], 0, 0, 0);
                }
            }
    };

    // ---- 2-phase pipelined K loop: issue-next -> read-cur -> MFMA -> vmcnt(0)+barrier ----
    ISSUE(0, 0);
    PIPE_SYNC();
    int cur = 0;
    for (int k0 = 0; k0 < K; k0 += 32) {
        int bo_cur = cur * BUF_BYTES;
        int bo_nxt = BUF_BYTES - bo_cur;
        if (k0 + 32 < K) ISSUE(k0 + 32, bo_nxt);
        READ_FRAGS(bo_cur);
        COMPUTE();
        PIPE_SYNC();
        cur ^= 1;
    }

    // ---- epilogue ----
    if constexpr (WMODE == 2) {
        if (tid < 128) red[tid] = 0.f;
        __syncthreads();
        float bv[4], dwv[4];
        #pragma unroll
        for (int nt = 0; nt < 4; ++nt) {
            int colg = wn * 64 + nt * 16 + lr;
            bv[nt] = bias[colg];
            dwv[nt] = dw2[colg];
        }
        #pragma unroll
        for (int mt = 0; mt < 4; ++mt)
            #pragma unroll
            for (int j = 0; j < 4; ++j) {
                float p = 0.f;
                #pragma unroll
                for (int nt = 0; nt < 4; ++nt)
                    p += fmaxf(acc[mt][nt][j] + bv[nt], 0.f) * dwv[nt];
                p += __shfl_xor(p, 1);
                p += __shfl_xor(p, 2);
                p += __shfl_xor(p, 4);
                p += __shfl_xor(p, 8);
                if (lr == 0) atomicAdd(&red[wm * 64 + mt * 16 + lg * 4 + j], p);
            }
        __syncthreads();
        if (tid < 128) {
            int row = bm + tid;
            if (row < M) outv[row] = red[tid] + db2[0];
        }
    } else {
        float bv[4];
        int col[4];
        #pragma unroll
        for (int nt = 0; nt < 4; ++nt) {
            col[nt] = bn + wn * 64 + nt * 16 + lr;
            bv[nt] = bias ? bias[col[nt]] : 0.f;
        }
        #pragma unroll
        for (int mt = 0; mt < 4; ++mt) {
            int row0 = bm + wm * 64 + mt * 16 + lg * 4;
            #pragma unroll
            for (int j = 0; j < 4; ++j) {
                int row = row0 + j;
                if (row >= M) continue;
                size_t rbase = (size_t)row * ldc;
                #pragma unroll
                for (int nt = 0; nt < 4; ++nt) {
                    size_t off = rbase + col[nt];
                    float v = acc[mt][nt][j] + bv[nt];
                    if (flags & FLAG_RELU) v = fmaxf(v, 0.f);
                    u16 hh, ll; split2(v, hh, ll);
                    Chi[off] = hh;
                    if constexpr (WMODE == 0) Clo[off] = ll;
                }
            }
        }
    }
}

// ---------------- CSR build (merged, sections A|B|C|D) ----------------
__global__ void count_all_kernel(const int* __restrict__ hks, const int* __restrict__ hkd,
                                 const int* __restrict__ hss, const int* __restrict__ hsd,
                                 int* __restrict__ deg)
{
    int e = blockIdx.x * blockDim.x + threadIdx.x;
    if (e < E_HK) {
        atomicAdd(deg + OFFA + hkd[e], 1);
        atomicAdd(deg + OFFC + hks[e], 1);
    } else if (e < E_HK + E_HS) {
        int i = e - E_HK;
        atomicAdd(deg + OFFB + hsd[i], 1);
        atomicAdd(deg + OFFD + hss[i], 1);
    }
}

__global__ void scan_block_kernel(const int* __restrict__ in, int* __restrict__ out,
                                  int* __restrict__ bsum, int n)
{
    __shared__ int tmp[256];
    int i = blockIdx.x * 256 + threadIdx.x;
    int v = (i < n) ? in[i] : 0;
    tmp[threadIdx.x] = v;
    __syncthreads();
    #pragma unroll
    for (int off = 1; off < 256; off <<= 1) {
        int t = (threadIdx.x >= off) ? tmp[threadIdx.x - off] : 0;
        __syncthreads();
        tmp[threadIdx.x] += t;
        __syncthreads();
    }
    if (i < n) out[i] = tmp[threadIdx.x] - v;
    if (threadIdx.x == 255 && bsum) bsum[blockIdx.x] = tmp[255];
}

__global__ void scan2_kernel(int* __restrict__ data, int n) // n <= 512, in-place exclusive
{
    __shared__ int tmp[512];
    int v = (threadIdx.x < n) ? data[threadIdx.x] : 0;
    tmp[threadIdx.x] = v;
    __syncthreads();
    #pragma unroll
    for (int off = 1; off < 512; off <<= 1) {
        int t = (threadIdx.x >= off) ? tmp[threadIdx.x - off] : 0;
        __syncthreads();
        tmp[threadIdx.x] += t;
        __syncthreads();
    }
    if (threadIdx.x < n) data[threadIdx.x] = tmp[threadIdx.x] - v;
}

__global__ void scan_add_kernel(int* __restrict__ out, const int* __restrict__ bsumex, int n)
{
    int i = blockIdx.x * 256 + threadIdx.x;
    if (i < n) out[i] += bsumex[blockIdx.x];
}

__global__ void fill_all_kernel(const int* __restrict__ hks, const int* __restrict__ hkd,
                                const int* __restrict__ hss, const int* __restrict__ hsd,
                                int* __restrict__ cur, u16* __restrict__ adj)
{
    int e = blockIdx.x * blockDim.x + threadIdx.x;
    if (e < E_HK) {
        int s = hks[e], d = hkd[e];
        int p = atomicAdd(cur + OFFA + d, 1); adj[p] = (u16)s;
        int q = atomicAdd(cur + OFFC + s, 1); adj[q] = (u16)d;
    } else if (e < E_HK + E_HS) {
        int i = e - E_HK;
        int s = hss[i], d = hsd[i];
        int p = atomicAdd(cur + OFFB + d, 1); adj[p] = (u16)s;
        int q = atomicAdd(cur + OFFD + s, 1); adj[q] = (u16)d;
    }
}

// ---------------- gather mean (hi-plane read; hi[+lo] write; 16B/lane) ----------------
template <int D, bool WRITELO>
__global__ void gather_mean_kernel(const u16* __restrict__ Xhi,
                                   const int* __restrict__ cur, const int* __restrict__ deg,
                                   const u16* __restrict__ adj,
                                   u16* __restrict__ Ohi, u16* __restrict__ Olo, int ndst)
{
    constexpr int LANES = D / 8;          // 16B per lane
    constexpr int RPB = 256 / LANES;
    int r = blockIdx.x * RPB + threadIdx.x / LANES;
    if (r >= ndst) return;
    int lane = threadIdx.x % LANES;
    int end = cur[r];
    int n = deg[r];
    int j = end - n;
    float s[8];
    #pragma unroll
    for (int q = 0; q < 8; ++q) s[q] = 0.f;
    for (; j + 1 < end; j += 2) {
        u16x8 a = *(const u16x8*)(Xhi + (size_t)adj[j] * D + lane * 8);
        u16x8 b = *(const u16x8*)(Xhi + (size_t)adj[j + 1] * D + lane * 8);
        #pragma unroll
        for (int q = 0; q < 8; ++q) s[q] += bf2f(a[q]) + bf2f(b[q]);
    }
    if (j < end) {
        u16x8 a = *(const u16x8*)(Xhi + (size_t)adj[j] * D + lane * 8);
        #pragma unroll
        for (int q = 0; q < 8; ++q) s[q] += bf2f(a[q]);
    }
    float inv = (n > 0) ? 1.0f / (float)n : 0.f;
    size_t off = (size_t)r * D + lane * 8;
    u16x8 h8, l8;
    #pragma unroll
    for (int q = 0; q < 8; ++q) { u16 hh, ll; split2(s[q] * inv, hh, ll); h8[q] = hh; l8[q] = ll; }
    *(u16x8*)(Ohi + off) = h8;
    if constexpr (WRITELO) *(u16x8*)(Olo + off) = l8;
}

// ---------------- fused news assembly: N += meanC(PP) + meanD(PP2); [relu] ----------------
template <int D, bool RELU, bool HASLO>
__global__ void fuse_news_kernel(const u16* __restrict__ PPh, const u16* __restrict__ PP2h,
                                 const int* __restrict__ curC, const int* __restrict__ degC,
                                 const int* __restrict__ curD, const int* __restrict__ degD,
                                 const u16* __restrict__ adj,
                                 u16* __restrict__ Nh, u16* __restrict__ Nl, int ndst)
{
    constexpr int LANES = D / 8;          // 16B per lane
    constexpr int RPB = 256 / LANES;
    int r = blockIdx.x * RPB + threadIdx.x / LANES;
    if (r >= ndst) return;
    int lane = threadIdx.x % LANES;
    float s[8];
    #pragma unroll
    for (int q = 0; q < 8; ++q) s[q] = 0.f;
    {
        int end = curC[r], n = degC[r];
        float a[8];
        #pragma unroll
        for (int q = 0; q < 8; ++q) a[q] = 0.f;
        for (int j = end - n; j < end; ++j) {
            u16x8 v = *(const u16x8*)(PPh + (size_t)adj[j] * D + lane * 8);
            #pragma unroll
            for (int q = 0; q < 8; ++q) a[q] += bf2f(v[q]);
        }
        float inv = (n > 0) ? 1.0f / (float)n : 0.f;
        #pragma unroll
        for (int q = 0; q < 8; ++q) s[q] += a[q] * inv;
    }
    {
        int end = curD[r], n = degD[r];
        float a[8];
        #pragma unroll
        for (int q = 0; q < 8; ++q) a[q] = 0.f;
        for (int j = end - n; j < end; ++j) {
            u16x8 v = *(const u16x8*)(PP2h + (size_t)adj[j] * D + lane * 8);
            #pragma unroll
            for (int q = 0; q < 8; ++q) a[q] += bf2f(v[q]);
        }
        float inv = (n > 0) ? 1.0f / (float)n : 0.f;
        #pragma unroll
        for (int q = 0; q < 8; ++q) s[q] += a[q] * inv;
    }
    size_t off = (size_t)r * D + lane * 8;
    u16x8 h = *(const u16x8*)(Nh + off);
    if constexpr (HASLO) {
        u16x8 l = *(const u16x8*)(Nl + off);
        #pragma unroll
        for (int q = 0; q < 8; ++q) s[q] += bf2f(h[q]) + bf2f(l[q]);
    } else {
        #pragma unroll
        for (int q = 0; q < 8; ++q) s[q] += bf2f(h[q]);
    }
    #pragma unroll
    for (int q = 0; q < 8; ++q) {
        float v = s[q];
        if (RELU) v = fmaxf(v, 0.f);
        s[q] = v;
    }
    u16x8 oh, ol;
    #pragma unroll
    for (int q = 0; q < 8; ++q) { u16 hh, ll; split2(s[q], hh, ll); oh[q] = hh; ol[q] = ll; }
    *(u16x8*)(Nh + off) = oh;
    if constexpr (HASLO) *(u16x8*)(Nl + off) = ol;
}

// ---------------- batched weight split/convert ----------------
#define MAXJOBS 20
struct SplitJobs {
    const float* a[MAXJOBS];
    const float* b[MAXJOBS];     // optional second operand (summed)
    u16* hi[MAXJOBS];
    u16* lo[MAXJOBS];
    int n[MAXJOBS];
    int ncols[MAXJOBS];          // source row width
    int dstride[MAXJOBS];        // dest row stride
    int boff[MAXJOBS + 1];
    int njobs;
};

__global__ void split_all_kernel(SplitJobs J)
{
    int bid = blockIdx.x;
    int j = 0;
    while (j + 1 < J.njobs && bid >= J.boff[j + 1]) ++j;
    int i = (bid - J.boff[j]) * 1024 + threadIdx.x * 4;
    if (i >= J.n[j]) return;
    float4 v = *(const float4*)(J.a[j] + i);
    if (J.b[j]) {
        float4 w = *(const float4*)(J.b[j] + i);
        v.x += w.x; v.y += w.y; v.z += w.z; v.w += w.w;
    }
    int row = i / J.ncols[j], col = i - row * J.ncols[j];
    size_t d = (size_t)row * J.dstride[j] + col;
    ushort4 h, l;
    split2(v.x, h.x, l.x); split2(v.y, h.y, l.y); split2(v.z, h.z, l.z); split2(v.w, h.w, l.w);
    *(ushort4*)(J.hi[j] + d) = h;
    *(ushort4*)(J.lo[j] + d) = l;
}

__global__ void bias_sum_kernel(const float* __restrict__ b1, const float* __restrict__ b2,
                                float* __restrict__ BS1, float* __restrict__ BS2)
{
    int i = blockIdx.x * 256 + threadIdx.x;
    if (i < 256) BS1[i] = b1[256 + i] + b1[768 + i];
    else if (i < 384) { int j = i - 256; BS2[j] = b2[128 + j] + b2[384 + j]; }
}

// ---------------- launch ----------------
extern "C" void kernel_launch(void* const* d_in, const int* in_sizes, int n_in,
                              void* d_out, int out_size, void* d_ws, size_t ws_size,
                              hipStream_t stream)
{
    const float* x_news = (const float*)d_in[0];
    const float* x_kw   = (const float*)d_in[1];
    const float* x_st   = (const float*)d_in[2];
    const float* Wn = (const float*)d_in[3];  const float* bn = (const float*)d_in[4];
    const float* Wk = (const float*)d_in[5];  const float* bk = (const float*)d_in[6];
    const float* Wst = (const float*)d_in[7]; const float* bs = (const float*)d_in[8];
    const float* W1l = (const float*)d_in[9];  const float* b1 = (const float*)d_in[10];
    const float* W1r = (const float*)d_in[11];
    const float* W2l = (const float*)d_in[12]; const float* b2 = (const float*)d_in[13];
    const float* W2r = (const float*)d_in[14];
    const float* DW1 = (const float*)d_in[15]; const float* Db1 = (const float*)d_in[16];
    const float* DW2 = (const float*)d_in[17]; const float* Db2 = (const float*)d_in[18];
    const int* e_hk_src = (const int*)d_in[19];
    const int* e_hk_dst = (const int*)d_in[20];
    const int* e_hs_src = (const int*)d_in[21];
    const int* e_hs_dst = (const int*)d_in[22];
    const int* l_hk_src = (const int*)d_in[23];
    const int* l_hk_dst = (const int*)d_in[24];
    const int* l_hs_src = (const int*)d_in[25];
    const int* l_hs_dst = (const int*)d_in[26];
    float* out = (float*)d_out;

    // ---- workspace layout (bytes, 16B aligned) ----
    char* base = (char*)d_ws;
    auto alloc = [&](size_t bytes) -> char* {
        char* p = base;
        base += (bytes + 15) & ~(size_t)15;
        return p;
    };
    auto aplane = [&](size_t elems) -> u16* { return (u16*)alloc(elems * 2); };

    u16* HNh = aplane((size_t)N_NEWS * HID);  u16* HNl = aplane((size_t)N_NEWS * HID);
    u16* HKh = aplane((size_t)N_KW * HID);    u16* HKl = aplane((size_t)N_KW * HID);
    u16* HSh = aplane((size_t)N_ST * HID);    u16* HSl = aplane((size_t)N_ST * HID);
    u16* K1h = aplane((size_t)N_KW * HID);
    u16* S1h = aplane((size_t)N_ST * HID);
    u16* PAh = aplane((size_t)(N_KW + N_ST) * HID);   // 12000 rows (kw | st sections)
    u16* PAl = aplane((size_t)(N_KW + N_ST) * HID);
    u16* N1h = aplane((size_t)N_NEWS * HID);
    // weight planes
    u16* WnH = aplane(196608);  u16* WnL = aplane(196608);
    u16* WkH = aplane(32768);   u16* WkL = aplane(32768);
    u16* WsH = aplane(16384);   u16* WsL = aplane(16384);
    u16* CW1KH = aplane(131072); u16* CW1KL = aplane(131072);  // [256][512] W1l0|W1r0
    u16* CW1SH = aplane(131072); u16* CW1SL = aplane(131072);  // [256][512] W1l2|W1r2
    u16* W1l1H = aplane(65536);  u16* W1l1L = aplane(65536);
    u16* W1l3H = aplane(65536);  u16* W1l3L = aplane(65536);
    u16* SW1H = aplane(65536);   u16* SW1L = aplane(65536);    // W1r1+W1r3
    u16* CW2KH = aplane(65536);  u16* CW2KL = aplane(65536);   // [128][512] W2l0|W2r0
    u16* CW2SH = aplane(65536);  u16* CW2SL = aplane(65536);   // [128][512] W2l2|W2r2
    u16* W2l1H = aplane(32768);  u16* W2l1L = aplane(32768);
    u16* W2l3H = aplane(32768);  u16* W2l3L = aplane(32768);
    u16* SW2H = aplane(32768);   u16* SW2L = aplane(32768);    // W2r1+W2r3
    u16* DW1H = aplane(65536);   u16* DW1L = aplane(65536);
    float* BS1 = (float*)alloc(256 * 4);
    float* BS2 = (float*)alloc(128 * 4);
    // int pools
    int* deg = (int*)alloc((size_t)NTOT * 4);
    int* cur = (int*)alloc((size_t)NTOT * 4);
    u16* adj = (u16*)alloc((size_t)2 * (E_HK + E_HS) * 2);
    int* bsum = (int*)alloc(512 * 4);

    // overlays: layer-2 outputs reuse the HN region (dead after layer 1)
    u16* K2h = HNh;
    u16* N2h = K2h + (size_t)N_KW * OUTD;
    u16* S2h = N2h + (size_t)N_NEWS * OUTD;

    // ---- CSR build ----
    hipMemsetAsync(deg, 0, (size_t)NTOT * sizeof(int), stream);
    int etot = E_HK + E_HS;
    count_all_kernel<<<(etot + 255) / 256, 256, 0, stream>>>(e_hk_src, e_hk_dst, e_hs_src, e_hs_dst, deg);
    int nb = (NTOT + 255) / 256; // 438
    scan_block_kernel<<<nb, 256, 0, stream>>>(deg, cur, bsum, NTOT);
    scan2_kernel<<<1, 512, 0, stream>>>(bsum, nb);
    scan_add_kernel<<<nb, 256, 0, stream>>>(cur, bsum, NTOT);
    fill_all_kernel<<<(etot + 255) / 256, 256, 0, stream>>>(e_hk_src, e_hk_dst, e_hs_src, e_hs_dst, cur, adj);

    // ---- batched weight conversion ----
    {
        SplitJobs J{};
        int nj = 0, blocks = 0;
        auto job = [&](const float* a, const float* b, u16* hi, u16* lo, int n, int ncols, int dstride) {
            J.a[nj] = a; J.b[nj] = b; J.hi[nj] = hi; J.lo[nj] = lo;
            J.n[nj] = n; J.ncols[nj] = ncols; J.dstride[nj] = dstride;
            J.boff[nj] = blocks;
            blocks += (n / 4 + 255) / 256;
            ++nj;
        };
        job(Wn, nullptr, WnH, WnL, 196608, 196608, 196608);
        job(Wk, nullptr, WkH, WkL, 32768, 32768, 32768);
        job(Wst, nullptr, WsH, WsL, 16384, 16384, 16384);
        job(W1l + 0 * 65536, nullptr, CW1KH, CW1KL, 65536, 256, 512);
        job(W1r + 0 * 65536, nullptr, CW1KH + 256, CW1KL + 256, 65536, 256, 512);
        job(W1l + 2 * 65536, nullptr, CW1SH, CW1SL, 65536, 256, 512);
        job(W1r + 2 * 65536, nullptr, CW1SH + 256, CW1SL + 256, 65536, 256, 512);
        job(W1l + 1 * 65536, nullptr, W1l1H, W1l1L, 65536, 65536, 65536);
        job(W1l + 3 * 65536, nullptr, W1l3H, W1l3L, 65536, 65536, 65536);
        job(W1r + 1 * 65536, W1r + 3 * 65536, SW1H, SW1L, 65536, 65536, 65536);
        job(W2l + 0 * 32768, nullptr, CW2KH, CW2KL, 32768, 256, 512);
        job(W2r + 0 * 32768, nullptr, CW2KH + 256, CW2KL + 256, 32768, 256, 512);
        job(W2l + 2 * 32768, nullptr, CW2SH, CW2SL, 32768, 256, 512);
        job(W2r + 2 * 32768, nullptr, CW2SH + 256, CW2SL + 256, 32768, 256, 512);
        job(W2l + 1 * 32768, nullptr, W2l1H, W2l1L, 32768, 32768, 32768);
        job(W2l + 3 * 32768, nullptr, W2l3H, W2l3L, 32768, 32768, 32768);
        job(W2r + 1 * 32768, W2r + 3 * 32768, SW2H, SW2L, 32768, 32768, 32768);
        job(DW1, nullptr, DW1H, DW1L, 65536, 65536, 65536);
        J.boff[nj] = blocks;
        J.njobs = nj;
        split_all_kernel<<<blocks, 256, 0, stream>>>(J);
    }
    bias_sum_kernel<<<2, 256, 0, stream>>>(b1, b2, BS1, BS2);

    // ---- GEMM wrappers ----
    auto gemmF = [&](const float* A, int lda, const u16* Bh, const u16* Bl, int ldw,
                     const float* bias, u16* Ch, u16* Cl, int ldc,
                     int M, int N, int K, int flags) {
        dim3 g((M + 127) / 128, N / 128);
        gemm_kernel<0, 0, false><<<g, 256, 0, stream>>>(
            A, nullptr, nullptr, nullptr, nullptr, nullptr, nullptr, lda, 0,
            Bh, Bl, ldw, bias, Ch, Cl, ldc, nullptr, nullptr, nullptr, M, K, flags);
    };
    auto gemmP1 = [&](const u16* Ahp, const u16* Alp, int lda, const u16* Bh, const u16* Bl, int ldw,
                      const float* bias, u16* Ch, int ldc,
                      int M, int N, int K, int flags) {
        dim3 g((M + 127) / 128, N / 128);
        gemm_kernel<1, 1, false><<<g, 256, 0, stream>>>(
            nullptr, Ahp, Alp, nullptr, nullptr, nullptr, nullptr, lda, 0,
            Bh, Bl, ldw, bias, Ch, nullptr, ldc, nullptr, nullptr, nullptr, M, K, flags);
    };
    auto gemm21 = [&](const u16* A1hp, const u16* A1lp, const u16* A2hp, const u16* A2lp,
                      int lda, int kpiv, const u16* Bh, const u16* Bl, int ldw,
                      const float* bias, u16* Ch, int ldc,
                      int M, int N, int K, int flags) {
        dim3 g((M + 127) / 128, N / 128);
        gemm_kernel<2, 1, false><<<g, 256, 0, stream>>>(
            nullptr, A1hp, A1lp, A2hp, A2lp, nullptr, nullptr, lda, kpiv,
            Bh, Bl, ldw, bias, Ch, nullptr, ldc, nullptr, nullptr, nullptr, M, K, flags);
    };
    auto gemmLP = [&](const u16* Ahp, int lda, const u16* Bh, int ldw,
                      const float* bias, u16* Ch, int ldc, int M, int N, int K, int flags) {
        dim3 g((M + 127) / 128, N / 128);
        gemm_kernel<1, 1, true><<<g, 256, 0, stream>>>(
            nullptr, Ahp, nullptr, nullptr, nullptr, nullptr, nullptr, lda, 0,
            Bh, nullptr, ldw, bias, Ch, nullptr, ldc, nullptr, nullptr, nullptr, M, K, flags);
    };
    auto gemmL2 = [&](const u16* A1hp, const u16* A2hp, int lda, int kpiv,
                      const u16* Bh, int ldw, const float* bias, u16* Ch, int ldc,
                      int M, int N, int K, int flags) {
        dim3 g((M + 127) / 128, N / 128);
        gemm_kernel<2, 1, true><<<g, 256, 0, stream>>>(
            nullptr, A1hp, nullptr, A2hp, nullptr, nullptr, nullptr, lda, kpiv,
            Bh, nullptr, ldw, bias, Ch, nullptr, ldc, nullptr, nullptr, nullptr, M, K, flags);
    };
    auto gemmD = [&](const u16* A1hp, const u16* A2hp,
                     const int* r1, const int* r2, const u16* Bh,
                     const float* bias, const float* dw2, const float* db2, float* ov) {
        dim3 g((E_LBL + 127) / 128, 1);
        gemm_kernel<2, 2, true><<<g, 256, 0, stream>>>(
            nullptr, A1hp, nullptr, A2hp, nullptr, r1, r2, 128, 128,
            Bh, nullptr, 256, bias, nullptr, nullptr, 0, dw2, db2, ov, E_LBL, 256, 0);
    };

    // ---- input projections (full precision, hi+lo outputs) ----
    gemmF(x_news, F_NEWS, WnH, WnL, F_NEWS, bn, HNh, HNl, HID, N_NEWS, HID, F_NEWS, FLAG_RELU);
    gemmF(x_kw,   F_KW,   WkH, WkL, F_KW,   bk, HKh, HKl, HID, N_KW,   HID, F_KW,   FLAG_RELU);
    gemmF(x_st,   F_ST,   WsH, WsL, F_ST,   bs, HSh, HSl, HID, N_ST,   HID, F_ST,   FLAG_RELU);

    // ---- layer 1 (full-precision compute, hi-only storage) ----
    gather_mean_kernel<256, true><<<(N_KW + N_ST + 7) / 8, 256, 0, stream>>>(
        HNh, cur + OFFA, deg + OFFA, adj, PAh, PAl, N_KW + N_ST);
    gemm21(PAh, PAl, HKh, HKl, HID, 256, CW1KH, CW1KL, 512, b1, K1h, HID, N_KW, HID, 512, FLAG_RELU);
    gemm21(PAh + (size_t)N_KW * HID, PAl + (size_t)N_KW * HID, HSh, HSl, HID, 256,
           CW1SH, CW1SL, 512, b1 + 2 * 256, S1h, HID, N_ST, HID, 512, FLAG_RELU);
    gemmLP(HKh, HID, W1l1H, HID, nullptr, PAh, HID, N_KW, HID, HID, 0);   // PP
    gemmLP(HSh, HID, W1l3H, HID, nullptr, PAl, HID, N_ST, HID, HID, 0);   // PP2
    gemmP1(HNh, HNl, HID, SW1H, SW1L, HID, BS1, N1h, HID, N_NEWS, HID, HID, 0);
    fuse_news_kernel<256, true, false><<<(N_NEWS + 7) / 8, 256, 0, stream>>>(
        PAh, PAl, cur + OFFC, deg + OFFC, cur + OFFD, deg + OFFD, adj, N1h, nullptr, N_NEWS);

    // ---- layer 2 (LOWP: hi-only, 1 MFMA) ----
    gather_mean_kernel<256, false><<<(N_KW + N_ST + 7) / 8, 256, 0, stream>>>(
        N1h, cur + OFFA, deg + OFFA, adj, PAh, nullptr, N_KW + N_ST);
    gemmL2(PAh, K1h, HID, 256, CW2KH, 512, b2, K2h, OUTD, N_KW, OUTD, 512, 0);
    gemmL2(PAh + (size_t)N_KW * HID, S1h, HID, 256, CW2SH, 512, b2 + 2 * 128, S2h, OUTD, N_ST, OUTD, 512, 0);
    gemmLP(K1h, HID, W2l1H, HID, nullptr, PAh, OUTD, N_KW, OUTD, HID, 0);  // PP (n2)
    gemmLP(S1h, HID, W2l3H, HID, nullptr, PAl, OUTD, N_ST, OUTD, HID, 0);  // PP2 (n2)
    gemmLP(N1h, HID, SW2H, HID, BS2, N2h, OUTD, N_NEWS, OUTD, HID, 0);
    fuse_news_kernel<128, false, false><<<(N_NEWS + 15) / 16, 256, 0, stream>>>(
        PAh, PAl, cur + OFFC, deg + OFFC, cur + OFFD, deg + OFFD, adj, N2h, nullptr, N_NEWS);

    // ---- fused decoders (LOWP) ----
    gemmD(N2h, K2h, l_hk_src, l_hk_dst, DW1H, Db1, DW2, Db2, out);
    gemmD(N2h, S2h, l_hs_src, l_hs_dst, DW1H + 32768, Db1 + 128, DW2 + 128, Db2 + 1, out + E_LBL);
}

// Round 13
// 728.940 us; speedup vs baseline: 1.7277x; 1.0130x over previous
//
#include <hip/hip_runtime.h>
#include <hip/hip_bf16.h>

// ---------------- problem constants ----------------
constexpr int N_NEWS = 50000, N_KW = 10000, N_ST = 2000;
constexpr int F_NEWS = 768, F_KW = 128, F_ST = 64;
constexpr int HID = 256, OUTD = 128;
constexpr int E_HK = 500000, E_HS = 250000, E_LBL = 150000;

// CSR section offsets in the concatenated degree/cursor pools
constexpr int OFFA = 0;                    // e_hk keyed by dst (kw)
constexpr int OFFB = N_KW;                 // e_hs keyed by dst (st)
constexpr int OFFC = N_KW + N_ST;          // e_hk keyed by src (news)
constexpr int OFFD = OFFC + N_NEWS;        // e_hs keyed by src (news)
constexpr int NTOT = OFFD + N_NEWS;        // 112000

enum { FLAG_ACC = 1, FLAG_RELU = 2 };

typedef unsigned short u16;
typedef __attribute__((ext_vector_type(8))) short bf16x8;
typedef __attribute__((ext_vector_type(8))) unsigned short u16x8;
typedef __attribute__((ext_vector_type(4))) float f32x4;

__device__ __forceinline__ u16 f2bf(float x) {
    return __builtin_bit_cast(u16, __float2bfloat16(x));
}
__device__ __forceinline__ float bf2f(u16 h) {
    unsigned u = ((unsigned)h) << 16;
    return __builtin_bit_cast(float, u);
}
__device__ __forceinline__ void split2(float x, u16& h, u16& l) {
    h = f2bf(x);
    l = f2bf(x - bf2f(h));
}

// async global->LDS DMA, 16B per lane; LDS dest = wave-uniform base + lane*16
__device__ __forceinline__ void gload16(const void* g, void* s) {
    __builtin_amdgcn_global_load_lds(
        (const __attribute__((address_space(1))) void*)g,
        (__attribute__((address_space(3))) void*)s, 16, 0, 0);
}

// ---------------- split-bf16 MFMA GEMM, dbuf LDS + COUNTED-vmcnt pipeline (T3+T4) ------
// ASRC: 0 = fp32 A (DMA fp32, split in regs), 1 = plane A, 2 = dual-table plane A
// WMODE: 0 = write hi+lo planes, 1 = hi only, 2 = fused decoder reduce -> outv
// LOWP: hi-plane-only operands, 1 MFMA/product (vs 3)
template<int ASRC, int WMODE, bool LOWP>
__global__ __launch_bounds__(256) void gemm_kernel(
    const float* __restrict__ Af,
    const u16* __restrict__ A1h, const u16* __restrict__ A1l,
    const u16* __restrict__ A2h, const u16* __restrict__ A2l,
    const int* __restrict__ ridx1, const int* __restrict__ ridx2, int lda, int kpiv,
    const u16* __restrict__ Bhg, const u16* __restrict__ Blg, int ldw,
    const float* __restrict__ bias,
    u16* __restrict__ Chi, u16* __restrict__ Clo, int ldc,
    const float* __restrict__ dw2, const float* __restrict__ db2,
    float* __restrict__ outv,
    int M, int K, int flags)
{
    constexpr int A_BYTES = (ASRC == 0) ? 16384 : (LOWP ? 8192 : 16384);
    constexpr int B_BYTES = LOWP ? 8192 : 16384;
    constexpr int BUF_BYTES = A_BYTES + B_BYTES;
    constexpr int NLOADS = (ASRC == 0) ? 8 : (LOWP ? 4 : 8);   // per-wave DMA ops per tile
    __shared__ __align__(16) char ldsraw[2 * BUF_BYTES];
    __shared__ float red[128];

    const int tid = threadIdx.x;
    const int bm = blockIdx.x * 128;
    const int bn = blockIdx.y * 128;
    const int l = tid & 63;
    const int w = tid >> 6;
    const int wm = w >> 1, wn = w & 1;
    const int lg = l >> 4, lr = l & 15;

    // ---- per-thread DMA sources + in-buffer dest byte offsets ----
    const float* srcAf[4];
    const u16 *srcA1h[2], *srcA1l[2], *srcA2h[2], *srcA2l[2];
    const u16 *srcBh[2], *srcBl[2];
    int offAf[4], offAh[2], offAl[2], offBh[2], offBl[2];

    if constexpr (ASRC == 0) {
        #pragma unroll
        for (int j = 0; j < 4; ++j) {
            int g = (w * 4 + j) * 64 + l;
            int r = g >> 3, cg = g & 7;
            int rg = bm + r; if (rg > M - 1) rg = M - 1;
            long ar = ridx1 ? (long)ridx1[rg] : (long)rg;
            srcAf[j] = Af + ar * lda + (cg ^ (r & 7)) * 4;
            offAf[j] = (w * 4 + j) * 1024;           // 64 lanes * 16 B
        }
    } else {
        #pragma unroll
        for (int j = 0; j < 2; ++j) {
            int g = (w * 2 + j) * 64 + l;
            int r = g >> 2, cg = g & 3;
            int rg = bm + r; if (rg > M - 1) rg = M - 1;
            int col = (cg ^ (r & 3)) * 8;
            long a1 = ridx1 ? (long)ridx1[rg] : (long)rg;
            srcA1h[j] = A1h + a1 * lda + col;
            if constexpr (!LOWP) srcA1l[j] = A1l + a1 * lda + col;
            if constexpr (ASRC == 2) {
                long a2 = ridx2 ? (long)ridx2[rg] : (long)rg;
                srcA2h[j] = A2h + a2 * lda + col - kpiv;
                if constexpr (!LOWP) srcA2l[j] = A2l + a2 * lda + col - kpiv;
            }
            offAh[j] = (w * 2 + j) * 1024;
            offAl[j] = 8192 + (w * 2 + j) * 1024;
        }
    }
    #pragma unroll
    for (int j = 0; j < 2; ++j) {
        int g = (w * 2 + j) * 64 + l;
        int r = g >> 2, cg = g & 3;
        int col = (cg ^ (r & 3)) * 8;
        srcBh[j] = Bhg + (long)(bn + r) * ldw + col;
        if constexpr (!LOWP) srcBl[j] = Blg + (long)(bn + r) * ldw + col;
        offBh[j] = A_BYTES + (w * 2 + j) * 1024;
        offBl[j] = A_BYTES + 8192 + (w * 2 + j) * 1024;
    }

    auto ISSUE = [&](int k0, int bo) {
        char* buf = ldsraw + bo;
        if constexpr (ASRC == 0) {
            #pragma unroll
            for (int j = 0; j < 4; ++j) gload16(srcAf[j] + k0, buf + offAf[j]);
        } else if constexpr (ASRC == 1) {
            #pragma unroll
            for (int j = 0; j < 2; ++j) {
                gload16(srcA1h[j] + k0, buf + offAh[j]);
                if constexpr (!LOWP) gload16(srcA1l[j] + k0, buf + offAl[j]);
            }
        } else {
            bool first = k0 < kpiv;
            #pragma unroll
            for (int j = 0; j < 2; ++j) {
                gload16((first ? srcA1h[j] : srcA2h[j]) + k0, buf + offAh[j]);
                if constexpr (!LOWP) gload16((first ? srcA1l[j] : srcA2l[j]) + k0, buf + offAl[j]);
            }
        }
        #pragma unroll
        for (int j = 0; j < 2; ++j) {
            gload16(srcBh[j] + k0, buf + offBh[j]);
            if constexpr (!LOWP) gload16(srcBl[j] + k0, buf + offBl[j]);
        }
    };

    f32x4 acc[4][4];
    #pragma unroll
    for (int i = 0; i < 4; ++i)
        #pragma unroll
        for (int j = 0; j < 4; ++j) acc[i][j] = (f32x4){0.f, 0.f, 0.f, 0.f};

    bf16x8 fah[4], fal[4], fbh[4], fbl[4];
    float4 vaf[4][2];

    auto READ_FRAGS = [&](int bo) {
        const char* buf = ldsraw + bo;
        const float* Af32b = (const float*)buf;
        const u16* AhB = (const u16*)buf;
        const u16* AlB = (const u16*)(buf + 8192);
        const u16* BhB = (const u16*)(buf + A_BYTES);
        const u16* BlB = (const u16*)(buf + A_BYTES + 8192);
        #pragma unroll
        for (int mt = 0; mt < 4; ++mt) {
            int r = wm * 64 + mt * 16 + lr;
            if constexpr (ASRC == 0) {
                int cg0 = (lg * 2) ^ (r & 7);
                int cg1 = (lg * 2 + 1) ^ (r & 7);
                vaf[mt][0] = *(const float4*)&Af32b[r * 32 + cg0 * 4];
                vaf[mt][1] = *(const float4*)&Af32b[r * 32 + cg1 * 4];
            } else {
                int cg = lg ^ (r & 3);
                fah[mt] = *(const bf16x8*)&AhB[r * 32 + cg * 8];
                if constexpr (!LOWP) fal[mt] = *(const bf16x8*)&AlB[r * 32 + cg * 8];
            }
        }
        #pragma unroll
        for (int nt = 0; nt < 4; ++nt) {
            int r = wn * 64 + nt * 16 + lr;
            int cg = lg ^ (r & 3);
            fbh[nt] = *(const bf16x8*)&BhB[r * 32 + cg * 8];
            if constexpr (!LOWP) fbl[nt] = *(const bf16x8*)&BlB[r * 32 + cg * 8];
        }
    };

    auto COMPUTE = [&]() {
        if constexpr (ASRC == 0) {
            #pragma unroll
            for (int mt = 0; mt < 4; ++mt) {
                float vv[8] = {vaf[mt][0].x, vaf[mt][0].y, vaf[mt][0].z, vaf[mt][0].w,
                               vaf[mt][1].x, vaf[mt][1].y, vaf[mt][1].z, vaf[mt][1].w};
                bf16x8 h8, l8;
                #pragma unroll
                for (int q = 0; q < 8; ++q) {
                    u16 hh, ll; split2(vv[q], hh, ll);
                    h8[q] = (short)hh; l8[q] = (short)ll;
                }
                fah[mt] = h8; fal[mt] = l8;
            }
        }
        #pragma unroll
        for (int mt = 0; mt < 4; ++mt)
            #pragma unroll
            for (int nt = 0; nt < 4; ++nt) {
                acc[mt][nt] = __builtin_amdgcn_mfma_f32_16x16x32_bf16(fah[mt], fbh[nt], acc[mt][nt], 0, 0, 0);
                if constexpr (!LOWP) {
                    acc[mt][nt] = __builtin_amdgcn_mfma_f32_16x16x32_bf16(fah[mt], fbl[nt], acc[mt][nt], 0, 0, 0);
                    acc[mt][nt] = __builtin_amdgcn_mfma_f32_16x16x32_bf16(fal[mt], fbh[nt], acc[mt][nt], 0, 0, 0);
                }
            }
    };

    // ---- counted-vmcnt 2-buffer K loop (T3+T4 minimum recipe) ----
    // prologue: two tiles in flight
    ISSUE(0, 0);
    if (K > 32) ISSUE(32, BUF_BYTES);
    int cur = 0;
    for (int k0 = 0; k0 < K; k0 += 32) {
        // wait only until THIS tile's loads are done (next tile's stay in flight)
        if (k0 + 32 < K) {
            if constexpr (NLOADS == 8) asm volatile("s_waitcnt vmcnt(8)" ::: "memory");
            else                       asm volatile("s_waitcnt vmcnt(4)" ::: "memory");
        } else {
            asm volatile("s_waitcnt vmcnt(0)" ::: "memory");
        }
        __builtin_amdgcn_s_barrier();            // all waves' tile-k DMA visible
        __builtin_amdgcn_sched_barrier(0);
        int bo_cur = cur * BUF_BYTES;
        READ_FRAGS(bo_cur);
        asm volatile("s_waitcnt lgkmcnt(0)" ::: "memory");   // reads landed in regs
        __builtin_amdgcn_sched_barrier(0);                   // rule #18 pin
        __builtin_amdgcn_s_barrier();            // all waves done reading buf[cur]
        if (k0 + 64 < K) ISSUE(k0 + 64, bo_cur); // refill the buffer we just read
        COMPUTE();
        cur ^= 1;
    }

    // ---- epilogue ----
    if constexpr (WMODE == 2) {
        if (tid < 128) red[tid] = 0.f;
        __syncthreads();
        float bv[4], dwv[4];
        #pragma unroll
        for (int nt = 0; nt < 4; ++nt) {
            int colg = wn * 64 + nt * 16 + lr;
            bv[nt] = bias[colg];
            dwv[nt] = dw2[colg];
        }
        #pragma unroll
        for (int mt = 0; mt < 4; ++mt)
            #pragma unroll
            for (int j = 0; j < 4; ++j) {
                float p = 0.f;
                #pragma unroll
                for (int nt = 0; nt < 4; ++nt)
                    p += fmaxf(acc[mt][nt][j] + bv[nt], 0.f) * dwv[nt];
                p += __shfl_xor(p, 1);
                p += __shfl_xor(p, 2);
                p += __shfl_xor(p, 4);
                p += __shfl_xor(p, 8);
                if (lr == 0) atomicAdd(&red[wm * 64 + mt * 16 + lg * 4 + j], p);
            }
        __syncthreads();
        if (tid < 128) {
            int row = bm + tid;
            if (row < M) outv[row] = red[tid] + db2[0];
        }
    } else {
        float bv[4];
        int col[4];
        #pragma unroll
        for (int nt = 0; nt < 4; ++nt) {
            col[nt] = bn + wn * 64 + nt * 16 + lr;
            bv[nt] = bias ? bias[col[nt]] : 0.f;
        }
        #pragma unroll
        for (int mt = 0; mt < 4; ++mt) {
            int row0 = bm + wm * 64 + mt * 16 + lg * 4;
            #pragma unroll
            for (int j = 0; j < 4; ++j) {
                int row = row0 + j;
                if (row >= M) continue;
                size_t rbase = (size_t)row * ldc;
                #pragma unroll
                for (int nt = 0; nt < 4; ++nt) {
                    size_t off = rbase + col[nt];
                    float v = acc[mt][nt][j] + bv[nt];
                    if (flags & FLAG_RELU) v = fmaxf(v, 0.f);
                    u16 hh, ll; split2(v, hh, ll);
                    Chi[off] = hh;
                    if constexpr (WMODE == 0) Clo[off] = ll;
                }
            }
        }
    }
}

// ---------------- CSR build (merged, sections A|B|C|D) ----------------
__global__ void count_all_kernel(const int* __restrict__ hks, const int* __restrict__ hkd,
                                 const int* __restrict__ hss, const int* __restrict__ hsd,
                                 int* __restrict__ deg)
{
    int e = blockIdx.x * blockDim.x + threadIdx.x;
    if (e < E_HK) {
        atomicAdd(deg + OFFA + hkd[e], 1);
        atomicAdd(deg + OFFC + hks[e], 1);
    } else if (e < E_HK + E_HS) {
        int i = e - E_HK;
        atomicAdd(deg + OFFB + hsd[i], 1);
        atomicAdd(deg + OFFD + hss[i], 1);
    }
}

__global__ void scan_block_kernel(const int* __restrict__ in, int* __restrict__ out,
                                  int* __restrict__ bsum, int n)
{
    __shared__ int tmp[256];
    int i = blockIdx.x * 256 + threadIdx.x;
    int v = (i < n) ? in[i] : 0;
    tmp[threadIdx.x] = v;
    __syncthreads();
    #pragma unroll
    for (int off = 1; off < 256; off <<= 1) {
        int t = (threadIdx.x >= off) ? tmp[threadIdx.x - off] : 0;
        __syncthreads();
        tmp[threadIdx.x] += t;
        __syncthreads();
    }
    if (i < n) out[i] = tmp[threadIdx.x] - v;
    if (threadIdx.x == 255 && bsum) bsum[blockIdx.x] = tmp[255];
}

__global__ void scan2_kernel(int* __restrict__ data, int n) // n <= 512, in-place exclusive
{
    __shared__ int tmp[512];
    int v = (threadIdx.x < n) ? data[threadIdx.x] : 0;
    tmp[threadIdx.x] = v;
    __syncthreads();
    #pragma unroll
    for (int off = 1; off < 512; off <<= 1) {
        int t = (threadIdx.x >= off) ? tmp[threadIdx.x - off] : 0;
        __syncthreads();
        tmp[threadIdx.x] += t;
        __syncthreads();
    }
    if (threadIdx.x < n) data[threadIdx.x] = tmp[threadIdx.x] - v;
}

__global__ void scan_add_kernel(int* __restrict__ out, const int* __restrict__ bsumex, int n)
{
    int i = blockIdx.x * 256 + threadIdx.x;
    if (i < n) out[i] += bsumex[blockIdx.x];
}

__global__ void fill_all_kernel(const int* __restrict__ hks, const int* __restrict__ hkd,
                                const int* __restrict__ hss, const int* __restrict__ hsd,
                                int* __restrict__ cur, u16* __restrict__ adj)
{
    int e = blockIdx.x * blockDim.x + threadIdx.x;
    if (e < E_HK) {
        int s = hks[e], d = hkd[e];
        int p = atomicAdd(cur + OFFA + d, 1); adj[p] = (u16)s;
        int q = atomicAdd(cur + OFFC + s, 1); adj[q] = (u16)d;
    } else if (e < E_HK + E_HS) {
        int i = e - E_HK;
        int s = hss[i], d = hsd[i];
        int p = atomicAdd(cur + OFFB + d, 1); adj[p] = (u16)s;
        int q = atomicAdd(cur + OFFD + s, 1); adj[q] = (u16)d;
    }
}

// ---------------- gather mean (hi-plane read; hi[+lo] write; 16B/lane) ----------------
template <int D, bool WRITELO>
__global__ void gather_mean_kernel(const u16* __restrict__ Xhi,
                                   const int* __restrict__ cur, const int* __restrict__ deg,
                                   const u16* __restrict__ adj,
                                   u16* __restrict__ Ohi, u16* __restrict__ Olo, int ndst)
{
    constexpr int LANES = D / 8;          // 16B per lane
    constexpr int RPB = 256 / LANES;
    int r = blockIdx.x * RPB + threadIdx.x / LANES;
    if (r >= ndst) return;
    int lane = threadIdx.x % LANES;
    int end = cur[r];
    int n = deg[r];
    int j = end - n;
    float s[8];
    #pragma unroll
    for (int q = 0; q < 8; ++q) s[q] = 0.f;
    for (; j + 1 < end; j += 2) {
        u16x8 a = *(const u16x8*)(Xhi + (size_t)adj[j] * D + lane * 8);
        u16x8 b = *(const u16x8*)(Xhi + (size_t)adj[j + 1] * D + lane * 8);
        #pragma unroll
        for (int q = 0; q < 8; ++q) s[q] += bf2f(a[q]) + bf2f(b[q]);
    }
    if (j < end) {
        u16x8 a = *(const u16x8*)(Xhi + (size_t)adj[j] * D + lane * 8);
        #pragma unroll
        for (int q = 0; q < 8; ++q) s[q] += bf2f(a[q]);
    }
    float inv = (n > 0) ? 1.0f / (float)n : 0.f;
    size_t off = (size_t)r * D + lane * 8;
    u16x8 h8, l8;
    #pragma unroll
    for (int q = 0; q < 8; ++q) { u16 hh, ll; split2(s[q] * inv, hh, ll); h8[q] = hh; l8[q] = ll; }
    *(u16x8*)(Ohi + off) = h8;
    if constexpr (WRITELO) *(u16x8*)(Olo + off) = l8;
}

// ---------------- fused news assembly: N += meanC(PP) + meanD(PP2); [relu] ----------------
template <int D, bool RELU, bool HASLO>
__global__ void fuse_news_kernel(const u16* __restrict__ PPh, const u16* __restrict__ PP2h,
                                 const int* __restrict__ curC, const int* __restrict__ degC,
                                 const int* __restrict__ curD, const int* __restrict__ degD,
                                 const u16* __restrict__ adj,
                                 u16* __restrict__ Nh, u16* __restrict__ Nl, int ndst)
{
    constexpr int LANES = D / 8;          // 16B per lane
    constexpr int RPB = 256 / LANES;
    int r = blockIdx.x * RPB + threadIdx.x / LANES;
    if (r >= ndst) return;
    int lane = threadIdx.x % LANES;
    float s[8];
    #pragma unroll
    for (int q = 0; q < 8; ++q) s[q] = 0.f;
    {
        int end = curC[r], n = degC[r];
        float a[8];
        #pragma unroll
        for (int q = 0; q < 8; ++q) a[q] = 0.f;
        for (int j = end - n; j < end; ++j) {
            u16x8 v = *(const u16x8*)(PPh + (size_t)adj[j] * D + lane * 8);
            #pragma unroll
            for (int q = 0; q < 8; ++q) a[q] += bf2f(v[q]);
        }
        float inv = (n > 0) ? 1.0f / (float)n : 0.f;
        #pragma unroll
        for (int q = 0; q < 8; ++q) s[q] += a[q] * inv;
    }
    {
        int end = curD[r], n = degD[r];
        float a[8];
        #pragma unroll
        for (int q = 0; q < 8; ++q) a[q] = 0.f;
        for (int j = end - n; j < end; ++j) {
            u16x8 v = *(const u16x8*)(PP2h + (size_t)adj[j] * D + lane * 8);
            #pragma unroll
            for (int q = 0; q < 8; ++q) a[q] += bf2f(v[q]);
        }
        float inv = (n > 0) ? 1.0f / (float)n : 0.f;
        #pragma unroll
        for (int q = 0; q < 8; ++q) s[q] += a[q] * inv;
    }
    size_t off = (size_t)r * D + lane * 8;
    u16x8 h = *(const u16x8*)(Nh + off);
    if constexpr (HASLO) {
        u16x8 l = *(const u16x8*)(Nl + off);
        #pragma unroll
        for (int q = 0; q < 8; ++q) s[q] += bf2f(h[q]) + bf2f(l[q]);
    } else {
        #pragma unroll
        for (int q = 0; q < 8; ++q) s[q] += bf2f(h[q]);
    }
    #pragma unroll
    for (int q = 0; q < 8; ++q) {
        float v = s[q];
        if (RELU) v = fmaxf(v, 0.f);
        s[q] = v;
    }
    u16x8 oh, ol;
    #pragma unroll
    for (int q = 0; q < 8; ++q) { u16 hh, ll; split2(s[q], hh, ll); oh[q] = hh; ol[q] = ll; }
    *(u16x8*)(Nh + off) = oh;
    if constexpr (HASLO) *(u16x8*)(Nl + off) = ol;
}

// ---------------- batched weight split/convert ----------------
#define MAXJOBS 20
struct SplitJobs {
    const float* a[MAXJOBS];
    const float* b[MAXJOBS];     // optional second operand (summed)
    u16* hi[MAXJOBS];
    u16* lo[MAXJOBS];
    int n[MAXJOBS];
    int ncols[MAXJOBS];          // source row width
    int dstride[MAXJOBS];        // dest row stride
    int boff[MAXJOBS + 1];
    int njobs;
};

__global__ void split_all_kernel(SplitJobs J)
{
    int bid = blockIdx.x;
    int j = 0;
    while (j + 1 < J.njobs && bid >= J.boff[j + 1]) ++j;
    int i = (bid - J.boff[j]) * 1024 + threadIdx.x * 4;
    if (i >= J.n[j]) return;
    float4 v = *(const float4*)(J.a[j] + i);
    if (J.b[j]) {
        float4 w = *(const float4*)(J.b[j] + i);
        v.x += w.x; v.y += w.y; v.z += w.z; v.w += w.w;
    }
    int row = i / J.ncols[j], col = i - row * J.ncols[j];
    size_t d = (size_t)row * J.dstride[j] + col;
    ushort4 h, l;
    split2(v.x, h.x, l.x); split2(v.y, h.y, l.y); split2(v.z, h.z, l.z); split2(v.w, h.w, l.w);
    *(ushort4*)(J.hi[j] + d) = h;
    *(ushort4*)(J.lo[j] + d) = l;
}

__global__ void bias_sum_kernel(const float* __restrict__ b1, const float* __restrict__ b2,
                                float* __restrict__ BS1, float* __restrict__ BS2)
{
    int i = blockIdx.x * 256 + threadIdx.x;
    if (i < 256) BS1[i] = b1[256 + i] + b1[768 + i];
    else if (i < 384) { int j = i - 256; BS2[j] = b2[128 + j] + b2[384 + j]; }
}

// ---------------- launch ----------------
extern "C" void kernel_launch(void* const* d_in, const int* in_sizes, int n_in,
                              void* d_out, int out_size, void* d_ws, size_t ws_size,
                              hipStream_t stream)
{
    const float* x_news = (const float*)d_in[0];
    const float* x_kw   = (const float*)d_in[1];
    const float* x_st   = (const float*)d_in[2];
    const float* Wn = (const float*)d_in[3];  const float* bn = (const float*)d_in[4];
    const float* Wk = (const float*)d_in[5];  const float* bk = (const float*)d_in[6];
    const float* Wst = (const float*)d_in[7]; const float* bs = (const float*)d_in[8];
    const float* W1l = (const float*)d_in[9];  const float* b1 = (const float*)d_in[10];
    const float* W1r = (const float*)d_in[11];
    const float* W2l = (const float*)d_in[12]; const float* b2 = (const float*)d_in[13];
    const float* W2r = (const float*)d_in[14];
    const float* DW1 = (const float*)d_in[15]; const float* Db1 = (const float*)d_in[16];
    const float* DW2 = (const float*)d_in[17]; const float* Db2 = (const float*)d_in[18];
    const int* e_hk_src = (const int*)d_in[19];
    const int* e_hk_dst = (const int*)d_in[20];
    const int* e_hs_src = (const int*)d_in[21];
    const int* e_hs_dst = (const int*)d_in[22];
    const int* l_hk_src = (const int*)d_in[23];
    const int* l_hk_dst = (const int*)d_in[24];
    const int* l_hs_src = (const int*)d_in[25];
    const int* l_hs_dst = (const int*)d_in[26];
    float* out = (float*)d_out;

    // ---- workspace layout (bytes, 16B aligned) ----
    char* base = (char*)d_ws;
    auto alloc = [&](size_t bytes) -> char* {
        char* p = base;
        base += (bytes + 15) & ~(size_t)15;
        return p;
    };
    auto aplane = [&](size_t elems) -> u16* { return (u16*)alloc(elems * 2); };

    u16* HNh = aplane((size_t)N_NEWS * HID);  u16* HNl = aplane((size_t)N_NEWS * HID);
    u16* HKh = aplane((size_t)N_KW * HID);    u16* HKl = aplane((size_t)N_KW * HID);
    u16* HSh = aplane((size_t)N_ST * HID);    u16* HSl = aplane((size_t)N_ST * HID);
    u16* K1h = aplane((size_t)N_KW * HID);
    u16* S1h = aplane((size_t)N_ST * HID);
    u16* PAh = aplane((size_t)(N_KW + N_ST) * HID);   // 12000 rows (kw | st sections)
    u16* PAl = aplane((size_t)(N_KW + N_ST) * HID);
    u16* N1h = aplane((size_t)N_NEWS * HID);
    // weight planes
    u16* WnH = aplane(196608);  u16* WnL = aplane(196608);
    u16* WkH = aplane(32768);   u16* WkL = aplane(32768);
    u16* WsH = aplane(16384);   u16* WsL = aplane(16384);
    u16* CW1KH = aplane(131072); u16* CW1KL = aplane(131072);  // [256][512] W1l0|W1r0
    u16* CW1SH = aplane(131072); u16* CW1SL = aplane(131072);  // [256][512] W1l2|W1r2
    u16* W1l1H = aplane(65536);  u16* W1l1L = aplane(65536);
    u16* W1l3H = aplane(65536);  u16* W1l3L = aplane(65536);
    u16* SW1H = aplane(65536);   u16* SW1L = aplane(65536);    // W1r1+W1r3
    u16* CW2KH = aplane(65536);  u16* CW2KL = aplane(65536);   // [128][512] W2l0|W2r0
    u16* CW2SH = aplane(65536);  u16* CW2SL = aplane(65536);   // [128][512] W2l2|W2r2
    u16* W2l1H = aplane(32768);  u16* W2l1L = aplane(32768);
    u16* W2l3H = aplane(32768);  u16* W2l3L = aplane(32768);
    u16* SW2H = aplane(32768);   u16* SW2L = aplane(32768);    // W2r1+W2r3
    u16* DW1H = aplane(65536);   u16* DW1L = aplane(65536);
    float* BS1 = (float*)alloc(256 * 4);
    float* BS2 = (float*)alloc(128 * 4);
    // int pools
    int* deg = (int*)alloc((size_t)NTOT * 4);
    int* cur = (int*)alloc((size_t)NTOT * 4);
    u16* adj = (u16*)alloc((size_t)2 * (E_HK + E_HS) * 2);
    int* bsum = (int*)alloc(512 * 4);

    // overlays: layer-2 outputs reuse the HN region (dead after layer 1)
    u16* K2h = HNh;
    u16* N2h = K2h + (size_t)N_KW * OUTD;
    u16* S2h = N2h + (size_t)N_NEWS * OUTD;

    // ---- CSR build ----
    hipMemsetAsync(deg, 0, (size_t)NTOT * sizeof(int), stream);
    int etot = E_HK + E_HS;
    count_all_kernel<<<(etot + 255) / 256, 256, 0, stream>>>(e_hk_src, e_hk_dst, e_hs_src, e_hs_dst, deg);
    int nb = (NTOT + 255) / 256; // 438
    scan_block_kernel<<<nb, 256, 0, stream>>>(deg, cur, bsum, NTOT);
    scan2_kernel<<<1, 512, 0, stream>>>(bsum, nb);
    scan_add_kernel<<<nb, 256, 0, stream>>>(cur, bsum, NTOT);
    fill_all_kernel<<<(etot + 255) / 256, 256, 0, stream>>>(e_hk_src, e_hk_dst, e_hs_src, e_hs_dst, cur, adj);

    // ---- batched weight conversion ----
    {
        SplitJobs J{};
        int nj = 0, blocks = 0;
        auto job = [&](const float* a, const float* b, u16* hi, u16* lo, int n, int ncols, int dstride) {
            J.a[nj] = a; J.b[nj] = b; J.hi[nj] = hi; J.lo[nj] = lo;
            J.n[nj] = n; J.ncols[nj] = ncols; J.dstride[nj] = dstride;
            J.boff[nj] = blocks;
            blocks += (n / 4 + 255) / 256;
            ++nj;
        };
        job(Wn, nullptr, WnH, WnL, 196608, 196608, 196608);
        job(Wk, nullptr, WkH, WkL, 32768, 32768, 32768);
        job(Wst, nullptr, WsH, WsL, 16384, 16384, 16384);
        job(W1l + 0 * 65536, nullptr, CW1KH, CW1KL, 65536, 256, 512);
        job(W1r + 0 * 65536, nullptr, CW1KH + 256, CW1KL + 256, 65536, 256, 512);
        job(W1l + 2 * 65536, nullptr, CW1SH, CW1SL, 65536, 256, 512);
        job(W1r + 2 * 65536, nullptr, CW1SH + 256, CW1SL + 256, 65536, 256, 512);
        job(W1l + 1 * 65536, nullptr, W1l1H, W1l1L, 65536, 65536, 65536);
        job(W1l + 3 * 65536, nullptr, W1l3H, W1l3L, 65536, 65536, 65536);
        job(W1r + 1 * 65536, W1r + 3 * 65536, SW1H, SW1L, 65536, 65536, 65536);
        job(W2l + 0 * 32768, nullptr, CW2KH, CW2KL, 32768, 256, 512);
        job(W2r + 0 * 32768, nullptr, CW2KH + 256, CW2KL + 256, 32768, 256, 512);
        job(W2l + 2 * 32768, nullptr, CW2SH, CW2SL, 32768, 256, 512);
        job(W2r + 2 * 32768, nullptr, CW2SH + 256, CW2SL + 256, 32768, 256, 512);
        job(W2l + 1 * 32768, nullptr, W2l1H, W2l1L, 32768, 32768, 32768);
        job(W2l + 3 * 32768, nullptr, W2l3H, W2l3L, 32768, 32768, 32768);
        job(W2r + 1 * 32768, W2r + 3 * 32768, SW2H, SW2L, 32768, 32768, 32768);
        job(DW1, nullptr, DW1H, DW1L, 65536, 65536, 65536);
        J.boff[nj] = blocks;
        J.njobs = nj;
        split_all_kernel<<<blocks, 256, 0, stream>>>(J);
    }
    bias_sum_kernel<<<2, 256, 0, stream>>>(b1, b2, BS1, BS2);

    // ---- GEMM wrappers ----
    auto gemmF = [&](const float* A, int lda, const u16* Bh, const u16* Bl, int ldw,
                     const float* bias, u16* Ch, u16* Cl, int ldc,
                     int M, int N, int K, int flags) {
        dim3 g((M + 127) / 128, N / 128);
        gemm_kernel<0, 0, false><<<g, 256, 0, stream>>>(
            A, nullptr, nullptr, nullptr, nullptr, nullptr, nullptr, lda, 0,
            Bh, Bl, ldw, bias, Ch, Cl, ldc, nullptr, nullptr, nullptr, M, K, flags);
    };
    auto gemmP1 = [&](const u16* Ahp, const u16* Alp, int lda, const u16* Bh, const u16* Bl, int ldw,
                      const float* bias, u16* Ch, int ldc,
                      int M, int N, int K, int flags) {
        dim3 g((M + 127) / 128, N / 128);
        gemm_kernel<1, 1, false><<<g, 256, 0, stream>>>(
            nullptr, Ahp, Alp, nullptr, nullptr, nullptr, nullptr, lda, 0,
            Bh, Bl, ldw, bias, Ch, nullptr, ldc, nullptr, nullptr, nullptr, M, K, flags);
    };
    auto gemm21 = [&](const u16* A1hp, const u16* A1lp, const u16* A2hp, const u16* A2lp,
                      int lda, int kpiv, const u16* Bh, const u16* Bl, int ldw,
                      const float* bias, u16* Ch, int ldc,
                      int M, int N, int K, int flags) {
        dim3 g((M + 127) / 128, N / 128);
        gemm_kernel<2, 1, false><<<g, 256, 0, stream>>>(
            nullptr, A1hp, A1lp, A2hp, A2lp, nullptr, nullptr, lda, kpiv,
            Bh, Bl, ldw, bias, Ch, nullptr, ldc, nullptr, nullptr, nullptr, M, K, flags);
    };
    auto gemmLP = [&](const u16* Ahp, int lda, const u16* Bh, int ldw,
                      const float* bias, u16* Ch, int ldc, int M, int N, int K, int flags) {
        dim3 g((M + 127) / 128, N / 128);
        gemm_kernel<1, 1, true><<<g, 256, 0, stream>>>(
            nullptr, Ahp, nullptr, nullptr, nullptr, nullptr, nullptr, lda, 0,
            Bh, nullptr, ldw, bias, Ch, nullptr, ldc, nullptr, nullptr, nullptr, M, K, flags);
    };
    auto gemmL2 = [&](const u16* A1hp, const u16* A2hp, int lda, int kpiv,
                      const u16* Bh, int ldw, const float* bias, u16* Ch, int ldc,
                      int M, int N, int K, int flags) {
        dim3 g((M + 127) / 128, N / 128);
        gemm_kernel<2, 1, true><<<g, 256, 0, stream>>>(
            nullptr, A1hp, nullptr, A2hp, nullptr, nullptr, nullptr, lda, kpiv,
            Bh, nullptr, ldw, bias, Ch, nullptr, ldc, nullptr, nullptr, nullptr, M, K, flags);
    };
    auto gemmD = [&](const u16* A1hp, const u16* A2hp,
                     const int* r1, const int* r2, const u16* Bh,
                     const float* bias, const float* dw2, const float* db2, float* ov) {
        dim3 g((E_LBL + 127) / 128, 1);
        gemm_kernel<2, 2, true><<<g, 256, 0, stream>>>(
            nullptr, A1hp, nullptr, A2hp, nullptr, r1, r2, 128, 128,
            Bh, nullptr, 256, bias, nullptr, nullptr, 0, dw2, db2, ov, E_LBL, 256, 0);
    };

    // ---- input projections (full precision, hi+lo outputs) ----
    gemmF(x_news, F_NEWS, WnH, WnL, F_NEWS, bn, HNh, HNl, HID, N_NEWS, HID, F_NEWS, FLAG_RELU);
    gemmF(x_kw,   F_KW,   WkH, WkL, F_KW,   bk, HKh, HKl, HID, N_KW,   HID, F_KW,   FLAG_RELU);
    gemmF(x_st,   F_ST,   WsH, WsL, F_ST,   bs, HSh, HSl, HID, N_ST,   HID, F_ST,   FLAG_RELU);

    // ---- layer 1 (full-precision compute, hi-only storage) ----
    gather_mean_kernel<256, true><<<(N_KW + N_ST + 7) / 8, 256, 0, stream>>>(
        HNh, cur + OFFA, deg + OFFA, adj, PAh, PAl, N_KW + N_ST);
    gemm21(PAh, PAl, HKh, HKl, HID, 256, CW1KH, CW1KL, 512, b1, K1h, HID, N_KW, HID, 512, FLAG_RELU);
    gemm21(PAh + (size_t)N_KW * HID, PAl + (size_t)N_KW * HID, HSh, HSl, HID, 256,
           CW1SH, CW1SL, 512, b1 + 2 * 256, S1h, HID, N_ST, HID, 512, FLAG_RELU);
    gemmLP(HKh, HID, W1l1H, HID, nullptr, PAh, HID, N_KW, HID, HID, 0);   // PP
    gemmLP(HSh, HID, W1l3H, HID, nullptr, PAl, HID, N_ST, HID, HID, 0);   // PP2
    gemmP1(HNh, HNl, HID, SW1H, SW1L, HID, BS1, N1h, HID, N_NEWS, HID, HID, 0);
    fuse_news_kernel<256, true, false><<<(N_NEWS + 7) / 8, 256, 0, stream>>>(
        PAh, PAl, cur + OFFC, deg + OFFC, cur + OFFD, deg + OFFD, adj, N1h, nullptr, N_NEWS);

    // ---- layer 2 (LOWP: hi-only, 1 MFMA) ----
    gather_mean_kernel<256, false><<<(N_KW + N_ST + 7) / 8, 256, 0, stream>>>(
        N1h, cur + OFFA, deg + OFFA, adj, PAh, nullptr, N_KW + N_ST);
    gemmL2(PAh, K1h, HID, 256, CW2KH, 512, b2, K2h, OUTD, N_KW, OUTD, 512, 0);
    gemmL2(PAh + (size_t)N_KW * HID, S1h, HID, 256, CW2SH, 512, b2 + 2 * 128, S2h, OUTD, N_ST, OUTD, 512, 0);
    gemmLP(K1h, HID, W2l1H, HID, nullptr, PAh, OUTD, N_KW, OUTD, HID, 0);  // PP (n2)
    gemmLP(S1h, HID, W2l3H, HID, nullptr, PAl, OUTD, N_ST, OUTD, HID, 0);  // PP2 (n2)
    gemmLP(N1h, HID, SW2H, HID, BS2, N2h, OUTD, N_NEWS, OUTD, HID, 0);
    fuse_news_kernel<128, false, false><<<(N_NEWS + 15) / 16, 256, 0, stream>>>(
        PAh, PAl, cur + OFFC, deg + OFFC, cur + OFFD, deg + OFFD, adj, N2h, nullptr, N_NEWS);

    // ---- fused decoders (LOWP) ----
    gemmD(N2h, K2h, l_hk_src, l_hk_dst, DW1H, Db1, DW2, Db2, out);
    gemmD(N2h, S2h, l_hs_src, l_hs_dst, DW1H + 32768, Db1 + 128, DW2 + 128, Db2 + 1, out + E_LBL);
}